// Round 2
// baseline (6313.124 us; speedup 1.0000x reference)
//
#include <hip/hip_runtime.h>
#include <hip/hip_bf16.h>
#include <cstdint>
#include <cstddef>

#define HID 256
#define EMBD 128
#define FIN 5
#define BM 64
#define KC 32

// ---------------- K1: degree count (dst) ----------------
__global__ __launch_bounds__(256) void k_deg(const int* __restrict__ ei,
                                             float* __restrict__ deg, int E) {
  int e = blockIdx.x * 256 + threadIdx.x;
  if (e >= E) return;
  int d = ei[(size_t)E + e];
  unsafeAtomicAdd(&deg[d], 1.0f);
}

// ---------------- K2: inv = rsqrt(deg+1); gfeat reductions ----------------
__global__ __launch_bounds__(256) void k_inv_gfeat(const float* __restrict__ deg,
                                                   const float* __restrict__ x,
                                                   float* __restrict__ inv,
                                                   float* __restrict__ gacc, int N) {
  int i = blockIdx.x * 256 + threadIdx.x;
  float s2 = 0.f, s3 = 0.f, s4 = 0.f, cnt = 0.f, sl = 0.f, sm = 0.f;
  if (i < N) {
    inv[i] = rsqrtf(deg[i] + 1.0f);
    float x0 = x[(size_t)i * 5 + 0];
    float x1 = x[(size_t)i * 5 + 1];
    float x2 = x[(size_t)i * 5 + 2];
    float x3 = x[(size_t)i * 5 + 3];
    float x4 = x[(size_t)i * 5 + 4];
    s2 = x2; s3 = x3; s4 = x4;
    if (x2 == 1.0f) { cnt = 1.f; sl = x0; sm = x1; }
  }
  #pragma unroll
  for (int off = 32; off > 0; off >>= 1) {
    s2 += __shfl_down(s2, off);
    s3 += __shfl_down(s3, off);
    s4 += __shfl_down(s4, off);
    cnt += __shfl_down(cnt, off);
    sl += __shfl_down(sl, off);
    sm += __shfl_down(sm, off);
  }
  if ((threadIdx.x & 63) == 0) {
    unsafeAtomicAdd(&gacc[0], s2);
    unsafeAtomicAdd(&gacc[1], s3);
    unsafeAtomicAdd(&gacc[2], s4);
    unsafeAtomicAdd(&gacc[3], cnt);
    unsafeAtomicAdd(&gacc[4], sl);
    unsafeAtomicAdd(&gacc[5], sm);
  }
}

// ---------------- K3: U[dst] += x[src]*c (5-wide); w_raw[src] += inv[dst] ----------------
__global__ __launch_bounds__(256) void k_edge1(const int* __restrict__ ei,
                                               const float* __restrict__ x,
                                               const float* __restrict__ inv,
                                               float* __restrict__ U,
                                               float* __restrict__ w, int E) {
  int e = blockIdx.x * 256 + threadIdx.x;
  if (e >= E) return;
  int s = ei[e];
  int d = ei[(size_t)E + e];
  float is = inv[s], idv = inv[d];
  float c = is * idv;
  #pragma unroll
  for (int k = 0; k < FIN; k++)
    unsafeAtomicAdd(&U[(size_t)d * FIN + k], x[(size_t)s * FIN + k] * c);
  unsafeAtomicAdd(&w[s], idv);
}

// ---------------- K4: H1 = relu((U + x*inv^2) @ W1 + b1); finalize w ----------------
__global__ __launch_bounds__(256) void k_h1(const float* __restrict__ U,
                                            const float* __restrict__ x,
                                            const float* __restrict__ inv,
                                            const float* __restrict__ W1,
                                            const float* __restrict__ b1,
                                            float* __restrict__ H1,
                                            float* __restrict__ w, int N) {
  int i = blockIdx.x;
  int t = threadIdx.x;
  __shared__ float us[FIN];
  float iv = inv[i];
  if (t < FIN) us[t] = U[(size_t)i * FIN + t] + x[(size_t)i * FIN + t] * iv * iv;
  if (t == 0) w[i] = iv * w[i] + iv * iv;
  __syncthreads();
  float acc = b1[t];
  #pragma unroll
  for (int k = 0; k < FIN; k++) acc = fmaf(us[k], W1[k * HID + t], acc);
  H1[(size_t)i * HID + t] = fmaxf(acc, 0.0f);
}

// ---------------- K5: M[dst] += H1[src] * (inv[src]*inv[dst])  (256-wide) ----------------
__global__ __launch_bounds__(256) void k_edge2(const int* __restrict__ ei,
                                               const float* __restrict__ inv,
                                               const float* __restrict__ H1,
                                               float* __restrict__ M, int E) {
  int lane = threadIdx.x & 63;
  int e = blockIdx.x * 4 + (threadIdx.x >> 6);
  if (e >= E) return;
  int s = ei[e];
  int d = ei[(size_t)E + e];
  float c = inv[s] * inv[d];
  float4 hv = *(const float4*)(H1 + (size_t)s * HID + lane * 4);
  float* mp = M + (size_t)d * HID + lane * 4;
  unsafeAtomicAdd(mp + 0, hv.x * c);
  unsafeAtomicAdd(mp + 1, hv.y * c);
  unsafeAtomicAdd(mp + 2, hv.z * c);
  unsafeAtomicAdd(mp + 3, hv.w * c);
}

// ---------------- K6: fused GEMM: H2 = relu((M + H1*inv^2) @ W2 + b2); v += H2^T w ----------------
__global__ __launch_bounds__(256) void k_gemm2(const float* __restrict__ M,
                                               const float* __restrict__ H1,
                                               const float* __restrict__ inv,
                                               const float* __restrict__ w,
                                               const float* __restrict__ W2,
                                               const float* __restrict__ b2,
                                               float* __restrict__ v, int N) {
  __shared__ float Msh[KC][BM];      // transposed: Msh[k][r]
  __shared__ float W2sh[KC][HID];
  __shared__ float vsh[4][HID];
  int t = threadIdx.x;
  int cg = t & 63;   // column group -> cols 4*cg..4*cg+3
  int rg = t >> 6;   // row group    -> rows 16*rg..16*rg+15
  int row0 = blockIdx.x * BM;

  float4 acc[16];
  #pragma unroll
  for (int r = 0; r < 16; r++) acc[r] = make_float4(0.f, 0.f, 0.f, 0.f);

  for (int kk = 0; kk < HID; kk += KC) {
    // stage M + self-loop term, transposed into Msh[k][r]
    {
      int r = t >> 2, q = t & 3;
      int grow = row0 + r;
      if (grow < N) {
        float iv = inv[grow];
        float iv2 = iv * iv;
        const float4* mrow = (const float4*)(M + (size_t)grow * HID + kk);
        const float4* hrow = (const float4*)(H1 + (size_t)grow * HID + kk);
        #pragma unroll
        for (int j = 0; j < 2; j++) {
          float4 mv = mrow[q * 2 + j];
          float4 hv = hrow[q * 2 + j];
          int c = q * 8 + j * 4;
          Msh[c + 0][r] = fmaf(hv.x, iv2, mv.x);
          Msh[c + 1][r] = fmaf(hv.y, iv2, mv.y);
          Msh[c + 2][r] = fmaf(hv.z, iv2, mv.z);
          Msh[c + 3][r] = fmaf(hv.w, iv2, mv.w);
        }
      } else {
        #pragma unroll
        for (int j = 0; j < 2; j++) {
          int c = q * 8 + j * 4;
          Msh[c + 0][r] = 0.f; Msh[c + 1][r] = 0.f;
          Msh[c + 2][r] = 0.f; Msh[c + 3][r] = 0.f;
        }
      }
    }
    // stage W2 chunk flat (conflict-free, coalesced)
    {
      float4* dst = (float4*)&W2sh[0][0];
      const float4* src = (const float4*)(W2 + (size_t)kk * HID);
      #pragma unroll
      for (int i = 0; i < 8; i++) dst[t + i * 256] = src[t + i * 256];
    }
    __syncthreads();
    #pragma unroll
    for (int k = 0; k < KC; k++) {
      float4 wv = *(const float4*)&W2sh[k][cg * 4];
      const float4* mr = (const float4*)&Msh[k][rg * 16];
      #pragma unroll
      for (int r4 = 0; r4 < 4; r4++) {
        float4 mv = mr[r4];
        float4* a0 = &acc[r4 * 4 + 0];
        float4* a1 = &acc[r4 * 4 + 1];
        float4* a2 = &acc[r4 * 4 + 2];
        float4* a3 = &acc[r4 * 4 + 3];
        a0->x = fmaf(mv.x, wv.x, a0->x); a0->y = fmaf(mv.x, wv.y, a0->y);
        a0->z = fmaf(mv.x, wv.z, a0->z); a0->w = fmaf(mv.x, wv.w, a0->w);
        a1->x = fmaf(mv.y, wv.x, a1->x); a1->y = fmaf(mv.y, wv.y, a1->y);
        a1->z = fmaf(mv.y, wv.z, a1->z); a1->w = fmaf(mv.y, wv.w, a1->w);
        a2->x = fmaf(mv.z, wv.x, a2->x); a2->y = fmaf(mv.z, wv.y, a2->y);
        a2->z = fmaf(mv.z, wv.z, a2->z); a2->w = fmaf(mv.z, wv.w, a2->w);
        a3->x = fmaf(mv.w, wv.x, a3->x); a3->y = fmaf(mv.w, wv.y, a3->y);
        a3->z = fmaf(mv.w, wv.z, a3->z); a3->w = fmaf(mv.w, wv.w, a3->w);
      }
    }
    __syncthreads();
  }

  // epilogue: relu + bias, weighted column sums (H2 never stored)
  float4 bb = *(const float4*)&b2[cg * 4];
  float4 ps = make_float4(0.f, 0.f, 0.f, 0.f);
  #pragma unroll
  for (int r = 0; r < 16; r++) {
    int grow = row0 + rg * 16 + r;
    if (grow < N) {
      float ww = w[grow];
      ps.x = fmaf(ww, fmaxf(acc[r].x + bb.x, 0.f), ps.x);
      ps.y = fmaf(ww, fmaxf(acc[r].y + bb.y, 0.f), ps.y);
      ps.z = fmaf(ww, fmaxf(acc[r].z + bb.z, 0.f), ps.z);
      ps.w = fmaf(ww, fmaxf(acc[r].w + bb.w, 0.f), ps.w);
    }
  }
  *(float4*)&vsh[rg][cg * 4] = ps;
  __syncthreads();
  float s = vsh[0][t] + vsh[1][t] + vsh[2][t] + vsh[3][t];
  unsafeAtomicAdd(&v[t], s);
}

// ---------------- K7: embedding, gfeat, MLP head, final transform ----------------
__global__ __launch_bounds__(256) void k_head(const float* __restrict__ v,
                                              const float* __restrict__ gacc,
                                              const float* __restrict__ W3,
                                              const float* __restrict__ b3,
                                              const float* __restrict__ Wp1,
                                              const float* __restrict__ bp1,
                                              const float* __restrict__ Wp2,
                                              const float* __restrict__ bp2,
                                              const float* __restrict__ Wp3,
                                              const float* __restrict__ bp3,
                                              float* __restrict__ out, int N) {
  __shared__ float vsh[HID];
  __shared__ float emb[EMBD + 7];
  __shared__ float h64[64];
  __shared__ float h32[32];
  __shared__ float val[4];
  int t = threadIdx.x;
  vsh[t] = v[t];
  __syncthreads();
  if (t < EMBD) {
    float a = 0.f;
    for (int c = 0; c < HID; c++) a = fmaf(vsh[c], W3[c * EMBD + t], a);
    emb[t] = a / (float)N + b3[t];
  } else if (t == EMBD) {
    emb[EMBD + 0] = gacc[0];
    emb[EMBD + 1] = gacc[1];
    emb[EMBD + 2] = gacc[2];
    emb[EMBD + 3] = gacc[1] + gacc[2];
    float cnt = gacc[3];
    emb[EMBD + 4] = cnt > 0.f ? gacc[4] / fmaxf(cnt, 1.f) : 0.f;
    emb[EMBD + 5] = cnt > 0.f ? gacc[5] / fmaxf(cnt, 1.f) : 0.f;
    emb[EMBD + 6] = 100.0f / 500.0f;  // T_norm
  }
  __syncthreads();
  if (t < 64) {
    float a = bp1[t];
    for (int k = 0; k < EMBD + 7; k++) a = fmaf(emb[k], Wp1[k * 64 + t], a);
    h64[t] = fmaxf(a, 0.f);
  }
  __syncthreads();
  if (t < 32) {
    float a = bp2[t];
    for (int k = 0; k < 64; k++) a = fmaf(h64[k], Wp2[k * 32 + t], a);
    h32[t] = fmaxf(a, 0.f);
  }
  __syncthreads();
  if (t < 4) {
    float a = bp3[t];
    for (int k = 0; k < 32; k++) a = fmaf(h32[k], Wp3[k * 4 + t], a);
    val[t] = a > 20.f ? a : log1pf(expf(a));  // softplus
  }
  __syncthreads();
  if (t == 0) {
    const float Tn = 100.0f / 500.0f;
    const float scale = 1.0f - 0.7f * Tn;
    float am = 1.0f + val[0] * scale;
    float aM = 1.0f + (val[0] + val[1] + 1.0f) * scale;
    float bm = 1.0f + val[2] * scale * 0.3f;
    float bM = bm + (val[3] + 0.1f) * scale * 0.3f;
    out[0] = am; out[1] = aM; out[2] = bm; out[3] = bM;
  }
  if (t < EMBD + 7) out[4 + t] = emb[t];
}

extern "C" void kernel_launch(void* const* d_in, const int* in_sizes, int n_in,
                              void* d_out, int out_size, void* d_ws, size_t ws_size,
                              hipStream_t stream) {
  const float* x = (const float*)d_in[0];
  const int* ei = (const int*)d_in[1];
  const float* W1 = (const float*)d_in[2];
  const float* b1 = (const float*)d_in[3];
  const float* W2 = (const float*)d_in[4];
  const float* b2 = (const float*)d_in[5];
  const float* W3 = (const float*)d_in[6];
  const float* b3 = (const float*)d_in[7];
  const float* Wp1 = (const float*)d_in[8];
  const float* bp1 = (const float*)d_in[9];
  const float* Wp2 = (const float*)d_in[10];
  const float* bp2 = (const float*)d_in[11];
  const float* Wp3 = (const float*)d_in[12];
  const float* bp3 = (const float*)d_in[13];

  int N = in_sizes[0] / FIN;
  int E = in_sizes[1] / 2;

  float* ws = (float*)d_ws;
  size_t o_deg = 0;
  size_t o_U = o_deg + (size_t)N;               // 5N
  size_t o_w = o_U + (size_t)FIN * N;           // N
  size_t o_gacc = o_w + (size_t)N;              // 16
  size_t o_v = o_gacc + 16;                     // 256
  size_t o_M = o_v + HID;                       // 256N  (7N+272: 16B-aligned for N%4==0)
  size_t o_inv = o_M + (size_t)N * HID;         // N
  size_t o_H1 = o_inv + (size_t)N;              // 256N
  size_t total = o_H1 + (size_t)N * HID;
  if (ws_size < total * sizeof(float)) {
    // sentinel: insufficient workspace (output pattern 0x42 -> ~48.56f)
    hipMemsetAsync(d_out, 0x42, (size_t)out_size * sizeof(float), stream);
    return;
  }

  // zero the accumulated regions: [deg | U | w | gacc | v | M]
  hipMemsetAsync(ws, 0, (o_M + (size_t)N * HID) * sizeof(float), stream);

  k_deg<<<(E + 255) / 256, 256, 0, stream>>>(ei, ws + o_deg, E);
  k_inv_gfeat<<<(N + 255) / 256, 256, 0, stream>>>(ws + o_deg, x, ws + o_inv, ws + o_gacc, N);
  k_edge1<<<(E + 255) / 256, 256, 0, stream>>>(ei, x, ws + o_inv, ws + o_U, ws + o_w, E);
  k_h1<<<N, 256, 0, stream>>>(ws + o_U, x, ws + o_inv, W1, b1, ws + o_H1, ws + o_w, N);
  k_edge2<<<(E + 3) / 4, 256, 0, stream>>>(ei, ws + o_inv, ws + o_H1, ws + o_M, E);
  k_gemm2<<<(N + BM - 1) / BM, 256, 0, stream>>>(ws + o_M, ws + o_H1, ws + o_inv, ws + o_w,
                                                 W2, b2, ws + o_v, N);
  k_head<<<1, 256, 0, stream>>>(ws + o_v, ws + o_gacc, W3, b3, Wp1, bp1, Wp2, bp2,
                                Wp3, bp3, (float*)d_out, N);
}

// Round 3
// 875.977 us; speedup vs baseline: 7.2070x; 7.2070x over previous
//
#include <hip/hip_runtime.h>
#include <hip/hip_bf16.h>
#include <cstdint>
#include <cstddef>

#define HID 256
#define EMBD 128
#define FIN 5
#define BM 64
#define KC 32

__device__ __forceinline__ unsigned short f2bf(float f) {
  unsigned int u = __float_as_uint(f);
  u += 0x7FFFu + ((u >> 16) & 1u);   // round-to-nearest-even
  return (unsigned short)(u >> 16);
}
__device__ __forceinline__ float bf2f(unsigned short u) {
  return __uint_as_float(((unsigned int)u) << 16);
}

// ---------------- K1: degree count (dst), int ----------------
__global__ __launch_bounds__(256) void k_deg(const int* __restrict__ ei,
                                             int* __restrict__ cnt, int E) {
  int e = blockIdx.x * 256 + threadIdx.x;
  if (e >= E) return;
  atomicAdd(&cnt[ei[(size_t)E + e]], 1);
}

// ---------------- K2: inv = rsqrt(cnt+1); gfeat reductions ----------------
__global__ __launch_bounds__(256) void k_inv_gfeat(const int* __restrict__ cnt,
                                                   const float* __restrict__ x,
                                                   float* __restrict__ inv,
                                                   float* __restrict__ gacc, int N) {
  int i = blockIdx.x * 256 + threadIdx.x;
  float s2 = 0.f, s3 = 0.f, s4 = 0.f, c0 = 0.f, sl = 0.f, sm = 0.f;
  if (i < N) {
    inv[i] = rsqrtf((float)cnt[i] + 1.0f);
    float x0 = x[(size_t)i * 5 + 0];
    float x1 = x[(size_t)i * 5 + 1];
    float x2 = x[(size_t)i * 5 + 2];
    float x3 = x[(size_t)i * 5 + 3];
    float x4 = x[(size_t)i * 5 + 4];
    s2 = x2; s3 = x3; s4 = x4;
    if (x2 == 1.0f) { c0 = 1.f; sl = x0; sm = x1; }
  }
  #pragma unroll
  for (int off = 32; off > 0; off >>= 1) {
    s2 += __shfl_down(s2, off);
    s3 += __shfl_down(s3, off);
    s4 += __shfl_down(s4, off);
    c0 += __shfl_down(c0, off);
    sl += __shfl_down(sl, off);
    sm += __shfl_down(sm, off);
  }
  if ((threadIdx.x & 63) == 0) {
    unsafeAtomicAdd(&gacc[0], s2);
    unsafeAtomicAdd(&gacc[1], s3);
    unsafeAtomicAdd(&gacc[2], s4);
    unsafeAtomicAdd(&gacc[3], c0);
    unsafeAtomicAdd(&gacc[4], sl);
    unsafeAtomicAdd(&gacc[5], sm);
  }
}

// ---------------- scan: cnt -> exclusive prefix (row) ----------------
__global__ __launch_bounds__(256) void k_scan_a(const int* __restrict__ cnt,
                                                int* __restrict__ bsum, int N) {
  __shared__ int sh[256];
  int i = blockIdx.x * 256 + threadIdx.x;
  sh[threadIdx.x] = (i < N) ? cnt[i] : 0;
  __syncthreads();
  for (int off = 128; off > 0; off >>= 1) {
    if (threadIdx.x < off) sh[threadIdx.x] += sh[threadIdx.x + off];
    __syncthreads();
  }
  if (threadIdx.x == 0) bsum[blockIdx.x] = sh[0];
}

__global__ __launch_bounds__(1024) void k_scan_b(int* __restrict__ bsum, int nb) {
  __shared__ int sh[1024];
  int t = threadIdx.x;
  sh[t] = (t < nb) ? bsum[t] : 0;
  __syncthreads();
  for (int off = 1; off < 1024; off <<= 1) {
    int v = (t >= off) ? sh[t - off] : 0;
    __syncthreads();
    sh[t] += v;
    __syncthreads();
  }
  if (t < nb) bsum[t] = (t > 0) ? sh[t - 1] : 0;  // exclusive
}

__global__ __launch_bounds__(256) void k_scan_c(const int* __restrict__ cnt,
                                                const int* __restrict__ bsum,
                                                int* __restrict__ row, int N) {
  __shared__ int sh[256];
  int i = blockIdx.x * 256 + threadIdx.x;
  int v = (i < N) ? cnt[i] : 0;
  sh[threadIdx.x] = v;
  __syncthreads();
  for (int off = 1; off < 256; off <<= 1) {
    int u = (threadIdx.x >= off) ? sh[threadIdx.x - off] : 0;
    __syncthreads();
    sh[threadIdx.x] += u;
    __syncthreads();
  }
  if (i < N) row[i] = bsum[blockIdx.x] + sh[threadIdx.x] - v;  // exclusive
}

// ---------------- scatter: build csr_src; accumulate w_raw[src] += inv[dst] ----------------
// After this kernel, row[d] holds the ORIGINAL row[d+1] (end offset of node d).
__global__ __launch_bounds__(256) void k_scatter(const int* __restrict__ ei,
                                                 const float* __restrict__ inv,
                                                 int* __restrict__ row,
                                                 int* __restrict__ csr,
                                                 float* __restrict__ w, int E) {
  int e = blockIdx.x * 256 + threadIdx.x;
  if (e >= E) return;
  int s = ei[e];
  int d = ei[(size_t)E + e];
  int pos = atomicAdd(&row[d], 1);
  csr[pos] = s;
  unsafeAtomicAdd(&w[s], inv[d]);
}

// ---------------- K4: fused U-gather + H1 = relu(U@W1+b1) (bf16 out); finalize w ----------------
__global__ __launch_bounds__(256) void k_h1(const float* __restrict__ x,
                                            const int* __restrict__ row,
                                            const int* __restrict__ csr,
                                            const float* __restrict__ inv,
                                            const float* __restrict__ W1,
                                            const float* __restrict__ b1,
                                            unsigned short* __restrict__ H1b,
                                            float* __restrict__ w, int N) {
  int i = blockIdx.x;
  int t = threadIdx.x;
  __shared__ float us[FIN];
  float invd = inv[i];
  int start = (i > 0) ? row[i - 1] : 0;
  int end = row[i];
  if (t < FIN) us[t] = x[(size_t)i * FIN + t] * invd * invd;  // self-loop term
  if (t == 0) w[i] = invd * w[i] + invd * invd;               // finalize pooling weight
  __syncthreads();
  float p0 = 0.f, p1 = 0.f, p2 = 0.f, p3 = 0.f, p4 = 0.f;
  for (int e = start + t; e < end; e += 256) {
    int s = csr[e];
    float c = inv[s] * invd;
    const float* xs = x + (size_t)s * FIN;
    p0 = fmaf(xs[0], c, p0);
    p1 = fmaf(xs[1], c, p1);
    p2 = fmaf(xs[2], c, p2);
    p3 = fmaf(xs[3], c, p3);
    p4 = fmaf(xs[4], c, p4);
  }
  #pragma unroll
  for (int off = 32; off > 0; off >>= 1) {
    p0 += __shfl_down(p0, off);
    p1 += __shfl_down(p1, off);
    p2 += __shfl_down(p2, off);
    p3 += __shfl_down(p3, off);
    p4 += __shfl_down(p4, off);
  }
  if ((t & 63) == 0) {
    atomicAdd(&us[0], p0);
    atomicAdd(&us[1], p1);
    atomicAdd(&us[2], p2);
    atomicAdd(&us[3], p3);
    atomicAdd(&us[4], p4);
  }
  __syncthreads();
  float acc = b1[t];
  #pragma unroll
  for (int k = 0; k < FIN; k++) acc = fmaf(us[k], W1[k * HID + t], acc);
  H1b[(size_t)i * HID + t] = f2bf(fmaxf(acc, 0.0f));
}

// ---------------- K5: gather aggregation Z[d] = sum_e c*H1[src] + inv^2*H1[d] (bf16) ----------------
__global__ __launch_bounds__(256) void k_agg(const int* __restrict__ row,
                                             const int* __restrict__ csr,
                                             const float* __restrict__ inv,
                                             const unsigned short* __restrict__ H1b,
                                             unsigned short* __restrict__ Zb, int N) {
  int wv = threadIdx.x >> 6;
  int l = threadIdx.x & 63;
  int d = blockIdx.x * 4 + wv;
  if (d >= N) return;
  float invd = inv[d];
  int start = (d > 0) ? row[d - 1] : 0;
  int end = row[d];
  float4 acc = make_float4(0.f, 0.f, 0.f, 0.f);
  int e = start;
  for (; e + 1 < end; e += 2) {
    int s0 = csr[e], s1 = csr[e + 1];
    float cc0 = inv[s0] * invd, cc1 = inv[s1] * invd;
    ushort4 a = *(const ushort4*)(H1b + (size_t)s0 * HID + l * 4);
    ushort4 b = *(const ushort4*)(H1b + (size_t)s1 * HID + l * 4);
    acc.x += cc0 * bf2f(a.x) + cc1 * bf2f(b.x);
    acc.y += cc0 * bf2f(a.y) + cc1 * bf2f(b.y);
    acc.z += cc0 * bf2f(a.z) + cc1 * bf2f(b.z);
    acc.w += cc0 * bf2f(a.w) + cc1 * bf2f(b.w);
  }
  if (e < end) {
    int s0 = csr[e];
    float cc0 = inv[s0] * invd;
    ushort4 a = *(const ushort4*)(H1b + (size_t)s0 * HID + l * 4);
    acc.x = fmaf(cc0, bf2f(a.x), acc.x);
    acc.y = fmaf(cc0, bf2f(a.y), acc.y);
    acc.z = fmaf(cc0, bf2f(a.z), acc.z);
    acc.w = fmaf(cc0, bf2f(a.w), acc.w);
  }
  // self-loop
  {
    float c2 = invd * invd;
    ushort4 hs = *(const ushort4*)(H1b + (size_t)d * HID + l * 4);
    acc.x = fmaf(c2, bf2f(hs.x), acc.x);
    acc.y = fmaf(c2, bf2f(hs.y), acc.y);
    acc.z = fmaf(c2, bf2f(hs.z), acc.z);
    acc.w = fmaf(c2, bf2f(hs.w), acc.w);
  }
  ushort4 o;
  o.x = f2bf(acc.x); o.y = f2bf(acc.y); o.z = f2bf(acc.z); o.w = f2bf(acc.w);
  *(ushort4*)(Zb + (size_t)d * HID + l * 4) = o;
}

// ---------------- K6: fused GEMM: H2 = relu(Z @ W2 + b2); v += H2^T w ----------------
__global__ __launch_bounds__(256) void k_gemm2(const unsigned short* __restrict__ Zb,
                                               const float* __restrict__ w,
                                               const float* __restrict__ W2,
                                               const float* __restrict__ b2,
                                               float* __restrict__ v, int N) {
  __shared__ float Msh[KC][BM];      // transposed: Msh[k][r]
  __shared__ float W2sh[KC][HID];
  __shared__ float vsh[4][HID];
  int t = threadIdx.x;
  int cg = t & 63;
  int rg = t >> 6;
  int row0 = blockIdx.x * BM;

  float4 acc[16];
  #pragma unroll
  for (int r = 0; r < 16; r++) acc[r] = make_float4(0.f, 0.f, 0.f, 0.f);

  for (int kk = 0; kk < HID; kk += KC) {
    {
      int r = t >> 2, q = t & 3;
      int grow = row0 + r;
      int c = q * 8;
      if (grow < N) {
        uint4 zz = *(const uint4*)(Zb + (size_t)grow * HID + kk + q * 8);
        Msh[c + 0][r] = __uint_as_float(zz.x << 16);
        Msh[c + 1][r] = __uint_as_float(zz.x & 0xFFFF0000u);
        Msh[c + 2][r] = __uint_as_float(zz.y << 16);
        Msh[c + 3][r] = __uint_as_float(zz.y & 0xFFFF0000u);
        Msh[c + 4][r] = __uint_as_float(zz.z << 16);
        Msh[c + 5][r] = __uint_as_float(zz.z & 0xFFFF0000u);
        Msh[c + 6][r] = __uint_as_float(zz.w << 16);
        Msh[c + 7][r] = __uint_as_float(zz.w & 0xFFFF0000u);
      } else {
        #pragma unroll
        for (int j = 0; j < 8; j++) Msh[c + j][r] = 0.f;
      }
    }
    {
      float4* dst = (float4*)&W2sh[0][0];
      const float4* src = (const float4*)(W2 + (size_t)kk * HID);
      #pragma unroll
      for (int i = 0; i < 8; i++) dst[t + i * 256] = src[t + i * 256];
    }
    __syncthreads();
    #pragma unroll
    for (int k = 0; k < KC; k++) {
      float4 wv = *(const float4*)&W2sh[k][cg * 4];
      const float4* mr = (const float4*)&Msh[k][rg * 16];
      #pragma unroll
      for (int r4 = 0; r4 < 4; r4++) {
        float4 mv = mr[r4];
        float4* a0 = &acc[r4 * 4 + 0];
        float4* a1 = &acc[r4 * 4 + 1];
        float4* a2 = &acc[r4 * 4 + 2];
        float4* a3 = &acc[r4 * 4 + 3];
        a0->x = fmaf(mv.x, wv.x, a0->x); a0->y = fmaf(mv.x, wv.y, a0->y);
        a0->z = fmaf(mv.x, wv.z, a0->z); a0->w = fmaf(mv.x, wv.w, a0->w);
        a1->x = fmaf(mv.y, wv.x, a1->x); a1->y = fmaf(mv.y, wv.y, a1->y);
        a1->z = fmaf(mv.y, wv.z, a1->z); a1->w = fmaf(mv.y, wv.w, a1->w);
        a2->x = fmaf(mv.z, wv.x, a2->x); a2->y = fmaf(mv.z, wv.y, a2->y);
        a2->z = fmaf(mv.z, wv.z, a2->z); a2->w = fmaf(mv.z, wv.w, a2->w);
        a3->x = fmaf(mv.w, wv.x, a3->x); a3->y = fmaf(mv.w, wv.y, a3->y);
        a3->z = fmaf(mv.w, wv.z, a3->z); a3->w = fmaf(mv.w, wv.w, a3->w);
      }
    }
    __syncthreads();
  }

  float4 bb = *(const float4*)&b2[cg * 4];
  float4 ps = make_float4(0.f, 0.f, 0.f, 0.f);
  #pragma unroll
  for (int r = 0; r < 16; r++) {
    int grow = row0 + rg * 16 + r;
    if (grow < N) {
      float ww = w[grow];
      ps.x = fmaf(ww, fmaxf(acc[r].x + bb.x, 0.f), ps.x);
      ps.y = fmaf(ww, fmaxf(acc[r].y + bb.y, 0.f), ps.y);
      ps.z = fmaf(ww, fmaxf(acc[r].z + bb.z, 0.f), ps.z);
      ps.w = fmaf(ww, fmaxf(acc[r].w + bb.w, 0.f), ps.w);
    }
  }
  *(float4*)&vsh[rg][cg * 4] = ps;
  __syncthreads();
  float s = vsh[0][t] + vsh[1][t] + vsh[2][t] + vsh[3][t];
  unsafeAtomicAdd(&v[t], s);
}

// ---------------- K7: embedding, gfeat, MLP head, final transform ----------------
__global__ __launch_bounds__(256) void k_head(const float* __restrict__ v,
                                              const float* __restrict__ gacc,
                                              const float* __restrict__ W3,
                                              const float* __restrict__ b3,
                                              const float* __restrict__ Wp1,
                                              const float* __restrict__ bp1,
                                              const float* __restrict__ Wp2,
                                              const float* __restrict__ bp2,
                                              const float* __restrict__ Wp3,
                                              const float* __restrict__ bp3,
                                              float* __restrict__ out, int N) {
  __shared__ float vsh[HID];
  __shared__ float emb[EMBD + 7];
  __shared__ float h64[64];
  __shared__ float h32[32];
  __shared__ float val[4];
  int t = threadIdx.x;
  vsh[t] = v[t];
  __syncthreads();
  if (t < EMBD) {
    float a = 0.f;
    for (int c = 0; c < HID; c++) a = fmaf(vsh[c], W3[c * EMBD + t], a);
    emb[t] = a / (float)N + b3[t];
  } else if (t == EMBD) {
    emb[EMBD + 0] = gacc[0];
    emb[EMBD + 1] = gacc[1];
    emb[EMBD + 2] = gacc[2];
    emb[EMBD + 3] = gacc[1] + gacc[2];
    float cnt = gacc[3];
    emb[EMBD + 4] = cnt > 0.f ? gacc[4] / fmaxf(cnt, 1.f) : 0.f;
    emb[EMBD + 5] = cnt > 0.f ? gacc[5] / fmaxf(cnt, 1.f) : 0.f;
    emb[EMBD + 6] = 100.0f / 500.0f;  // T_norm
  }
  __syncthreads();
  if (t < 64) {
    float a = bp1[t];
    for (int k = 0; k < EMBD + 7; k++) a = fmaf(emb[k], Wp1[k * 64 + t], a);
    h64[t] = fmaxf(a, 0.f);
  }
  __syncthreads();
  if (t < 32) {
    float a = bp2[t];
    for (int k = 0; k < 64; k++) a = fmaf(h64[k], Wp2[k * 32 + t], a);
    h32[t] = fmaxf(a, 0.f);
  }
  __syncthreads();
  if (t < 4) {
    float a = bp3[t];
    for (int k = 0; k < 32; k++) a = fmaf(h32[k], Wp3[k * 4 + t], a);
    val[t] = a > 20.f ? a : log1pf(expf(a));  // softplus
  }
  __syncthreads();
  if (t == 0) {
    const float Tn = 100.0f / 500.0f;
    const float scale = 1.0f - 0.7f * Tn;
    float am = 1.0f + val[0] * scale;
    float aM = 1.0f + (val[0] + val[1] + 1.0f) * scale;
    float bm = 1.0f + val[2] * scale * 0.3f;
    float bM = bm + (val[3] + 0.1f) * scale * 0.3f;
    out[0] = am; out[1] = aM; out[2] = bm; out[3] = bM;
  }
  if (t < EMBD + 7) out[4 + t] = emb[t];
}

static inline size_t al4(size_t a) { return (a + 3) & ~(size_t)3; }

extern "C" void kernel_launch(void* const* d_in, const int* in_sizes, int n_in,
                              void* d_out, int out_size, void* d_ws, size_t ws_size,
                              hipStream_t stream) {
  const float* x = (const float*)d_in[0];
  const int* ei = (const int*)d_in[1];
  const float* W1 = (const float*)d_in[2];
  const float* b1 = (const float*)d_in[3];
  const float* W2 = (const float*)d_in[4];
  const float* b2 = (const float*)d_in[5];
  const float* W3 = (const float*)d_in[6];
  const float* b3 = (const float*)d_in[7];
  const float* Wp1 = (const float*)d_in[8];
  const float* bp1 = (const float*)d_in[9];
  const float* Wp2 = (const float*)d_in[10];
  const float* bp2 = (const float*)d_in[11];
  const float* Wp3 = (const float*)d_in[12];
  const float* bp3 = (const float*)d_in[13];

  int N = in_sizes[0] / FIN;
  int E = in_sizes[1] / 2;
  int nb = (N + 255) / 256;

  float* ws = (float*)d_ws;
  // layout (units of 4B, all 16B-aligned): zeroed prefix first
  size_t o_cnt = 0;                              // N ints
  size_t o_w   = al4(o_cnt + N);                 // N floats
  size_t o_gacc= al4(o_w + N);                   // 16
  size_t o_v   = o_gacc + 16;                    // 256
  size_t o_bs  = o_v + 256;                      // 1024 ints (block sums)
  size_t zero_end = o_bs + 1024;
  size_t o_row = zero_end;                       // N+4 ints
  size_t o_csr = al4(o_row + N + 4);             // E ints
  size_t o_inv = al4(o_csr + E);                 // N floats
  size_t o_H1  = al4(o_inv + N);                 // 128N (256N bf16)
  size_t o_Z   = o_H1 + (size_t)N * (HID / 2);   // 128N (256N bf16)
  size_t total = o_Z + (size_t)N * (HID / 2);
  if (ws_size < total * sizeof(float)) {
    hipMemsetAsync(d_out, 0x42, (size_t)out_size * sizeof(float), stream);
    return;
  }

  int* cnt = (int*)(ws + o_cnt);
  int* bsum = (int*)(ws + o_bs);
  int* row = (int*)(ws + o_row);
  int* csr = (int*)(ws + o_csr);
  unsigned short* H1b = (unsigned short*)(ws + o_H1);
  unsigned short* Zb = (unsigned short*)(ws + o_Z);

  hipMemsetAsync(ws, 0, zero_end * sizeof(float), stream);

  k_deg<<<(E + 255) / 256, 256, 0, stream>>>(ei, cnt, E);
  k_inv_gfeat<<<nb, 256, 0, stream>>>(cnt, x, ws + o_inv, ws + o_gacc, N);
  k_scan_a<<<nb, 256, 0, stream>>>(cnt, bsum, N);
  k_scan_b<<<1, 1024, 0, stream>>>(bsum, nb);
  k_scan_c<<<nb, 256, 0, stream>>>(cnt, bsum, row, N);
  k_scatter<<<(E + 255) / 256, 256, 0, stream>>>(ei, ws + o_inv, row, csr, ws + o_w, E);
  k_h1<<<N, 256, 0, stream>>>(x, row, csr, ws + o_inv, W1, b1, H1b, ws + o_w, N);
  k_agg<<<(N + 3) / 4, 256, 0, stream>>>(row, csr, ws + o_inv, H1b, Zb, N);
  k_gemm2<<<(N + BM - 1) / BM, 256, 0, stream>>>(Zb, ws + o_w, W2, b2, ws + o_v, N);
  k_head<<<1, 256, 0, stream>>>(ws + o_v, ws + o_gacc, W3, b3, Wp1, bp1, Wp2, bp2,
                                Wp3, bp3, (float*)d_out, N);
}

// Round 4
// 730.203 us; speedup vs baseline: 8.6457x; 1.1996x over previous
//
#include <hip/hip_runtime.h>
#include <hip/hip_bf16.h>
#include <cstdint>
#include <cstddef>

#define HID 256
#define EMBD 128
#define FIN 5

typedef __attribute__((ext_vector_type(8))) short bf16x8;
typedef __attribute__((ext_vector_type(4))) float f32x4;

__device__ __forceinline__ unsigned short f2bf(float f) {
  unsigned int u = __float_as_uint(f);
  u += 0x7FFFu + ((u >> 16) & 1u);   // round-to-nearest-even
  return (unsigned short)(u >> 16);
}
__device__ __forceinline__ float bf2f(unsigned short u) {
  return __uint_as_float(((unsigned int)u) << 16);
}
__device__ __forceinline__ float bflo(unsigned int u) { return __uint_as_float(u << 16); }
__device__ __forceinline__ float bfhi(unsigned int u) { return __uint_as_float(u & 0xFFFF0000u); }
__device__ __forceinline__ unsigned int pack2bf(float a, float b) {
  return ((unsigned int)f2bf(b) << 16) | (unsigned int)f2bf(a);
}

// ---------------- K1: degree count (dst) ----------------
__global__ __launch_bounds__(256) void k_deg(const int* __restrict__ ei,
                                             int* __restrict__ cnt, int E) {
  int e = blockIdx.x * 256 + threadIdx.x;
  if (e >= E) return;
  atomicAdd(&cnt[ei[(size_t)E + e]], 1);
}

// ---------------- K2: inv = rsqrt(cnt+1); gfeat reductions ----------------
__global__ __launch_bounds__(256) void k_inv_gfeat(const int* __restrict__ cnt,
                                                   const float* __restrict__ x,
                                                   float* __restrict__ inv,
                                                   float* __restrict__ gacc, int N) {
  int i = blockIdx.x * 256 + threadIdx.x;
  float s2 = 0.f, s3 = 0.f, s4 = 0.f, c0 = 0.f, sl = 0.f, sm = 0.f;
  if (i < N) {
    inv[i] = rsqrtf((float)cnt[i] + 1.0f);
    float x0 = x[(size_t)i * 5 + 0];
    float x1 = x[(size_t)i * 5 + 1];
    float x2 = x[(size_t)i * 5 + 2];
    float x3 = x[(size_t)i * 5 + 3];
    float x4 = x[(size_t)i * 5 + 4];
    s2 = x2; s3 = x3; s4 = x4;
    if (x2 == 1.0f) { c0 = 1.f; sl = x0; sm = x1; }
  }
  #pragma unroll
  for (int off = 32; off > 0; off >>= 1) {
    s2 += __shfl_down(s2, off);
    s3 += __shfl_down(s3, off);
    s4 += __shfl_down(s4, off);
    c0 += __shfl_down(c0, off);
    sl += __shfl_down(sl, off);
    sm += __shfl_down(sm, off);
  }
  if ((threadIdx.x & 63) == 0) {
    unsafeAtomicAdd(&gacc[0], s2);
    unsafeAtomicAdd(&gacc[1], s3);
    unsafeAtomicAdd(&gacc[2], s4);
    unsafeAtomicAdd(&gacc[3], c0);
    unsafeAtomicAdd(&gacc[4], sl);
    unsafeAtomicAdd(&gacc[5], sm);
  }
}

// ---------------- scan: cnt -> exclusive prefix (row) ----------------
__global__ __launch_bounds__(256) void k_scan_a(const int* __restrict__ cnt,
                                                int* __restrict__ bsum, int N) {
  __shared__ int sh[256];
  int i = blockIdx.x * 256 + threadIdx.x;
  sh[threadIdx.x] = (i < N) ? cnt[i] : 0;
  __syncthreads();
  for (int off = 128; off > 0; off >>= 1) {
    if (threadIdx.x < off) sh[threadIdx.x] += sh[threadIdx.x + off];
    __syncthreads();
  }
  if (threadIdx.x == 0) bsum[blockIdx.x] = sh[0];
}

__global__ __launch_bounds__(1024) void k_scan_b(int* __restrict__ bsum, int nb) {
  __shared__ int sh[1024];
  int t = threadIdx.x;
  sh[t] = (t < nb) ? bsum[t] : 0;
  __syncthreads();
  for (int off = 1; off < 1024; off <<= 1) {
    int v = (t >= off) ? sh[t - off] : 0;
    __syncthreads();
    sh[t] += v;
    __syncthreads();
  }
  if (t < nb) bsum[t] = (t > 0) ? sh[t - 1] : 0;  // exclusive
}

__global__ __launch_bounds__(256) void k_scan_c(const int* __restrict__ cnt,
                                                const int* __restrict__ bsum,
                                                int* __restrict__ row, int N) {
  __shared__ int sh[256];
  int i = blockIdx.x * 256 + threadIdx.x;
  int v = (i < N) ? cnt[i] : 0;
  sh[threadIdx.x] = v;
  __syncthreads();
  for (int off = 1; off < 256; off <<= 1) {
    int u = (threadIdx.x >= off) ? sh[threadIdx.x - off] : 0;
    __syncthreads();
    sh[threadIdx.x] += u;
    __syncthreads();
  }
  if (i < N) row[i] = bsum[blockIdx.x] + sh[threadIdx.x] - v;  // exclusive
}

// ---------------- scatter: build csr_src; accumulate w_raw[src] += inv[dst] ----------------
// After this kernel, row[d] holds the original row[d+1] (end offset of node d).
__global__ __launch_bounds__(256) void k_scatter(const int* __restrict__ ei,
                                                 const float* __restrict__ inv,
                                                 int* __restrict__ row,
                                                 int* __restrict__ csr,
                                                 float* __restrict__ w, int E) {
  int e = blockIdx.x * 256 + threadIdx.x;
  if (e >= E) return;
  int s = ei[e];
  int d = ei[(size_t)E + e];
  int pos = atomicAdd(&row[d], 1);
  csr[pos] = s;
  unsafeAtomicAdd(&w[s], inv[d]);
}

// ---------------- W2 -> bf16 transposed (W2t[n][k]) ----------------
__global__ __launch_bounds__(256) void k_w2t(const float* __restrict__ W2,
                                             unsigned short* __restrict__ W2t) {
  int n = blockIdx.x;
  int k = threadIdx.x;
  W2t[(size_t)n * HID + k] = f2bf(W2[(size_t)k * HID + n]);
}

// ---------------- K4: thread-per-node U gather + H1 = relu(U@W1+b1) bf16; finalize w ---------
__global__ __launch_bounds__(256) void k_h1f(const float* __restrict__ x,
                                             const int* __restrict__ row,
                                             const int* __restrict__ csr,
                                             const float* __restrict__ inv,
                                             const float* __restrict__ W1,
                                             const float* __restrict__ b1,
                                             unsigned short* __restrict__ H1b,
                                             float* __restrict__ w, int N) {
  __shared__ float W1sh[FIN][HID];
  __shared__ float b1sh[HID];
  int t = threadIdx.x;
  #pragma unroll
  for (int k = 0; k < FIN; k++) W1sh[k][t] = W1[k * HID + t];
  b1sh[t] = b1[t];
  int n = blockIdx.x * 256 + t;
  float u0 = 0.f, u1 = 0.f, u2 = 0.f, u3 = 0.f, u4 = 0.f;
  if (n < N) {
    float invd = inv[n];
    int start = (n > 0) ? row[n - 1] : 0;
    int end = row[n];
    for (int e = start; e < end; e++) {
      int s = csr[e];
      float c = inv[s] * invd;
      const float* xs = x + (size_t)s * FIN;
      u0 = fmaf(xs[0], c, u0);
      u1 = fmaf(xs[1], c, u1);
      u2 = fmaf(xs[2], c, u2);
      u3 = fmaf(xs[3], c, u3);
      u4 = fmaf(xs[4], c, u4);
    }
    float i2 = invd * invd;
    const float* xn = x + (size_t)n * FIN;
    u0 = fmaf(xn[0], i2, u0);
    u1 = fmaf(xn[1], i2, u1);
    u2 = fmaf(xn[2], i2, u2);
    u3 = fmaf(xn[3], i2, u3);
    u4 = fmaf(xn[4], i2, u4);
    w[n] = invd * w[n] + i2;  // finalize pooling weight
  }
  __syncthreads();
  if (n >= N) return;
  unsigned short* hrow = H1b + (size_t)n * HID;
  for (int c8 = 0; c8 < HID; c8 += 8) {
    float a[8];
    #pragma unroll
    for (int j = 0; j < 8; j++) {
      float s = b1sh[c8 + j];
      s = fmaf(u0, W1sh[0][c8 + j], s);
      s = fmaf(u1, W1sh[1][c8 + j], s);
      s = fmaf(u2, W1sh[2][c8 + j], s);
      s = fmaf(u3, W1sh[3][c8 + j], s);
      s = fmaf(u4, W1sh[4][c8 + j], s);
      a[j] = fmaxf(s, 0.f);
    }
    uint4 o;
    o.x = pack2bf(a[0], a[1]);
    o.y = pack2bf(a[2], a[3]);
    o.z = pack2bf(a[4], a[5]);
    o.w = pack2bf(a[6], a[7]);
    *(uint4*)(hrow + c8) = o;
  }
}

// ---------------- K5: gather aggregation Z[d] = sum c*H1[src] + inv^2*H1[d] (bf16) ---------
// wave per node; two 32-lane halves each process one edge (16B/lane), unroll x2.
__global__ __launch_bounds__(256) void k_agg(const int* __restrict__ row,
                                             const int* __restrict__ csr,
                                             const float* __restrict__ inv,
                                             const unsigned short* __restrict__ H1b,
                                             unsigned short* __restrict__ Zb, int N) {
  int wv = threadIdx.x >> 6;
  int l = threadIdx.x & 63;
  int h = l >> 5;        // which edge of the pair
  int sl = l & 31;       // col group: cols sl*8 .. sl*8+7
  int d = blockIdx.x * 4 + wv;
  if (d >= N) return;
  float invd = inv[d];
  int start = (d > 0) ? row[d - 1] : 0;
  int end = row[d];
  float acc[8] = {0.f, 0.f, 0.f, 0.f, 0.f, 0.f, 0.f, 0.f};
  int e = start + h;
  for (; e + 2 < end; e += 4) {
    int s0 = csr[e], s1 = csr[e + 2];
    float c0 = inv[s0] * invd, c1 = inv[s1] * invd;
    uint4 r0 = *(const uint4*)(H1b + (size_t)s0 * HID + sl * 8);
    uint4 r1 = *(const uint4*)(H1b + (size_t)s1 * HID + sl * 8);
    acc[0] += c0 * bflo(r0.x) + c1 * bflo(r1.x);
    acc[1] += c0 * bfhi(r0.x) + c1 * bfhi(r1.x);
    acc[2] += c0 * bflo(r0.y) + c1 * bflo(r1.y);
    acc[3] += c0 * bfhi(r0.y) + c1 * bfhi(r1.y);
    acc[4] += c0 * bflo(r0.z) + c1 * bflo(r1.z);
    acc[5] += c0 * bfhi(r0.z) + c1 * bfhi(r1.z);
    acc[6] += c0 * bflo(r0.w) + c1 * bflo(r1.w);
    acc[7] += c0 * bfhi(r0.w) + c1 * bfhi(r1.w);
  }
  for (; e < end; e += 2) {
    int s0 = csr[e];
    float c0 = inv[s0] * invd;
    uint4 r0 = *(const uint4*)(H1b + (size_t)s0 * HID + sl * 8);
    acc[0] = fmaf(c0, bflo(r0.x), acc[0]);
    acc[1] = fmaf(c0, bfhi(r0.x), acc[1]);
    acc[2] = fmaf(c0, bflo(r0.y), acc[2]);
    acc[3] = fmaf(c0, bfhi(r0.y), acc[3]);
    acc[4] = fmaf(c0, bflo(r0.z), acc[4]);
    acc[5] = fmaf(c0, bfhi(r0.z), acc[5]);
    acc[6] = fmaf(c0, bflo(r0.w), acc[6]);
    acc[7] = fmaf(c0, bfhi(r0.w), acc[7]);
  }
  #pragma unroll
  for (int j = 0; j < 8; j++) acc[j] += __shfl_xor(acc[j], 32);
  if (h == 0) {
    float c2 = invd * invd;
    uint4 rs = *(const uint4*)(H1b + (size_t)d * HID + sl * 8);
    acc[0] = fmaf(c2, bflo(rs.x), acc[0]);
    acc[1] = fmaf(c2, bfhi(rs.x), acc[1]);
    acc[2] = fmaf(c2, bflo(rs.y), acc[2]);
    acc[3] = fmaf(c2, bfhi(rs.y), acc[3]);
    acc[4] = fmaf(c2, bflo(rs.z), acc[4]);
    acc[5] = fmaf(c2, bfhi(rs.z), acc[5]);
    acc[6] = fmaf(c2, bflo(rs.w), acc[6]);
    acc[7] = fmaf(c2, bfhi(rs.w), acc[7]);
    uint4 o;
    o.x = pack2bf(acc[0], acc[1]);
    o.y = pack2bf(acc[2], acc[3]);
    o.z = pack2bf(acc[4], acc[5]);
    o.w = pack2bf(acc[6], acc[7]);
    *(uint4*)(Zb + (size_t)d * HID + sl * 8) = o;
  }
}

// ---------------- K6: MFMA GEMM: H2 = relu(Z @ W2 + b2); v += H2^T w ----------------
// block: 4 waves, 64 rows; wave: 16 rows x 256 cols via 16x16x32 bf16 MFMA.
__global__ __launch_bounds__(256) void k_gemm2(const unsigned short* __restrict__ Zb,
                                               const float* __restrict__ w,
                                               const unsigned short* __restrict__ W2t,
                                               const float* __restrict__ b2,
                                               float* __restrict__ v, int N) {
  __shared__ float vsh[4][HID];
  int t = threadIdx.x;
  int wv = t >> 6, l = t & 63;
  int lo = l & 15, hi = l >> 4;
  int row0 = blockIdx.x * 64 + wv * 16;

  // A fragments: rows row0+lo, k = kk*32 + hi*8 + j
  bf16x8 a[8];
  const unsigned short* zrow = Zb + (size_t)(row0 + lo) * HID + hi * 8;
  #pragma unroll
  for (int kk = 0; kk < 8; kk++)
    a[kk] = *reinterpret_cast<const bf16x8*>(zrow + kk * 32);

  float w4[4];
  #pragma unroll
  for (int i = 0; i < 4; i++) {
    int gr = row0 + hi * 4 + i;
    w4[i] = (gr < N) ? w[gr] : 0.f;
  }

  #pragma unroll
  for (int ct = 0; ct < 16; ct += 2) {
    f32x4 acc0 = {0.f, 0.f, 0.f, 0.f};
    f32x4 acc1 = {0.f, 0.f, 0.f, 0.f};
    const unsigned short* w0 = W2t + (size_t)(ct * 16 + lo) * HID + hi * 8;
    const unsigned short* w1 = w0 + 16 * HID;
    #pragma unroll
    for (int kk = 0; kk < 8; kk++) {
      bf16x8 b0 = *reinterpret_cast<const bf16x8*>(w0 + kk * 32);
      bf16x8 b1v = *reinterpret_cast<const bf16x8*>(w1 + kk * 32);
      acc0 = __builtin_amdgcn_mfma_f32_16x16x32_bf16(a[kk], b0, acc0, 0, 0, 0);
      acc1 = __builtin_amdgcn_mfma_f32_16x16x32_bf16(a[kk], b1v, acc1, 0, 0, 0);
    }
    // epilogue: relu+bias, weight by w[], reduce 16 rows -> per-col partial
    {
      float bc = b2[ct * 16 + lo];
      float p = 0.f;
      #pragma unroll
      for (int i = 0; i < 4; i++) p = fmaf(w4[i], fmaxf(acc0[i] + bc, 0.f), p);
      p += __shfl_xor(p, 16);
      p += __shfl_xor(p, 32);
      if (hi == 0) vsh[wv][ct * 16 + lo] = p;
    }
    {
      float bc = b2[(ct + 1) * 16 + lo];
      float p = 0.f;
      #pragma unroll
      for (int i = 0; i < 4; i++) p = fmaf(w4[i], fmaxf(acc1[i] + bc, 0.f), p);
      p += __shfl_xor(p, 16);
      p += __shfl_xor(p, 32);
      if (hi == 0) vsh[wv][(ct + 1) * 16 + lo] = p;
    }
  }
  __syncthreads();
  float s = vsh[0][t] + vsh[1][t] + vsh[2][t] + vsh[3][t];
  unsafeAtomicAdd(&v[t], s);
}

// ---------------- K7: embedding, gfeat, MLP head, final transform ----------------
__global__ __launch_bounds__(256) void k_head(const float* __restrict__ v,
                                              const float* __restrict__ gacc,
                                              const float* __restrict__ W3,
                                              const float* __restrict__ b3,
                                              const float* __restrict__ Wp1,
                                              const float* __restrict__ bp1,
                                              const float* __restrict__ Wp2,
                                              const float* __restrict__ bp2,
                                              const float* __restrict__ Wp3,
                                              const float* __restrict__ bp3,
                                              float* __restrict__ out, int N) {
  __shared__ float vsh[HID];
  __shared__ float emb[EMBD + 7];
  __shared__ float h64[64];
  __shared__ float h32[32];
  __shared__ float val[4];
  int t = threadIdx.x;
  vsh[t] = v[t];
  __syncthreads();
  if (t < EMBD) {
    float a = 0.f;
    for (int c = 0; c < HID; c++) a = fmaf(vsh[c], W3[c * EMBD + t], a);
    emb[t] = a / (float)N + b3[t];
  } else if (t == EMBD) {
    emb[EMBD + 0] = gacc[0];
    emb[EMBD + 1] = gacc[1];
    emb[EMBD + 2] = gacc[2];
    emb[EMBD + 3] = gacc[1] + gacc[2];
    float cnt = gacc[3];
    emb[EMBD + 4] = cnt > 0.f ? gacc[4] / fmaxf(cnt, 1.f) : 0.f;
    emb[EMBD + 5] = cnt > 0.f ? gacc[5] / fmaxf(cnt, 1.f) : 0.f;
    emb[EMBD + 6] = 100.0f / 500.0f;  // T_norm
  }
  __syncthreads();
  if (t < 64) {
    float a = bp1[t];
    for (int k = 0; k < EMBD + 7; k++) a = fmaf(emb[k], Wp1[k * 64 + t], a);
    h64[t] = fmaxf(a, 0.f);
  }
  __syncthreads();
  if (t < 32) {
    float a = bp2[t];
    for (int k = 0; k < 64; k++) a = fmaf(h64[k], Wp2[k * 32 + t], a);
    h32[t] = fmaxf(a, 0.f);
  }
  __syncthreads();
  if (t < 4) {
    float a = bp3[t];
    for (int k = 0; k < 32; k++) a = fmaf(h32[k], Wp3[k * 4 + t], a);
    val[t] = a > 20.f ? a : log1pf(expf(a));  // softplus
  }
  __syncthreads();
  if (t == 0) {
    const float Tn = 100.0f / 500.0f;
    const float scale = 1.0f - 0.7f * Tn;
    float am = 1.0f + val[0] * scale;
    float aM = 1.0f + (val[0] + val[1] + 1.0f) * scale;
    float bm = 1.0f + val[2] * scale * 0.3f;
    float bM = bm + (val[3] + 0.1f) * scale * 0.3f;
    out[0] = am; out[1] = aM; out[2] = bm; out[3] = bM;
  }
  if (t < EMBD + 7) out[4 + t] = emb[t];
}

static inline size_t al4(size_t a) { return (a + 3) & ~(size_t)3; }

extern "C" void kernel_launch(void* const* d_in, const int* in_sizes, int n_in,
                              void* d_out, int out_size, void* d_ws, size_t ws_size,
                              hipStream_t stream) {
  const float* x = (const float*)d_in[0];
  const int* ei = (const int*)d_in[1];
  const float* W1 = (const float*)d_in[2];
  const float* b1 = (const float*)d_in[3];
  const float* W2 = (const float*)d_in[4];
  const float* b2 = (const float*)d_in[5];
  const float* W3 = (const float*)d_in[6];
  const float* b3 = (const float*)d_in[7];
  const float* Wp1 = (const float*)d_in[8];
  const float* bp1 = (const float*)d_in[9];
  const float* Wp2 = (const float*)d_in[10];
  const float* bp2 = (const float*)d_in[11];
  const float* Wp3 = (const float*)d_in[12];
  const float* bp3 = (const float*)d_in[13];

  int N = in_sizes[0] / FIN;
  int E = in_sizes[1] / 2;
  int nb = (N + 255) / 256;
  int Npad = ((N + 63) / 64) * 64;

  float* ws = (float*)d_ws;
  // layout (units of 4B): zeroed prefix first
  size_t o_cnt = 0;                               // N ints
  size_t o_w   = al4(o_cnt + N);                  // N floats
  size_t o_gacc= al4(o_w + N);                    // 16
  size_t o_v   = o_gacc + 16;                     // 256
  size_t o_bs  = o_v + 256;                       // 1024 ints (block sums)
  size_t zero_end = o_bs + 1024;
  size_t o_row = zero_end;                        // N+4 ints
  size_t o_csr = al4(o_row + N + 4);              // E ints
  size_t o_inv = al4(o_csr + E);                  // N floats
  size_t o_w2t = al4(o_inv + N);                  // HID*HID/2 = 32768 (bf16 W2t)
  size_t o_H1  = o_w2t + (size_t)HID * HID / 2;   // N*128 (bf16)
  size_t o_Z   = o_H1 + (size_t)N * (HID / 2);    // Npad*128 (bf16)
  size_t total = o_Z + (size_t)Npad * (HID / 2);
  if (ws_size < total * sizeof(float)) {
    hipMemsetAsync(d_out, 0x42, (size_t)out_size * sizeof(float), stream);
    return;
  }

  int* cnt = (int*)(ws + o_cnt);
  int* bsum = (int*)(ws + o_bs);
  int* row = (int*)(ws + o_row);
  int* csr = (int*)(ws + o_csr);
  unsigned short* W2t = (unsigned short*)(ws + o_w2t);
  unsigned short* H1b = (unsigned short*)(ws + o_H1);
  unsigned short* Zb = (unsigned short*)(ws + o_Z);

  hipMemsetAsync(ws, 0, zero_end * sizeof(float), stream);

  k_deg<<<(E + 255) / 256, 256, 0, stream>>>(ei, cnt, E);
  k_w2t<<<HID, HID, 0, stream>>>(W2, W2t);
  k_inv_gfeat<<<nb, 256, 0, stream>>>(cnt, x, ws + o_inv, ws + o_gacc, N);
  k_scan_a<<<nb, 256, 0, stream>>>(cnt, bsum, N);
  k_scan_b<<<1, 1024, 0, stream>>>(bsum, nb);
  k_scan_c<<<nb, 256, 0, stream>>>(cnt, bsum, row, N);
  k_scatter<<<(E + 255) / 256, 256, 0, stream>>>(ei, ws + o_inv, row, csr, ws + o_w, E);
  k_h1f<<<nb, 256, 0, stream>>>(x, row, csr, ws + o_inv, W1, b1, H1b, ws + o_w, N);
  k_agg<<<(N + 3) / 4, 256, 0, stream>>>(row, csr, ws + o_inv, H1b, Zb, N);
  k_gemm2<<<Npad / 64, 256, 0, stream>>>(Zb, ws + o_w, W2t, b2, ws + o_v, N);
  k_head<<<1, 256, 0, stream>>>(ws + o_v, ws + o_gacc, W3, b3, Wp1, bp1, Wp2, bp2,
                                Wp3, bp3, (float*)d_out, N);
}

// Round 5
// 641.357 us; speedup vs baseline: 9.8434x; 1.1385x over previous
//
#include <hip/hip_runtime.h>
#include <hip/hip_bf16.h>
#include <hip/hip_fp16.h>
#include <cstdint>
#include <cstddef>

#define HID 256
#define EMBD 128
#define FIN 5

typedef __attribute__((ext_vector_type(8))) short bf16x8;
typedef __attribute__((ext_vector_type(4))) float f32x4;

__device__ __forceinline__ unsigned short f2bf(float f) {
  unsigned int u = __float_as_uint(f);
  u += 0x7FFFu + ((u >> 16) & 1u);   // RNE
  return (unsigned short)(u >> 16);
}
__device__ __forceinline__ float bflo(unsigned int u) { return __uint_as_float(u << 16); }
__device__ __forceinline__ float bfhi(unsigned int u) { return __uint_as_float(u & 0xFFFF0000u); }
__device__ __forceinline__ unsigned int pack2bf(float a, float b) {
  return ((unsigned int)f2bf(b) << 16) | (unsigned int)f2bf(a);
}
// fp8 e5m2 = top byte of fp16, manual RNE
__device__ __forceinline__ unsigned char f2bf8(float f) {
  unsigned short u = __half_as_ushort(__float2half(f));
  unsigned short r = u + 0x7Fu + ((u >> 8) & 1u);
  return (unsigned char)(r >> 8);
}
__device__ __forceinline__ float bf82f(unsigned int v) {
  return __half2float(__ushort_as_half((unsigned short)(v << 8)));
}
__device__ __forceinline__ unsigned int pk4fp8(float a, float b, float c, float d) {
  return (unsigned int)f2bf8(a) | ((unsigned int)f2bf8(b) << 8) |
         ((unsigned int)f2bf8(c) << 16) | ((unsigned int)f2bf8(d) << 24);
}
__device__ __forceinline__ void acc4u(float* a, unsigned int u) {
  a[0] += bf82f(u & 0xffu);
  a[1] += bf82f((u >> 8) & 0xffu);
  a[2] += bf82f((u >> 16) & 0xffu);
  a[3] += bf82f(u >> 24);
}

// ---------------- K_pre: deg count + W2 transpose/bf16 + gfeat sums (block-partitioned) ----
__global__ __launch_bounds__(256) void k_pre(const int* __restrict__ ei,
                                             const float* __restrict__ x,
                                             const float* __restrict__ W2,
                                             int* __restrict__ cnt,
                                             float* __restrict__ gacc,
                                             unsigned short* __restrict__ W2t,
                                             int E, int N, int Eb) {
  int b = blockIdx.x, t = threadIdx.x;
  if (b < Eb) {
    int e = b * 256 + t;
    if (e < E) atomicAdd(&cnt[ei[(size_t)E + e]], 1);
  } else if (b < Eb + HID) {
    int n = b - Eb;
    W2t[(size_t)n * HID + t] = f2bf(W2[(size_t)t * HID + n]);
  } else {
    int i = (b - Eb - HID) * 256 + t;
    float s2 = 0.f, s3 = 0.f, s4 = 0.f, c0 = 0.f, sl = 0.f, sm = 0.f;
    if (i < N) {
      float x0 = x[(size_t)i * 5 + 0];
      float x1 = x[(size_t)i * 5 + 1];
      float x2 = x[(size_t)i * 5 + 2];
      float x3 = x[(size_t)i * 5 + 3];
      float x4 = x[(size_t)i * 5 + 4];
      s2 = x2; s3 = x3; s4 = x4;
      if (x2 == 1.0f) { c0 = 1.f; sl = x0; sm = x1; }
    }
    #pragma unroll
    for (int off = 32; off > 0; off >>= 1) {
      s2 += __shfl_down(s2, off);
      s3 += __shfl_down(s3, off);
      s4 += __shfl_down(s4, off);
      c0 += __shfl_down(c0, off);
      sl += __shfl_down(sl, off);
      sm += __shfl_down(sm, off);
    }
    if ((t & 63) == 0) {
      unsafeAtomicAdd(&gacc[0], s2);
      unsafeAtomicAdd(&gacc[1], s3);
      unsafeAtomicAdd(&gacc[2], s4);
      unsafeAtomicAdd(&gacc[3], c0);
      unsafeAtomicAdd(&gacc[4], sl);
      unsafeAtomicAdd(&gacc[5], sm);
    }
  }
}

// ---------------- K_inv_scan: inv = rsqrt(cnt+1); block sums for scan ----------------
__global__ __launch_bounds__(256) void k_inv_scan(const int* __restrict__ cnt,
                                                  float* __restrict__ inv,
                                                  int* __restrict__ bsum, int N) {
  __shared__ int sh[256];
  int t = threadIdx.x;
  int i = blockIdx.x * 256 + t;
  int c = (i < N) ? cnt[i] : 0;
  if (i < N) inv[i] = rsqrtf((float)c + 1.0f);
  sh[t] = c;
  __syncthreads();
  for (int off = 128; off > 0; off >>= 1) {
    if (t < off) sh[t] += sh[t + off];
    __syncthreads();
  }
  if (t == 0) bsum[blockIdx.x] = sh[0];
}

__global__ __launch_bounds__(1024) void k_scan_b(int* __restrict__ bsum, int nb) {
  __shared__ int sh[1024];
  int t = threadIdx.x;
  sh[t] = (t < nb) ? bsum[t] : 0;
  __syncthreads();
  for (int off = 1; off < 1024; off <<= 1) {
    int v = (t >= off) ? sh[t - off] : 0;
    __syncthreads();
    sh[t] += v;
    __syncthreads();
  }
  if (t < nb) bsum[t] = (t > 0) ? sh[t - 1] : 0;  // exclusive
}

// ---------------- K_scan_xi: row = exclusive scan; xi = bf16(x*inv) ----------------
__global__ __launch_bounds__(256) void k_scan_xi(const int* __restrict__ cnt,
                                                 const int* __restrict__ bsum,
                                                 const float* __restrict__ x,
                                                 const float* __restrict__ inv,
                                                 int* __restrict__ row,
                                                 uint4* __restrict__ xi, int N) {
  __shared__ int sh[256];
  int t = threadIdx.x;
  int i = blockIdx.x * 256 + t;
  int v = (i < N) ? cnt[i] : 0;
  sh[t] = v;
  __syncthreads();
  for (int off = 1; off < 256; off <<= 1) {
    int u = (t >= off) ? sh[t - off] : 0;
    __syncthreads();
    sh[t] += u;
    __syncthreads();
  }
  if (i < N) {
    row[i] = bsum[blockIdx.x] + sh[t] - v;  // exclusive
    float iv = inv[i];
    const float* xp = x + (size_t)i * FIN;
    uint4 o;
    o.x = pack2bf(xp[0] * iv, xp[1] * iv);
    o.y = pack2bf(xp[2] * iv, xp[3] * iv);
    o.z = pack2bf(xp[4] * iv, 0.f);
    o.w = 0u;
    xi[i] = o;
  }
}

// ---------------- k_scatter: build csr_src; w_raw[src] += inv[dst] ----------------
// After this kernel, row[d] = end offset of node d (original row[d+1]).
__global__ __launch_bounds__(256) void k_scatter(const int* __restrict__ ei,
                                                 const float* __restrict__ inv,
                                                 int* __restrict__ row,
                                                 int* __restrict__ csr,
                                                 float* __restrict__ w, int E) {
  int e = blockIdx.x * 256 + threadIdx.x;
  if (e >= E) return;
  int s = ei[e];
  int d = ei[(size_t)E + e];
  int pos = atomicAdd(&row[d], 1);
  csr[pos] = s;
  unsafeAtomicAdd(&w[s], inv[d]);
}

// ---------------- K_h1f: thread-per-node xi gather; H1' = inv*relu(U@W1+b1) -> fp8 ------
__global__ __launch_bounds__(256) void k_h1f(const uint4* __restrict__ xi,
                                             const int* __restrict__ row,
                                             const int* __restrict__ csr,
                                             const float* __restrict__ inv,
                                             const float* __restrict__ W1,
                                             const float* __restrict__ b1,
                                             unsigned char* __restrict__ H1q,
                                             float* __restrict__ w, int N) {
  __shared__ float W1sh[FIN][HID];
  __shared__ float b1sh[HID];
  int t = threadIdx.x;
  #pragma unroll
  for (int k = 0; k < FIN; k++) W1sh[k][t] = W1[k * HID + t];
  b1sh[t] = b1[t];
  int n = blockIdx.x * 256 + t;
  float a0 = 0.f, a1 = 0.f, a2 = 0.f, a3 = 0.f, a4 = 0.f;
  float invd = 0.f;
  if (n < N) {
    invd = inv[n];
    int start = (n > 0) ? row[n - 1] : 0;
    int end = row[n];
    for (int e = start; e < end; e++) {
      uint4 vx = xi[csr[e]];
      a0 += bflo(vx.x); a1 += bfhi(vx.x);
      a2 += bflo(vx.y); a3 += bfhi(vx.y);
      a4 += bflo(vx.z);
    }
    uint4 vs = xi[n];
    a0 += bflo(vs.x); a1 += bfhi(vs.x);
    a2 += bflo(vs.y); a3 += bfhi(vs.y);
    a4 += bflo(vs.z);
    a0 *= invd; a1 *= invd; a2 *= invd; a3 *= invd; a4 *= invd;
    w[n] = invd * w[n] + invd * invd;  // finalize pooling weight
  }
  __syncthreads();
  if (n >= N) return;
  unsigned char* hrow = H1q + (size_t)n * HID;
  for (int c = 0; c < HID; c += 16) {
    float vv[16];
    #pragma unroll
    for (int j = 0; j < 16; j++) {
      float s = b1sh[c + j];
      s = fmaf(a0, W1sh[0][c + j], s);
      s = fmaf(a1, W1sh[1][c + j], s);
      s = fmaf(a2, W1sh[2][c + j], s);
      s = fmaf(a3, W1sh[3][c + j], s);
      s = fmaf(a4, W1sh[4][c + j], s);
      vv[j] = fmaxf(s, 0.f) * invd;   // H1' = inv * relu(...)
    }
    uint4 o;
    o.x = pk4fp8(vv[0], vv[1], vv[2], vv[3]);
    o.y = pk4fp8(vv[4], vv[5], vv[6], vv[7]);
    o.z = pk4fp8(vv[8], vv[9], vv[10], vv[11]);
    o.w = pk4fp8(vv[12], vv[13], vv[14], vv[15]);
    *(uint4*)(hrow + c) = o;
  }
}

// ---------------- K_agg: Z[d] = inv_d*(sum_s H1'[s] + H1'[d])  (fp8 gather -> bf16) ----
// wave per node; 4 quarters of 16 lanes each own one edge; lane covers 16 cols.
__global__ __launch_bounds__(256) void k_agg(const int* __restrict__ row,
                                             const int* __restrict__ csr,
                                             const float* __restrict__ inv,
                                             const unsigned char* __restrict__ H1q,
                                             unsigned short* __restrict__ Zb, int N) {
  int wv = threadIdx.x >> 6;
  int l = threadIdx.x & 63;
  int q = l >> 4;       // quarter: which edge in flight
  int sl = l & 15;      // col group: cols sl*16 .. sl*16+15
  int d = blockIdx.x * 4 + wv;
  float acc[16];
  #pragma unroll
  for (int j = 0; j < 16; j++) acc[j] = 0.f;
  if (d >= N) {
    if (l < 32) {  // zero pad rows for k_gemm2
      uint4 z = {0u, 0u, 0u, 0u};
      *(uint4*)(Zb + (size_t)d * HID + (l & 15) * 16 + (l >> 4) * 8) = z;
    }
    return;
  }
  float invd = inv[d];
  int start = (d > 0) ? row[d - 1] : 0;
  int end = row[d];
  int e = start + q;
  for (; e + 4 < end; e += 8) {
    uint4 r0 = *(const uint4*)(H1q + (size_t)csr[e] * HID + sl * 16);
    uint4 r1 = *(const uint4*)(H1q + (size_t)csr[e + 4] * HID + sl * 16);
    acc4u(acc + 0, r0.x); acc4u(acc + 4, r0.y);
    acc4u(acc + 8, r0.z); acc4u(acc + 12, r0.w);
    acc4u(acc + 0, r1.x); acc4u(acc + 4, r1.y);
    acc4u(acc + 8, r1.z); acc4u(acc + 12, r1.w);
  }
  for (; e < end; e += 4) {
    uint4 r0 = *(const uint4*)(H1q + (size_t)csr[e] * HID + sl * 16);
    acc4u(acc + 0, r0.x); acc4u(acc + 4, r0.y);
    acc4u(acc + 8, r0.z); acc4u(acc + 12, r0.w);
  }
  if (q == 0) {  // self-loop term, counted once
    uint4 rs = *(const uint4*)(H1q + (size_t)d * HID + sl * 16);
    acc4u(acc + 0, rs.x); acc4u(acc + 4, rs.y);
    acc4u(acc + 8, rs.z); acc4u(acc + 12, rs.w);
  }
  #pragma unroll
  for (int j = 0; j < 16; j++) {
    acc[j] += __shfl_xor(acc[j], 16);
    acc[j] += __shfl_xor(acc[j], 32);
  }
  if (l < 32) {
    int half = l >> 4;           // 0: cols +0..7, 1: cols +8..15
    int base = half * 8;
    int col0 = (l & 15) * 16 + half * 8;
    uint4 o;
    o.x = pack2bf(acc[base + 0] * invd, acc[base + 1] * invd);
    o.y = pack2bf(acc[base + 2] * invd, acc[base + 3] * invd);
    o.z = pack2bf(acc[base + 4] * invd, acc[base + 5] * invd);
    o.w = pack2bf(acc[base + 6] * invd, acc[base + 7] * invd);
    *(uint4*)(Zb + (size_t)d * HID + col0) = o;
  }
}

// ---------------- K_gemm2: MFMA H2 = relu(Z @ W2 + b2); v += H2^T w ----------------
__global__ __launch_bounds__(256) void k_gemm2(const unsigned short* __restrict__ Zb,
                                               const float* __restrict__ w,
                                               const unsigned short* __restrict__ W2t,
                                               const float* __restrict__ b2,
                                               float* __restrict__ v, int N) {
  __shared__ float vsh[4][HID];
  int t = threadIdx.x;
  int wv = t >> 6, l = t & 63;
  int lo = l & 15, hi = l >> 4;
  int row0 = blockIdx.x * 64 + wv * 16;

  bf16x8 a[8];
  const unsigned short* zrow = Zb + (size_t)(row0 + lo) * HID + hi * 8;
  #pragma unroll
  for (int kk = 0; kk < 8; kk++)
    a[kk] = *reinterpret_cast<const bf16x8*>(zrow + kk * 32);

  float w4[4];
  #pragma unroll
  for (int i = 0; i < 4; i++) {
    int gr = row0 + hi * 4 + i;
    w4[i] = (gr < N) ? w[gr] : 0.f;
  }

  #pragma unroll
  for (int ct = 0; ct < 16; ct += 2) {
    f32x4 acc0 = {0.f, 0.f, 0.f, 0.f};
    f32x4 acc1 = {0.f, 0.f, 0.f, 0.f};
    const unsigned short* w0 = W2t + (size_t)(ct * 16 + lo) * HID + hi * 8;
    const unsigned short* w1 = w0 + 16 * HID;
    #pragma unroll
    for (int kk = 0; kk < 8; kk++) {
      bf16x8 b0 = *reinterpret_cast<const bf16x8*>(w0 + kk * 32);
      bf16x8 b1v = *reinterpret_cast<const bf16x8*>(w1 + kk * 32);
      acc0 = __builtin_amdgcn_mfma_f32_16x16x32_bf16(a[kk], b0, acc0, 0, 0, 0);
      acc1 = __builtin_amdgcn_mfma_f32_16x16x32_bf16(a[kk], b1v, acc1, 0, 0, 0);
    }
    {
      float bc = b2[ct * 16 + lo];
      float p = 0.f;
      #pragma unroll
      for (int i = 0; i < 4; i++) p = fmaf(w4[i], fmaxf(acc0[i] + bc, 0.f), p);
      p += __shfl_xor(p, 16);
      p += __shfl_xor(p, 32);
      if (hi == 0) vsh[wv][ct * 16 + lo] = p;
    }
    {
      float bc = b2[(ct + 1) * 16 + lo];
      float p = 0.f;
      #pragma unroll
      for (int i = 0; i < 4; i++) p = fmaf(w4[i], fmaxf(acc1[i] + bc, 0.f), p);
      p += __shfl_xor(p, 16);
      p += __shfl_xor(p, 32);
      if (hi == 0) vsh[wv][(ct + 1) * 16 + lo] = p;
    }
  }
  __syncthreads();
  float s = vsh[0][t] + vsh[1][t] + vsh[2][t] + vsh[3][t];
  unsafeAtomicAdd(&v[t], s);
}

// ---------------- K_head: embedding, gfeat, MLP head, final transform ----------------
__global__ __launch_bounds__(256) void k_head(const float* __restrict__ v,
                                              const float* __restrict__ gacc,
                                              const float* __restrict__ W3,
                                              const float* __restrict__ b3,
                                              const float* __restrict__ Wp1,
                                              const float* __restrict__ bp1,
                                              const float* __restrict__ Wp2,
                                              const float* __restrict__ bp2,
                                              const float* __restrict__ Wp3,
                                              const float* __restrict__ bp3,
                                              float* __restrict__ out, int N) {
  __shared__ float vsh[HID];
  __shared__ float emb[EMBD + 7];
  __shared__ float h64[64];
  __shared__ float h32[32];
  __shared__ float val[4];
  int t = threadIdx.x;
  vsh[t] = v[t];
  __syncthreads();
  if (t < EMBD) {
    float a = 0.f;
    for (int c = 0; c < HID; c++) a = fmaf(vsh[c], W3[c * EMBD + t], a);
    emb[t] = a / (float)N + b3[t];
  } else if (t == EMBD) {
    emb[EMBD + 0] = gacc[0];
    emb[EMBD + 1] = gacc[1];
    emb[EMBD + 2] = gacc[2];
    emb[EMBD + 3] = gacc[1] + gacc[2];
    float cnt = gacc[3];
    emb[EMBD + 4] = cnt > 0.f ? gacc[4] / fmaxf(cnt, 1.f) : 0.f;
    emb[EMBD + 5] = cnt > 0.f ? gacc[5] / fmaxf(cnt, 1.f) : 0.f;
    emb[EMBD + 6] = 100.0f / 500.0f;  // T_norm
  }
  __syncthreads();
  if (t < 64) {
    float a = bp1[t];
    for (int k = 0; k < EMBD + 7; k++) a = fmaf(emb[k], Wp1[k * 64 + t], a);
    h64[t] = fmaxf(a, 0.f);
  }
  __syncthreads();
  if (t < 32) {
    float a = bp2[t];
    for (int k = 0; k < 64; k++) a = fmaf(h64[k], Wp2[k * 32 + t], a);
    h32[t] = fmaxf(a, 0.f);
  }
  __syncthreads();
  if (t < 4) {
    float a = bp3[t];
    for (int k = 0; k < 32; k++) a = fmaf(h32[k], Wp3[k * 4 + t], a);
    val[t] = a > 20.f ? a : log1pf(expf(a));  // softplus
  }
  __syncthreads();
  if (t == 0) {
    const float Tn = 100.0f / 500.0f;
    const float scale = 1.0f - 0.7f * Tn;
    float am = 1.0f + val[0] * scale;
    float aM = 1.0f + (val[0] + val[1] + 1.0f) * scale;
    float bm = 1.0f + val[2] * scale * 0.3f;
    float bM = bm + (val[3] + 0.1f) * scale * 0.3f;
    out[0] = am; out[1] = aM; out[2] = bm; out[3] = bM;
  }
  if (t < EMBD + 7) out[4 + t] = emb[t];
}

static inline size_t al4(size_t a) { return (a + 3) & ~(size_t)3; }

extern "C" void kernel_launch(void* const* d_in, const int* in_sizes, int n_in,
                              void* d_out, int out_size, void* d_ws, size_t ws_size,
                              hipStream_t stream) {
  const float* x = (const float*)d_in[0];
  const int* ei = (const int*)d_in[1];
  const float* W1 = (const float*)d_in[2];
  const float* b1 = (const float*)d_in[3];
  const float* W2 = (const float*)d_in[4];
  const float* b2 = (const float*)d_in[5];
  const float* W3 = (const float*)d_in[6];
  const float* b3 = (const float*)d_in[7];
  const float* Wp1 = (const float*)d_in[8];
  const float* bp1 = (const float*)d_in[9];
  const float* Wp2 = (const float*)d_in[10];
  const float* bp2 = (const float*)d_in[11];
  const float* Wp3 = (const float*)d_in[12];
  const float* bp3 = (const float*)d_in[13];

  int N = in_sizes[0] / FIN;
  int E = in_sizes[1] / 2;
  int Eb = (E + 255) / 256;
  int nb = (N + 255) / 256;
  int Npad = ((N + 63) / 64) * 64;

  float* ws = (float*)d_ws;
  size_t o_cnt = 0;                               // N ints
  size_t o_w   = al4(o_cnt + N);                  // N floats
  size_t o_gacc= al4(o_w + N);                    // 16
  size_t o_v   = o_gacc + 16;                     // 256
  size_t o_bs  = o_v + 256;                       // 1024 ints
  size_t zero_end = o_bs + 1024;
  size_t o_row = zero_end;                        // N+4 ints
  size_t o_csr = al4(o_row + N + 4);              // E ints
  size_t o_inv = al4(o_csr + E);                  // N floats
  size_t o_w2t = al4(o_inv + N);                  // 32768 (HID*HID bf16)
  size_t o_xi  = o_w2t + (size_t)HID * HID / 2;   // 4N (uint4/node)
  size_t o_H1q = o_xi + (size_t)N * 4;            // 64N (256 fp8/node)
  size_t o_Z   = o_H1q + (size_t)N * (HID / 4);   // 128*Npad (bf16)
  size_t total = o_Z + (size_t)Npad * (HID / 2);
  if (ws_size < total * sizeof(float)) {
    hipMemsetAsync(d_out, 0x42, (size_t)out_size * sizeof(float), stream);
    return;
  }

  int* cnt = (int*)(ws + o_cnt);
  int* bsum = (int*)(ws + o_bs);
  int* row = (int*)(ws + o_row);
  int* csr = (int*)(ws + o_csr);
  unsigned short* W2t = (unsigned short*)(ws + o_w2t);
  uint4* xi = (uint4*)(ws + o_xi);
  unsigned char* H1q = (unsigned char*)(ws + o_H1q);
  unsigned short* Zb = (unsigned short*)(ws + o_Z);

  hipMemsetAsync(ws, 0, zero_end * sizeof(float), stream);

  k_pre<<<Eb + HID + nb, 256, 0, stream>>>(ei, x, W2, cnt, ws + o_gacc, W2t, E, N, Eb);
  k_inv_scan<<<nb, 256, 0, stream>>>(cnt, ws + o_inv, bsum, N);
  k_scan_b<<<1, 1024, 0, stream>>>(bsum, nb);
  k_scan_xi<<<nb, 256, 0, stream>>>(cnt, bsum, x, ws + o_inv, row, xi, N);
  k_scatter<<<Eb, 256, 0, stream>>>(ei, ws + o_inv, row, csr, ws + o_w, E);
  k_h1f<<<nb, 256, 0, stream>>>(xi, row, csr, ws + o_inv, W1, b1, H1q, ws + o_w, N);
  k_agg<<<Npad / 4, 256, 0, stream>>>(row, csr, ws + o_inv, H1q, Zb, N);
  k_gemm2<<<Npad / 64, 256, 0, stream>>>(Zb, ws + o_w, W2t, b2, ws + o_v, N);
  k_head<<<1, 256, 0, stream>>>(ws + o_v, ws + o_gacc, W3, b3, Wp1, bp1, Wp2, bp2,
                                Wp3, bp3, (float*)d_out, N);
}

// Round 6
// 524.445 us; speedup vs baseline: 12.0377x; 1.2229x over previous
//
#include <hip/hip_runtime.h>
#include <hip/hip_bf16.h>
#include <hip/hip_fp16.h>
#include <cstdint>
#include <cstddef>

#define HID 256
#define EMBD 128
#define FIN 5
#define NBLK 256   // histogram/placement blocks

typedef __attribute__((ext_vector_type(8))) short bf16x8;
typedef __attribute__((ext_vector_type(4))) float f32x4;

__device__ __forceinline__ unsigned short f2bf(float f) {
  unsigned int u = __float_as_uint(f);
  u += 0x7FFFu + ((u >> 16) & 1u);   // RNE
  return (unsigned short)(u >> 16);
}
__device__ __forceinline__ float bflo(unsigned int u) { return __uint_as_float(u << 16); }
__device__ __forceinline__ float bfhi(unsigned int u) { return __uint_as_float(u & 0xFFFF0000u); }
__device__ __forceinline__ unsigned int pack2bf(float a, float b) {
  return ((unsigned int)f2bf(b) << 16) | (unsigned int)f2bf(a);
}
// fp8 e5m2 = top byte of fp16, manual RNE
__device__ __forceinline__ unsigned char f2bf8(float f) {
  unsigned short u = __half_as_ushort(__float2half(f));
  unsigned short r = u + 0x7Fu + ((u >> 8) & 1u);
  return (unsigned char)(r >> 8);
}
__device__ __forceinline__ float bf82f(unsigned int v) {
  return __half2float(__ushort_as_half((unsigned short)(v << 8)));
}
__device__ __forceinline__ unsigned int pk4fp8(float a, float b, float c, float d) {
  return (unsigned int)f2bf8(a) | ((unsigned int)f2bf8(b) << 8) |
         ((unsigned int)f2bf8(c) << 16) | ((unsigned int)f2bf8(d) << 24);
}
__device__ __forceinline__ void acc4u(float* a, unsigned int u) {
  a[0] += bf82f(u & 0xffu);
  a[1] += bf82f((u >> 8) & 0xffu);
  a[2] += bf82f((u >> 16) & 0xffu);
  a[3] += bf82f(u >> 24);
}

// ---------------- K1: dual LDS histogram (dst & src buckets) + W2 transpose ----------------
__global__ __launch_bounds__(256) void k_hist(const int* __restrict__ ei,
                                              const float* __restrict__ W2,
                                              int* __restrict__ h2dD,
                                              int* __restrict__ h2dS,
                                              unsigned short* __restrict__ W2t,
                                              int E, int NB, int per) {
  int b = blockIdx.x, t = threadIdx.x;
  if (b >= NBLK) {  // W2 transpose blocks
    int n = b - NBLK;
    W2t[(size_t)n * HID + t] = f2bf(W2[(size_t)t * HID + n]);
    return;
  }
  extern __shared__ int hsh[];  // 2*NB ints
  int* hD = hsh;
  int* hS = hsh + NB;
  for (int j = t; j < 2 * NB; j += 256) hsh[j] = 0;
  __syncthreads();
  int lo = b * per, hi = min(E, lo + per);
  for (int e = lo + t; e < hi; e += 256) {
    int s = ei[e];
    int d = ei[(size_t)E + e];
    atomicAdd(&hD[d >> 6], 1);
    atomicAdd(&hS[s >> 6], 1);
  }
  __syncthreads();
  for (int j = t; j < NB; j += 256) {
    h2dD[(size_t)b * NB + j] = hD[j];
    h2dS[(size_t)b * NB + j] = hS[j];
  }
}

// ---------------- K2: per-bucket exclusive scan over blocks ----------------
__global__ __launch_bounds__(256) void k_bred(int* __restrict__ h2dD,
                                              int* __restrict__ h2dS,
                                              int* __restrict__ btot, int NB) {
  __shared__ int sh[NBLK];
  int bb = blockIdx.x, t = threadIdx.x;
  int* arr = (bb < NB) ? h2dD : h2dS;
  int b = (bb < NB) ? bb : bb - NB;
  int v = arr[(size_t)t * NB + b];
  sh[t] = v;
  __syncthreads();
  for (int off = 1; off < 256; off <<= 1) {
    int u = (t >= off) ? sh[t - off] : 0;
    __syncthreads();
    sh[t] += u;
    __syncthreads();
  }
  arr[(size_t)t * NB + b] = sh[t] - v;   // exclusive over blocks
  if (t == 255) btot[bb] = sh[255];
}

// ---------------- K3: scan bucket totals -> bucket starts ----------------
__global__ __launch_bounds__(256) void k_bscan(const int* __restrict__ btot,
                                               int* __restrict__ bsD,
                                               int* __restrict__ bsS,
                                               int* __restrict__ row,
                                               int E, int NB, int N) {
  __shared__ int sh[256];
  __shared__ int carrysh;
  int t = threadIdx.x;
  for (int which = 0; which < 2; which++) {
    const int* src = btot + (size_t)which * NB;
    int* dst = which ? bsS : bsD;
    if (t == 0) carrysh = 0;
    __syncthreads();
    int nch = (NB + 255) / 256;
    for (int c = 0; c < nch; c++) {
      int i = c * 256 + t;
      int v = (i < NB) ? src[i] : 0;
      sh[t] = v;
      __syncthreads();
      for (int off = 1; off < 256; off <<= 1) {
        int u = (t >= off) ? sh[t - off] : 0;
        __syncthreads();
        sh[t] += u;
        __syncthreads();
      }
      int carry = carrysh;
      if (i < NB) dst[i] = carry + sh[t] - v;
      __syncthreads();
      if (t == 255) carrysh = carry + sh[255];
      __syncthreads();
    }
    if (t == 0) dst[NB] = E;
    __syncthreads();
  }
  if (t == 0) row[N] = E;
}

// ---------------- K4: placement into bucket-sorted edge arrays (LDS counters only) --------
__global__ __launch_bounds__(256) void k_place(const int* __restrict__ ei,
                                               const int* __restrict__ h2dD,
                                               const int* __restrict__ h2dS,
                                               const int* __restrict__ bsD,
                                               const int* __restrict__ bsS,
                                               unsigned int* __restrict__ seD,
                                               unsigned int* __restrict__ seS,
                                               int E, int NB, int per) {
  extern __shared__ int osh[];  // 2*NB ints
  int* oD = osh;
  int* oS = osh + NB;
  int b = blockIdx.x, t = threadIdx.x;
  for (int j = t; j < NB; j += 256) {
    oD[j] = bsD[j] + h2dD[(size_t)b * NB + j];
    oS[j] = bsS[j] + h2dS[(size_t)b * NB + j];
  }
  __syncthreads();
  int lo = b * per, hi = min(E, lo + per);
  for (int e = lo + t; e < hi; e += 256) {
    int s = ei[e];
    int d = ei[(size_t)E + e];
    int pd = atomicAdd(&oD[d >> 6], 1);
    seD[pd] = (unsigned int)s | ((unsigned int)(d & 63) << 20);
    int ps = atomicAdd(&oS[s >> 6], 1);
    seS[ps] = (unsigned int)d | ((unsigned int)(s & 63) << 20);
  }
}

// ---------------- K5: per-bucket dst CSR finalize: csr, row, deg ----------------
__global__ __launch_bounds__(256) void k_csrd(const unsigned int* __restrict__ seD,
                                              const int* __restrict__ bsD,
                                              int* __restrict__ csr,
                                              int* __restrict__ row,
                                              int* __restrict__ deg, int NB, int N) {
  __shared__ int cnt[64], sc[64], ofs[64];
  int b = blockIdx.x, t = threadIdx.x;
  if (t < 64) cnt[t] = 0;
  __syncthreads();
  int lo = bsD[b], hi = bsD[b + 1];
  for (int k = lo + t; k < hi; k += 256) atomicAdd(&cnt[seD[k] >> 20], 1);
  __syncthreads();
  if (t < 64) sc[t] = cnt[t];
  __syncthreads();
  for (int off = 1; off < 64; off <<= 1) {
    int u = (t < 64 && t >= off) ? sc[t - off] : 0;
    __syncthreads();
    if (t < 64) sc[t] += u;
    __syncthreads();
  }
  if (t < 64) {
    int ex = sc[t] - cnt[t];
    ofs[t] = ex;
    int node = b * 64 + t;
    if (node < N) { row[node] = lo + ex; deg[node] = cnt[t]; }
  }
  __syncthreads();
  for (int k = lo + t; k < hi; k += 256) {
    unsigned int v = seD[k];
    int p = atomicAdd(&ofs[v >> 20], 1);
    csr[lo + p] = (int)(v & 0xFFFFFu);
  }
}

// ---------------- K6: inv = rsqrt(deg+1); xi = bf16(x*inv); gfeat sums ----------------
__global__ __launch_bounds__(256) void k_inv(const int* __restrict__ deg,
                                             const float* __restrict__ x,
                                             float* __restrict__ inv,
                                             uint4* __restrict__ xi,
                                             float* __restrict__ gacc, int N) {
  int i = blockIdx.x * 256 + threadIdx.x;
  float s2 = 0.f, s3 = 0.f, s4 = 0.f, c0 = 0.f, sl = 0.f, sm = 0.f;
  if (i < N) {
    float iv = rsqrtf((float)deg[i] + 1.0f);
    inv[i] = iv;
    float x0 = x[(size_t)i * 5 + 0];
    float x1 = x[(size_t)i * 5 + 1];
    float x2 = x[(size_t)i * 5 + 2];
    float x3 = x[(size_t)i * 5 + 3];
    float x4 = x[(size_t)i * 5 + 4];
    uint4 o;
    o.x = pack2bf(x0 * iv, x1 * iv);
    o.y = pack2bf(x2 * iv, x3 * iv);
    o.z = pack2bf(x4 * iv, 0.f);
    o.w = 0u;
    xi[i] = o;
    s2 = x2; s3 = x3; s4 = x4;
    if (x2 == 1.0f) { c0 = 1.f; sl = x0; sm = x1; }
  }
  #pragma unroll
  for (int off = 32; off > 0; off >>= 1) {
    s2 += __shfl_down(s2, off);
    s3 += __shfl_down(s3, off);
    s4 += __shfl_down(s4, off);
    c0 += __shfl_down(c0, off);
    sl += __shfl_down(sl, off);
    sm += __shfl_down(sm, off);
  }
  if ((threadIdx.x & 63) == 0) {
    unsafeAtomicAdd(&gacc[0], s2);
    unsafeAtomicAdd(&gacc[1], s3);
    unsafeAtomicAdd(&gacc[2], s4);
    unsafeAtomicAdd(&gacc[3], c0);
    unsafeAtomicAdd(&gacc[4], sl);
    unsafeAtomicAdd(&gacc[5], sm);
  }
}

// ---------------- K7: per-bucket src pass: w_raw[s] = sum inv[dst] (LDS only) ----------
__global__ __launch_bounds__(256) void k_csrs(const unsigned int* __restrict__ seS,
                                              const int* __restrict__ bsS,
                                              const float* __restrict__ inv,
                                              float* __restrict__ w, int NB, int N) {
  __shared__ float wa[64];
  int b = blockIdx.x, t = threadIdx.x;
  if (t < 64) wa[t] = 0.f;
  __syncthreads();
  int lo = bsS[b], hi = bsS[b + 1];
  for (int k = lo + t; k < hi; k += 256) {
    unsigned int v = seS[k];
    atomicAdd(&wa[v >> 20], inv[v & 0xFFFFFu]);
  }
  __syncthreads();
  if (t < 64) {
    int node = b * 64 + t;
    if (node < N) w[node] = wa[t];
  }
}

// ---------------- K8: thread-per-node xi gather; H1' = inv*relu(U@W1+b1) -> fp8 --------
__global__ __launch_bounds__(256) void k_h1f(const uint4* __restrict__ xi,
                                             const int* __restrict__ row,
                                             const int* __restrict__ csr,
                                             const float* __restrict__ inv,
                                             const float* __restrict__ W1,
                                             const float* __restrict__ b1,
                                             unsigned char* __restrict__ H1q,
                                             float* __restrict__ w, int N) {
  __shared__ float W1sh[FIN][HID];
  __shared__ float b1sh[HID];
  int t = threadIdx.x;
  #pragma unroll
  for (int k = 0; k < FIN; k++) W1sh[k][t] = W1[k * HID + t];
  b1sh[t] = b1[t];
  int n = blockIdx.x * 256 + t;
  float a0 = 0.f, a1 = 0.f, a2 = 0.f, a3 = 0.f, a4 = 0.f;
  float invd = 0.f;
  if (n < N) {
    invd = inv[n];
    int start = row[n], end = row[n + 1];
    for (int e = start; e < end; e++) {
      uint4 vx = xi[csr[e]];
      a0 += bflo(vx.x); a1 += bfhi(vx.x);
      a2 += bflo(vx.y); a3 += bfhi(vx.y);
      a4 += bflo(vx.z);
    }
    uint4 vs = xi[n];
    a0 += bflo(vs.x); a1 += bfhi(vs.x);
    a2 += bflo(vs.y); a3 += bfhi(vs.y);
    a4 += bflo(vs.z);
    a0 *= invd; a1 *= invd; a2 *= invd; a3 *= invd; a4 *= invd;
    w[n] = invd * w[n] + invd * invd;  // finalize pooling weight
  }
  __syncthreads();
  if (n >= N) return;
  unsigned char* hrow = H1q + (size_t)n * HID;
  for (int c = 0; c < HID; c += 16) {
    float vv[16];
    #pragma unroll
    for (int j = 0; j < 16; j++) {
      float s = b1sh[c + j];
      s = fmaf(a0, W1sh[0][c + j], s);
      s = fmaf(a1, W1sh[1][c + j], s);
      s = fmaf(a2, W1sh[2][c + j], s);
      s = fmaf(a3, W1sh[3][c + j], s);
      s = fmaf(a4, W1sh[4][c + j], s);
      vv[j] = fmaxf(s, 0.f) * invd;   // H1' = inv * relu(...)
    }
    uint4 o;
    o.x = pk4fp8(vv[0], vv[1], vv[2], vv[3]);
    o.y = pk4fp8(vv[4], vv[5], vv[6], vv[7]);
    o.z = pk4fp8(vv[8], vv[9], vv[10], vv[11]);
    o.w = pk4fp8(vv[12], vv[13], vv[14], vv[15]);
    *(uint4*)(hrow + c) = o;
  }
}

// ---------------- K9: Z[d] = inv_d*(sum_s H1'[s] + H1'[d])  (fp8 gather -> bf16) --------
__global__ __launch_bounds__(256) void k_agg(const int* __restrict__ row,
                                             const int* __restrict__ csr,
                                             const float* __restrict__ inv,
                                             const unsigned char* __restrict__ H1q,
                                             unsigned short* __restrict__ Zb, int N) {
  int wv = threadIdx.x >> 6;
  int l = threadIdx.x & 63;
  int q = l >> 4;       // quarter: which edge in flight
  int sl = l & 15;      // col group: cols sl*16 .. sl*16+15
  int d = blockIdx.x * 4 + wv;
  float acc[16];
  #pragma unroll
  for (int j = 0; j < 16; j++) acc[j] = 0.f;
  if (d >= N) {
    if (l < 32) {  // zero pad rows for k_gemm2
      uint4 z = {0u, 0u, 0u, 0u};
      *(uint4*)(Zb + (size_t)d * HID + (l & 15) * 16 + (l >> 4) * 8) = z;
    }
    return;
  }
  float invd = inv[d];
  int start = row[d], end = row[d + 1];
  int e = start + q;
  for (; e + 4 < end; e += 8) {
    uint4 r0 = *(const uint4*)(H1q + (size_t)csr[e] * HID + sl * 16);
    uint4 r1 = *(const uint4*)(H1q + (size_t)csr[e + 4] * HID + sl * 16);
    acc4u(acc + 0, r0.x); acc4u(acc + 4, r0.y);
    acc4u(acc + 8, r0.z); acc4u(acc + 12, r0.w);
    acc4u(acc + 0, r1.x); acc4u(acc + 4, r1.y);
    acc4u(acc + 8, r1.z); acc4u(acc + 12, r1.w);
  }
  for (; e < end; e += 4) {
    uint4 r0 = *(const uint4*)(H1q + (size_t)csr[e] * HID + sl * 16);
    acc4u(acc + 0, r0.x); acc4u(acc + 4, r0.y);
    acc4u(acc + 8, r0.z); acc4u(acc + 12, r0.w);
  }
  if (q == 0) {  // self-loop term
    uint4 rs = *(const uint4*)(H1q + (size_t)d * HID + sl * 16);
    acc4u(acc + 0, rs.x); acc4u(acc + 4, rs.y);
    acc4u(acc + 8, rs.z); acc4u(acc + 12, rs.w);
  }
  #pragma unroll
  for (int j = 0; j < 16; j++) {
    acc[j] += __shfl_xor(acc[j], 16);
    acc[j] += __shfl_xor(acc[j], 32);
  }
  if (l < 32) {
    int half = l >> 4;
    int base = half * 8;
    int col0 = (l & 15) * 16 + half * 8;
    uint4 o;
    o.x = pack2bf(acc[base + 0] * invd, acc[base + 1] * invd);
    o.y = pack2bf(acc[base + 2] * invd, acc[base + 3] * invd);
    o.z = pack2bf(acc[base + 4] * invd, acc[base + 5] * invd);
    o.w = pack2bf(acc[base + 6] * invd, acc[base + 7] * invd);
    *(uint4*)(Zb + (size_t)d * HID + col0) = o;
  }
}

// ---------------- K10: MFMA GEMM: H2 = relu(Z @ W2 + b2); v += H2^T w ----------------
__global__ __launch_bounds__(256) void k_gemm2(const unsigned short* __restrict__ Zb,
                                               const float* __restrict__ w,
                                               const unsigned short* __restrict__ W2t,
                                               const float* __restrict__ b2,
                                               float* __restrict__ v, int N) {
  __shared__ float vsh[4][HID];
  int t = threadIdx.x;
  int wv = t >> 6, l = t & 63;
  int lo = l & 15, hi = l >> 4;
  int row0 = blockIdx.x * 64 + wv * 16;

  bf16x8 a[8];
  const unsigned short* zrow = Zb + (size_t)(row0 + lo) * HID + hi * 8;
  #pragma unroll
  for (int kk = 0; kk < 8; kk++)
    a[kk] = *reinterpret_cast<const bf16x8*>(zrow + kk * 32);

  float w4[4];
  #pragma unroll
  for (int i = 0; i < 4; i++) {
    int gr = row0 + hi * 4 + i;
    w4[i] = (gr < N) ? w[gr] : 0.f;
  }

  #pragma unroll
  for (int ct = 0; ct < 16; ct += 2) {
    f32x4 acc0 = {0.f, 0.f, 0.f, 0.f};
    f32x4 acc1 = {0.f, 0.f, 0.f, 0.f};
    const unsigned short* w0 = W2t + (size_t)(ct * 16 + lo) * HID + hi * 8;
    const unsigned short* w1 = w0 + 16 * HID;
    #pragma unroll
    for (int kk = 0; kk < 8; kk++) {
      bf16x8 b0 = *reinterpret_cast<const bf16x8*>(w0 + kk * 32);
      bf16x8 b1v = *reinterpret_cast<const bf16x8*>(w1 + kk * 32);
      acc0 = __builtin_amdgcn_mfma_f32_16x16x32_bf16(a[kk], b0, acc0, 0, 0, 0);
      acc1 = __builtin_amdgcn_mfma_f32_16x16x32_bf16(a[kk], b1v, acc1, 0, 0, 0);
    }
    {
      float bc = b2[ct * 16 + lo];
      float p = 0.f;
      #pragma unroll
      for (int i = 0; i < 4; i++) p = fmaf(w4[i], fmaxf(acc0[i] + bc, 0.f), p);
      p += __shfl_xor(p, 16);
      p += __shfl_xor(p, 32);
      if (hi == 0) vsh[wv][ct * 16 + lo] = p;
    }
    {
      float bc = b2[(ct + 1) * 16 + lo];
      float p = 0.f;
      #pragma unroll
      for (int i = 0; i < 4; i++) p = fmaf(w4[i], fmaxf(acc1[i] + bc, 0.f), p);
      p += __shfl_xor(p, 16);
      p += __shfl_xor(p, 32);
      if (hi == 0) vsh[wv][(ct + 1) * 16 + lo] = p;
    }
  }
  __syncthreads();
  float s = vsh[0][t] + vsh[1][t] + vsh[2][t] + vsh[3][t];
  unsafeAtomicAdd(&v[t], s);
}

// ---------------- K11: embedding, gfeat, MLP head, final transform ----------------
__global__ __launch_bounds__(256) void k_head(const float* __restrict__ v,
                                              const float* __restrict__ gacc,
                                              const float* __restrict__ W3,
                                              const float* __restrict__ b3,
                                              const float* __restrict__ Wp1,
                                              const float* __restrict__ bp1,
                                              const float* __restrict__ Wp2,
                                              const float* __restrict__ bp2,
                                              const float* __restrict__ Wp3,
                                              const float* __restrict__ bp3,
                                              float* __restrict__ out, int N) {
  __shared__ float vsh[HID];
  __shared__ float emb[EMBD + 7];
  __shared__ float h64[64];
  __shared__ float h32[32];
  __shared__ float val[4];
  int t = threadIdx.x;
  vsh[t] = v[t];
  __syncthreads();
  if (t < EMBD) {
    float a = 0.f;
    for (int c = 0; c < HID; c++) a = fmaf(vsh[c], W3[c * EMBD + t], a);
    emb[t] = a / (float)N + b3[t];
  } else if (t == EMBD) {
    emb[EMBD + 0] = gacc[0];
    emb[EMBD + 1] = gacc[1];
    emb[EMBD + 2] = gacc[2];
    emb[EMBD + 3] = gacc[1] + gacc[2];
    float cnt = gacc[3];
    emb[EMBD + 4] = cnt > 0.f ? gacc[4] / fmaxf(cnt, 1.f) : 0.f;
    emb[EMBD + 5] = cnt > 0.f ? gacc[5] / fmaxf(cnt, 1.f) : 0.f;
    emb[EMBD + 6] = 100.0f / 500.0f;  // T_norm
  }
  __syncthreads();
  if (t < 64) {
    float a = bp1[t];
    for (int k = 0; k < EMBD + 7; k++) a = fmaf(emb[k], Wp1[k * 64 + t], a);
    h64[t] = fmaxf(a, 0.f);
  }
  __syncthreads();
  if (t < 32) {
    float a = bp2[t];
    for (int k = 0; k < 64; k++) a = fmaf(h64[k], Wp2[k * 32 + t], a);
    h32[t] = fmaxf(a, 0.f);
  }
  __syncthreads();
  if (t < 4) {
    float a = bp3[t];
    for (int k = 0; k < 32; k++) a = fmaf(h32[k], Wp3[k * 4 + t], a);
    val[t] = a > 20.f ? a : log1pf(expf(a));  // softplus
  }
  __syncthreads();
  if (t == 0) {
    const float Tn = 100.0f / 500.0f;
    const float scale = 1.0f - 0.7f * Tn;
    float am = 1.0f + val[0] * scale;
    float aM = 1.0f + (val[0] + val[1] + 1.0f) * scale;
    float bm = 1.0f + val[2] * scale * 0.3f;
    float bM = bm + (val[3] + 0.1f) * scale * 0.3f;
    out[0] = am; out[1] = aM; out[2] = bm; out[3] = bM;
  }
  if (t < EMBD + 7) out[4 + t] = emb[t];
}

static inline size_t al4(size_t a) { return (a + 3) & ~(size_t)3; }

extern "C" void kernel_launch(void* const* d_in, const int* in_sizes, int n_in,
                              void* d_out, int out_size, void* d_ws, size_t ws_size,
                              hipStream_t stream) {
  const float* x = (const float*)d_in[0];
  const int* ei = (const int*)d_in[1];
  const float* W1 = (const float*)d_in[2];
  const float* b1 = (const float*)d_in[3];
  const float* W2 = (const float*)d_in[4];
  const float* b2 = (const float*)d_in[5];
  const float* W3 = (const float*)d_in[6];
  const float* b3 = (const float*)d_in[7];
  const float* Wp1 = (const float*)d_in[8];
  const float* bp1 = (const float*)d_in[9];
  const float* Wp2 = (const float*)d_in[10];
  const float* bp2 = (const float*)d_in[11];
  const float* Wp3 = (const float*)d_in[12];
  const float* bp3 = (const float*)d_in[13];

  int N = in_sizes[0] / FIN;
  int E = in_sizes[1] / 2;
  int nb = (N + 255) / 256;
  int Npad = ((N + 63) / 64) * 64;
  int NB = (N + 63) / 64;             // buckets of 64 nodes
  int per = (E + NBLK - 1) / NBLK;    // edges per hist/place block
  size_t shbytes = (size_t)2 * NB * sizeof(int);

  float* ws = (float*)d_ws;
  size_t o_gacc = 0;                                 // 16
  size_t o_v    = 16;                                // 256
  size_t zero_end = 272;
  size_t o_deg  = zero_end;                          // N ints
  size_t o_row  = al4(o_deg + N);                    // N+1 ints
  size_t o_inv  = al4(o_row + N + 1);                // N floats
  size_t o_w    = al4(o_inv + N);                    // N floats
  size_t o_xi   = al4(o_w + N);                      // 4N (uint4/node)
  size_t o_w2t  = o_xi + (size_t)N * 4;              // 32768 (HID*HID bf16)
  size_t o_h2dD = o_w2t + (size_t)HID * HID / 2;     // NBLK*NB ints
  size_t o_h2dS = o_h2dD + (size_t)NBLK * NB;        // NBLK*NB ints
  size_t o_btot = o_h2dS + (size_t)NBLK * NB;        // 2*NB
  size_t o_bsD  = o_btot + (size_t)2 * NB;           // NB+1
  size_t o_bsS  = o_bsD + NB + 1;                    // NB+1
  size_t o_seD  = al4(o_bsS + NB + 1);               // E uints
  size_t o_seS  = o_seD + E;                         // E uints
  size_t o_csr  = o_seS + E;                         // E ints
  size_t o_H1q  = al4(o_csr + E);                    // 64N (256 fp8/node)
  size_t o_Z    = o_H1q + (size_t)N * (HID / 4);     // 128*Npad (bf16)
  size_t total  = o_Z + (size_t)Npad * (HID / 2);
  if (ws_size < total * sizeof(float)) {
    hipMemsetAsync(d_out, 0x42, (size_t)out_size * sizeof(float), stream);
    return;
  }

  int* deg = (int*)(ws + o_deg);
  int* row = (int*)(ws + o_row);
  int* h2dD = (int*)(ws + o_h2dD);
  int* h2dS = (int*)(ws + o_h2dS);
  int* btot = (int*)(ws + o_btot);
  int* bsD = (int*)(ws + o_bsD);
  int* bsS = (int*)(ws + o_bsS);
  unsigned int* seD = (unsigned int*)(ws + o_seD);
  unsigned int* seS = (unsigned int*)(ws + o_seS);
  int* csr = (int*)(ws + o_csr);
  unsigned short* W2t = (unsigned short*)(ws + o_w2t);
  uint4* xi = (uint4*)(ws + o_xi);
  unsigned char* H1q = (unsigned char*)(ws + o_H1q);
  unsigned short* Zb = (unsigned short*)(ws + o_Z);

  hipMemsetAsync(ws, 0, zero_end * sizeof(float), stream);

  k_hist<<<NBLK + HID, 256, shbytes, stream>>>(ei, W2, h2dD, h2dS, W2t, E, NB, per);
  k_bred<<<2 * NB, 256, 0, stream>>>(h2dD, h2dS, btot, NB);
  k_bscan<<<1, 256, 0, stream>>>(btot, bsD, bsS, row, E, NB, N);
  k_place<<<NBLK, 256, shbytes, stream>>>(ei, h2dD, h2dS, bsD, bsS, seD, seS, E, NB, per);
  k_csrd<<<NB, 256, 0, stream>>>(seD, bsD, csr, row, deg, NB, N);
  k_inv<<<nb, 256, 0, stream>>>(deg, x, ws + o_inv, xi, ws + o_gacc, N);
  k_csrs<<<NB, 256, 0, stream>>>(seS, bsS, ws + o_inv, ws + o_w, NB, N);
  k_h1f<<<nb, 256, 0, stream>>>(xi, row, csr, ws + o_inv, W1, b1, H1q, ws + o_w, N);
  k_agg<<<Npad / 4, 256, 0, stream>>>(row, csr, ws + o_inv, H1q, Zb, N);
  k_gemm2<<<Npad / 64, 256, 0, stream>>>(Zb, ws + o_w, W2t, b2, ws + o_v, N);
  k_head<<<1, 256, 0, stream>>>(ws + o_v, ws + o_gacc, W3, b3, Wp1, bp1, Wp2, bp2,
                                Wp3, bp3, (float*)d_out, N);
}

// Round 7
// 519.895 us; speedup vs baseline: 12.1431x; 1.0088x over previous
//
#include <hip/hip_runtime.h>
#include <hip/hip_bf16.h>
#include <hip/hip_fp16.h>
#include <cstdint>
#include <cstddef>

#define HID 256
#define EMBD 128
#define FIN 5
#define NBLK 256   // histogram/placement blocks

typedef __attribute__((ext_vector_type(8))) short bf16x8;
typedef __attribute__((ext_vector_type(4))) float f32x4;

__device__ __forceinline__ unsigned short f2bf(float f) {
  unsigned int u = __float_as_uint(f);
  u += 0x7FFFu + ((u >> 16) & 1u);   // RNE
  return (unsigned short)(u >> 16);
}
__device__ __forceinline__ float bflo(unsigned int u) { return __uint_as_float(u << 16); }
__device__ __forceinline__ float bfhi(unsigned int u) { return __uint_as_float(u & 0xFFFF0000u); }
__device__ __forceinline__ unsigned int pack2bf(float a, float b) {
  return ((unsigned int)f2bf(b) << 16) | (unsigned int)f2bf(a);
}
// fp8 e5m2 = top byte of fp16, manual RNE
__device__ __forceinline__ unsigned char f2bf8(float f) {
  unsigned short u = __half_as_ushort(__float2half(f));
  unsigned short r = u + 0x7Fu + ((u >> 8) & 1u);
  return (unsigned char)(r >> 8);
}
__device__ __forceinline__ float bf82f(unsigned int v) {
  return __half2float(__ushort_as_half((unsigned short)(v << 8)));
}
__device__ __forceinline__ unsigned int pk4fp8(float a, float b, float c, float d) {
  return (unsigned int)f2bf8(a) | ((unsigned int)f2bf8(b) << 8) |
         ((unsigned int)f2bf8(c) << 16) | ((unsigned int)f2bf8(d) << 24);
}
__device__ __forceinline__ void acc4u(float* a, unsigned int u) {
  a[0] += bf82f(u & 0xffu);
  a[1] += bf82f((u >> 8) & 0xffu);
  a[2] += bf82f((u >> 16) & 0xffu);
  a[3] += bf82f(u >> 24);
}

// ---------------- K1: dual LDS histogram (dst & src buckets) + W2 -> fragment order ------
// W2f fragment order: B-frag for col-tile ct, k-block kb, lane (hi*16+lo), elem j:
//   W2f[(((ct*8+kb)*64 + hi*16+lo))*8 + j] = bf16(W2[kb*32+hi*8+j][ct*16+lo])
__global__ __launch_bounds__(256) void k_hist(const int* __restrict__ ei,
                                              const float* __restrict__ W2,
                                              int* __restrict__ h2dD,
                                              int* __restrict__ h2dS,
                                              unsigned short* __restrict__ W2f,
                                              int E, int NB, int per) {
  int b = blockIdx.x, t = threadIdx.x;
  if (b >= NBLK) {  // W2 pack blocks: b-NBLK = n (col), t = k
    int n = b - NBLK;
    size_t off = ((((size_t)(n >> 4) * 8 + (t >> 5)) * 64) +
                  (size_t)((t >> 3) & 3) * 16 + (n & 15)) * 8 + (t & 7);
    W2f[off] = f2bf(W2[(size_t)t * HID + n]);
    return;
  }
  extern __shared__ int hsh[];  // 2*NB ints
  int* hD = hsh;
  int* hS = hsh + NB;
  for (int j = t; j < 2 * NB; j += 256) hsh[j] = 0;
  __syncthreads();
  int lo = b * per, hi = min(E, lo + per);
  for (int e = lo + t; e < hi; e += 256) {
    int s = ei[e];
    int d = ei[(size_t)E + e];
    atomicAdd(&hD[d >> 6], 1);
    atomicAdd(&hS[s >> 6], 1);
  }
  __syncthreads();
  for (int j = t; j < NB; j += 256) {
    h2dD[(size_t)b * NB + j] = hD[j];
    h2dS[(size_t)b * NB + j] = hS[j];
  }
}

// ---------------- K2: per-bucket exclusive scan over blocks ----------------
__global__ __launch_bounds__(256) void k_bred(int* __restrict__ h2dD,
                                              int* __restrict__ h2dS,
                                              int* __restrict__ btot, int NB) {
  __shared__ int sh[NBLK];
  int bb = blockIdx.x, t = threadIdx.x;
  int* arr = (bb < NB) ? h2dD : h2dS;
  int b = (bb < NB) ? bb : bb - NB;
  int v = arr[(size_t)t * NB + b];
  sh[t] = v;
  __syncthreads();
  for (int off = 1; off < 256; off <<= 1) {
    int u = (t >= off) ? sh[t - off] : 0;
    __syncthreads();
    sh[t] += u;
    __syncthreads();
  }
  arr[(size_t)t * NB + b] = sh[t] - v;   // exclusive over blocks
  if (t == 255) btot[bb] = sh[255];
}

// ---------------- K3: scan bucket totals -> bucket starts ----------------
__global__ __launch_bounds__(256) void k_bscan(const int* __restrict__ btot,
                                               int* __restrict__ bsD,
                                               int* __restrict__ bsS,
                                               int* __restrict__ row,
                                               int E, int NB, int N) {
  __shared__ int sh[256];
  __shared__ int carrysh;
  int t = threadIdx.x;
  for (int which = 0; which < 2; which++) {
    const int* src = btot + (size_t)which * NB;
    int* dst = which ? bsS : bsD;
    if (t == 0) carrysh = 0;
    __syncthreads();
    int nch = (NB + 255) / 256;
    for (int c = 0; c < nch; c++) {
      int i = c * 256 + t;
      int v = (i < NB) ? src[i] : 0;
      sh[t] = v;
      __syncthreads();
      for (int off = 1; off < 256; off <<= 1) {
        int u = (t >= off) ? sh[t - off] : 0;
        __syncthreads();
        sh[t] += u;
        __syncthreads();
      }
      int carry = carrysh;
      if (i < NB) dst[i] = carry + sh[t] - v;
      __syncthreads();
      if (t == 255) carrysh = carry + sh[255];
      __syncthreads();
    }
    if (t == 0) dst[NB] = E;
    __syncthreads();
  }
  if (t == 0) row[N] = E;
}

// ---------------- K4: placement into bucket-sorted edge arrays (LDS counters only) --------
__global__ __launch_bounds__(256) void k_place(const int* __restrict__ ei,
                                               const int* __restrict__ h2dD,
                                               const int* __restrict__ h2dS,
                                               const int* __restrict__ bsD,
                                               const int* __restrict__ bsS,
                                               unsigned int* __restrict__ seD,
                                               unsigned int* __restrict__ seS,
                                               int E, int NB, int per) {
  extern __shared__ int osh[];  // 2*NB ints
  int* oD = osh;
  int* oS = osh + NB;
  int b = blockIdx.x, t = threadIdx.x;
  for (int j = t; j < NB; j += 256) {
    oD[j] = bsD[j] + h2dD[(size_t)b * NB + j];
    oS[j] = bsS[j] + h2dS[(size_t)b * NB + j];
  }
  __syncthreads();
  int lo = b * per, hi = min(E, lo + per);
  for (int e = lo + t; e < hi; e += 256) {
    int s = ei[e];
    int d = ei[(size_t)E + e];
    int pd = atomicAdd(&oD[d >> 6], 1);
    seD[pd] = (unsigned int)s | ((unsigned int)(d & 63) << 20);
    int ps = atomicAdd(&oS[s >> 6], 1);
    seS[ps] = (unsigned int)d | ((unsigned int)(s & 63) << 20);
  }
}

// ---------------- K5: per-bucket dst CSR finalize: csr, row, deg ----------------
__global__ __launch_bounds__(256) void k_csrd(const unsigned int* __restrict__ seD,
                                              const int* __restrict__ bsD,
                                              int* __restrict__ csr,
                                              int* __restrict__ row,
                                              int* __restrict__ deg, int NB, int N) {
  __shared__ int cnt[64], sc[64], ofs[64];
  int b = blockIdx.x, t = threadIdx.x;
  if (t < 64) cnt[t] = 0;
  __syncthreads();
  int lo = bsD[b], hi = bsD[b + 1];
  for (int k = lo + t; k < hi; k += 256) atomicAdd(&cnt[seD[k] >> 20], 1);
  __syncthreads();
  if (t < 64) sc[t] = cnt[t];
  __syncthreads();
  for (int off = 1; off < 64; off <<= 1) {
    int u = (t < 64 && t >= off) ? sc[t - off] : 0;
    __syncthreads();
    if (t < 64) sc[t] += u;
    __syncthreads();
  }
  if (t < 64) {
    int ex = sc[t] - cnt[t];
    ofs[t] = ex;
    int node = b * 64 + t;
    if (node < N) { row[node] = lo + ex; deg[node] = cnt[t]; }
  }
  __syncthreads();
  for (int k = lo + t; k < hi; k += 256) {
    unsigned int v = seD[k];
    int p = atomicAdd(&ofs[v >> 20], 1);
    csr[lo + p] = (int)(v & 0xFFFFFu);
  }
}

// ---------------- K6: inv = rsqrt(deg+1); xi = bf16(x*inv); gfeat sums ----------------
__global__ __launch_bounds__(256) void k_inv(const int* __restrict__ deg,
                                             const float* __restrict__ x,
                                             float* __restrict__ inv,
                                             uint4* __restrict__ xi,
                                             float* __restrict__ gacc, int N) {
  int i = blockIdx.x * 256 + threadIdx.x;
  float s2 = 0.f, s3 = 0.f, s4 = 0.f, c0 = 0.f, sl = 0.f, sm = 0.f;
  if (i < N) {
    float iv = rsqrtf((float)deg[i] + 1.0f);
    inv[i] = iv;
    float x0 = x[(size_t)i * 5 + 0];
    float x1 = x[(size_t)i * 5 + 1];
    float x2 = x[(size_t)i * 5 + 2];
    float x3 = x[(size_t)i * 5 + 3];
    float x4 = x[(size_t)i * 5 + 4];
    uint4 o;
    o.x = pack2bf(x0 * iv, x1 * iv);
    o.y = pack2bf(x2 * iv, x3 * iv);
    o.z = pack2bf(x4 * iv, 0.f);
    o.w = 0u;
    xi[i] = o;
    s2 = x2; s3 = x3; s4 = x4;
    if (x2 == 1.0f) { c0 = 1.f; sl = x0; sm = x1; }
  }
  #pragma unroll
  for (int off = 32; off > 0; off >>= 1) {
    s2 += __shfl_down(s2, off);
    s3 += __shfl_down(s3, off);
    s4 += __shfl_down(s4, off);
    c0 += __shfl_down(c0, off);
    sl += __shfl_down(sl, off);
    sm += __shfl_down(sm, off);
  }
  if ((threadIdx.x & 63) == 0) {
    unsafeAtomicAdd(&gacc[0], s2);
    unsafeAtomicAdd(&gacc[1], s3);
    unsafeAtomicAdd(&gacc[2], s4);
    unsafeAtomicAdd(&gacc[3], c0);
    unsafeAtomicAdd(&gacc[4], sl);
    unsafeAtomicAdd(&gacc[5], sm);
  }
}

// ---------------- K7: per-bucket src pass: w_raw[s] = sum inv[dst] (LDS only) ----------
__global__ __launch_bounds__(256) void k_csrs(const unsigned int* __restrict__ seS,
                                              const int* __restrict__ bsS,
                                              const float* __restrict__ inv,
                                              float* __restrict__ w, int NB, int N) {
  __shared__ float wa[64];
  int b = blockIdx.x, t = threadIdx.x;
  if (t < 64) wa[t] = 0.f;
  __syncthreads();
  int lo = bsS[b], hi = bsS[b + 1];
  for (int k = lo + t; k < hi; k += 256) {
    unsigned int v = seS[k];
    atomicAdd(&wa[v >> 20], inv[v & 0xFFFFFu]);
  }
  __syncthreads();
  if (t < 64) {
    int node = b * 64 + t;
    if (node < N) w[node] = wa[t];
  }
}

// ---------------- K8: thread-per-node xi gather; H1' = inv*relu(U@W1+b1) -> fp8 --------
__global__ __launch_bounds__(256) void k_h1f(const uint4* __restrict__ xi,
                                             const int* __restrict__ row,
                                             const int* __restrict__ csr,
                                             const float* __restrict__ inv,
                                             const float* __restrict__ W1,
                                             const float* __restrict__ b1,
                                             unsigned char* __restrict__ H1q,
                                             float* __restrict__ w, int N) {
  __shared__ float W1sh[FIN][HID];
  __shared__ float b1sh[HID];
  int t = threadIdx.x;
  #pragma unroll
  for (int k = 0; k < FIN; k++) W1sh[k][t] = W1[k * HID + t];
  b1sh[t] = b1[t];
  int n = blockIdx.x * 256 + t;
  float a0 = 0.f, a1 = 0.f, a2 = 0.f, a3 = 0.f, a4 = 0.f;
  float invd = 0.f;
  if (n < N) {
    invd = inv[n];
    int start = row[n], end = row[n + 1];
    for (int e = start; e < end; e++) {
      uint4 vx = xi[csr[e]];
      a0 += bflo(vx.x); a1 += bfhi(vx.x);
      a2 += bflo(vx.y); a3 += bfhi(vx.y);
      a4 += bflo(vx.z);
    }
    uint4 vs = xi[n];
    a0 += bflo(vs.x); a1 += bfhi(vs.x);
    a2 += bflo(vs.y); a3 += bfhi(vs.y);
    a4 += bflo(vs.z);
    a0 *= invd; a1 *= invd; a2 *= invd; a3 *= invd; a4 *= invd;
    w[n] = invd * w[n] + invd * invd;  // finalize pooling weight
  }
  __syncthreads();
  if (n >= N) return;
  unsigned char* hrow = H1q + (size_t)n * HID;
  for (int c = 0; c < HID; c += 16) {
    float vv[16];
    #pragma unroll
    for (int j = 0; j < 16; j++) {
      float s = b1sh[c + j];
      s = fmaf(a0, W1sh[0][c + j], s);
      s = fmaf(a1, W1sh[1][c + j], s);
      s = fmaf(a2, W1sh[2][c + j], s);
      s = fmaf(a3, W1sh[3][c + j], s);
      s = fmaf(a4, W1sh[4][c + j], s);
      vv[j] = fmaxf(s, 0.f) * invd;   // H1' = inv * relu(...)
    }
    uint4 o;
    o.x = pk4fp8(vv[0], vv[1], vv[2], vv[3]);
    o.y = pk4fp8(vv[4], vv[5], vv[6], vv[7]);
    o.z = pk4fp8(vv[8], vv[9], vv[10], vv[11]);
    o.w = pk4fp8(vv[12], vv[13], vv[14], vv[15]);
    *(uint4*)(hrow + c) = o;
  }
}

// ---------------- K9: Z[d] = inv_d*(sum_s H1'[s] + H1'[d])  (fp8 gather -> bf16) --------
__global__ __launch_bounds__(256) void k_agg(const int* __restrict__ row,
                                             const int* __restrict__ csr,
                                             const float* __restrict__ inv,
                                             const unsigned char* __restrict__ H1q,
                                             unsigned short* __restrict__ Zb, int N) {
  int wv = threadIdx.x >> 6;
  int l = threadIdx.x & 63;
  int q = l >> 4;       // quarter: which edge in flight
  int sl = l & 15;      // col group: cols sl*16 .. sl*16+15
  int d = blockIdx.x * 4 + wv;
  float acc[16];
  #pragma unroll
  for (int j = 0; j < 16; j++) acc[j] = 0.f;
  if (d >= N) {
    if (l < 32) {  // zero pad rows for k_gemm2
      uint4 z = {0u, 0u, 0u, 0u};
      *(uint4*)(Zb + (size_t)d * HID + (l & 15) * 16 + (l >> 4) * 8) = z;
    }
    return;
  }
  float invd = inv[d];
  int start = row[d], end = row[d + 1];
  int e = start + q;
  for (; e + 4 < end; e += 8) {
    uint4 r0 = *(const uint4*)(H1q + (size_t)csr[e] * HID + sl * 16);
    uint4 r1 = *(const uint4*)(H1q + (size_t)csr[e + 4] * HID + sl * 16);
    acc4u(acc + 0, r0.x); acc4u(acc + 4, r0.y);
    acc4u(acc + 8, r0.z); acc4u(acc + 12, r0.w);
    acc4u(acc + 0, r1.x); acc4u(acc + 4, r1.y);
    acc4u(acc + 8, r1.z); acc4u(acc + 12, r1.w);
  }
  for (; e < end; e += 4) {
    uint4 r0 = *(const uint4*)(H1q + (size_t)csr[e] * HID + sl * 16);
    acc4u(acc + 0, r0.x); acc4u(acc + 4, r0.y);
    acc4u(acc + 8, r0.z); acc4u(acc + 12, r0.w);
  }
  if (q == 0) {  // self-loop term
    uint4 rs = *(const uint4*)(H1q + (size_t)d * HID + sl * 16);
    acc4u(acc + 0, rs.x); acc4u(acc + 4, rs.y);
    acc4u(acc + 8, rs.z); acc4u(acc + 12, rs.w);
  }
  #pragma unroll
  for (int j = 0; j < 16; j++) {
    acc[j] += __shfl_xor(acc[j], 16);
    acc[j] += __shfl_xor(acc[j], 32);
  }
  if (l < 32) {
    int half = l >> 4;
    int base = half * 8;
    int col0 = (l & 15) * 16 + half * 8;
    uint4 o;
    o.x = pack2bf(acc[base + 0] * invd, acc[base + 1] * invd);
    o.y = pack2bf(acc[base + 2] * invd, acc[base + 3] * invd);
    o.z = pack2bf(acc[base + 4] * invd, acc[base + 5] * invd);
    o.w = pack2bf(acc[base + 6] * invd, acc[base + 7] * invd);
    *(uint4*)(Zb + (size_t)d * HID + col0) = o;
  }
}

// ---------------- K10: MFMA GEMM: H2 = relu(Z @ W2 + b2); part[blk] = H2^T w -----------
// 256 rows/block, 4 waves x 64 rows; W2f LDS-staged in 4 chunks; no global atomics.
__global__ __launch_bounds__(256, 2) void k_gemm2(const unsigned short* __restrict__ Zb,
                                                  const float* __restrict__ w,
                                                  const unsigned short* __restrict__ W2f,
                                                  const float* __restrict__ b2,
                                                  float* __restrict__ part, int N) {
  __shared__ unsigned short Bsh[16384];  // 32 KB: 4 col-tiles x 8 kb x 64 lanes x 8
  __shared__ float vsh[4][HID];
  int t = threadIdx.x;
  int wv = t >> 6, l = t & 63;
  int lo = l & 15, hi = l >> 4;
  int row0 = blockIdx.x * 256 + wv * 64;

  // A fragments: a[rt][kb] for rows row0+rt*16+lo, k = kb*32 + hi*8 + j
  bf16x8 a[4][8];
  #pragma unroll
  for (int rt = 0; rt < 4; rt++) {
    const unsigned short* zrow = Zb + (size_t)(row0 + rt * 16 + lo) * HID + hi * 8;
    #pragma unroll
    for (int kb = 0; kb < 8; kb++)
      a[rt][kb] = *reinterpret_cast<const bf16x8*>(zrow + kb * 32);
  }
  // pooling weights for C rows this lane owns (row = ... + hi*4 + i)
  float w4[4][4];
  #pragma unroll
  for (int rt = 0; rt < 4; rt++)
    #pragma unroll
    for (int i = 0; i < 4; i++) {
      int gr = row0 + rt * 16 + hi * 4 + i;
      w4[rt][i] = (gr < N) ? w[gr] : 0.f;
    }

  for (int c = 0; c < 4; c++) {  // chunk of 4 col-tiles
    // stage 32 KB of W2f (fragment-order, linear)
    {
      const uint4* src = (const uint4*)(W2f + (size_t)c * 16384);
      uint4* dst = (uint4*)Bsh;
      #pragma unroll
      for (int i = 0; i < 8; i++) dst[t + i * 256] = src[t + i * 256];
    }
    __syncthreads();
    #pragma unroll
    for (int cp = 0; cp < 2; cp++) {  // col-tile pairs within chunk
      int ct2 = cp * 2;
      f32x4 acc[2][4];
      #pragma unroll
      for (int u = 0; u < 2; u++)
        #pragma unroll
        for (int rt = 0; rt < 4; rt++) acc[u][rt] = (f32x4){0.f, 0.f, 0.f, 0.f};
      #pragma unroll
      for (int kb = 0; kb < 8; kb++) {
        bf16x8 b0 = *reinterpret_cast<const bf16x8*>(Bsh + ((ct2 * 8 + kb) * 64 + l) * 8);
        bf16x8 b1 = *reinterpret_cast<const bf16x8*>(Bsh + (((ct2 + 1) * 8 + kb) * 64 + l) * 8);
        #pragma unroll
        for (int rt = 0; rt < 4; rt++) {
          acc[0][rt] = __builtin_amdgcn_mfma_f32_16x16x32_bf16(a[rt][kb], b0, acc[0][rt], 0, 0, 0);
          acc[1][rt] = __builtin_amdgcn_mfma_f32_16x16x32_bf16(a[rt][kb], b1, acc[1][rt], 0, 0, 0);
        }
      }
      #pragma unroll
      for (int u = 0; u < 2; u++) {
        int col = (c * 4 + ct2 + u) * 16 + lo;
        float bc = b2[col];
        float p = 0.f;
        #pragma unroll
        for (int rt = 0; rt < 4; rt++)
          #pragma unroll
          for (int i = 0; i < 4; i++)
            p = fmaf(w4[rt][i], fmaxf(acc[u][rt][i] + bc, 0.f), p);
        p += __shfl_xor(p, 16);
        p += __shfl_xor(p, 32);
        if (hi == 0) vsh[wv][col] = p;
      }
    }
    __syncthreads();
  }
  float s = vsh[0][t] + vsh[1][t] + vsh[2][t] + vsh[3][t];
  part[(size_t)blockIdx.x * HID + t] = s;
}

// ---------------- K11: v-reduce, embedding, gfeat, MLP head, final transform -----------
__global__ __launch_bounds__(256) void k_head(const float* __restrict__ part, int P,
                                              const float* __restrict__ gacc,
                                              const float* __restrict__ W3,
                                              const float* __restrict__ b3,
                                              const float* __restrict__ Wp1,
                                              const float* __restrict__ bp1,
                                              const float* __restrict__ Wp2,
                                              const float* __restrict__ bp2,
                                              const float* __restrict__ Wp3,
                                              const float* __restrict__ bp3,
                                              float* __restrict__ out, int N) {
  __shared__ float vsh[HID];
  __shared__ float emb[EMBD + 7];
  __shared__ float h64[64];
  __shared__ float h32[32];
  __shared__ float val[4];
  int t = threadIdx.x;
  {
    float s = 0.f;
    for (int p = 0; p < P; p++) s += part[(size_t)p * HID + t];
    vsh[t] = s;
  }
  __syncthreads();
  if (t < EMBD) {
    float a = 0.f;
    for (int c = 0; c < HID; c++) a = fmaf(vsh[c], W3[c * EMBD + t], a);
    emb[t] = a / (float)N + b3[t];
  } else if (t == EMBD) {
    emb[EMBD + 0] = gacc[0];
    emb[EMBD + 1] = gacc[1];
    emb[EMBD + 2] = gacc[2];
    emb[EMBD + 3] = gacc[1] + gacc[2];
    float cnt = gacc[3];
    emb[EMBD + 4] = cnt > 0.f ? gacc[4] / fmaxf(cnt, 1.f) : 0.f;
    emb[EMBD + 5] = cnt > 0.f ? gacc[5] / fmaxf(cnt, 1.f) : 0.f;
    emb[EMBD + 6] = 100.0f / 500.0f;  // T_norm
  }
  __syncthreads();
  if (t < 64) {
    float a = bp1[t];
    for (int k = 0; k < EMBD + 7; k++) a = fmaf(emb[k], Wp1[k * 64 + t], a);
    h64[t] = fmaxf(a, 0.f);
  }
  __syncthreads();
  if (t < 32) {
    float a = bp2[t];
    for (int k = 0; k < 64; k++) a = fmaf(h64[k], Wp2[k * 32 + t], a);
    h32[t] = fmaxf(a, 0.f);
  }
  __syncthreads();
  if (t < 4) {
    float a = bp3[t];
    for (int k = 0; k < 32; k++) a = fmaf(h32[k], Wp3[k * 4 + t], a);
    val[t] = a > 20.f ? a : log1pf(expf(a));  // softplus
  }
  __syncthreads();
  if (t == 0) {
    const float Tn = 100.0f / 500.0f;
    const float scale = 1.0f - 0.7f * Tn;
    float am = 1.0f + val[0] * scale;
    float aM = 1.0f + (val[0] + val[1] + 1.0f) * scale;
    float bm = 1.0f + val[2] * scale * 0.3f;
    float bM = bm + (val[3] + 0.1f) * scale * 0.3f;
    out[0] = am; out[1] = aM; out[2] = bm; out[3] = bM;
  }
  if (t < EMBD + 7) out[4 + t] = emb[t];
}

static inline size_t al4(size_t a) { return (a + 3) & ~(size_t)3; }

extern "C" void kernel_launch(void* const* d_in, const int* in_sizes, int n_in,
                              void* d_out, int out_size, void* d_ws, size_t ws_size,
                              hipStream_t stream) {
  const float* x = (const float*)d_in[0];
  const int* ei = (const int*)d_in[1];
  const float* W1 = (const float*)d_in[2];
  const float* b1 = (const float*)d_in[3];
  const float* W2 = (const float*)d_in[4];
  const float* b2 = (const float*)d_in[5];
  const float* W3 = (const float*)d_in[6];
  const float* b3 = (const float*)d_in[7];
  const float* Wp1 = (const float*)d_in[8];
  const float* bp1 = (const float*)d_in[9];
  const float* Wp2 = (const float*)d_in[10];
  const float* bp2 = (const float*)d_in[11];
  const float* Wp3 = (const float*)d_in[12];
  const float* bp3 = (const float*)d_in[13];

  int N = in_sizes[0] / FIN;
  int E = in_sizes[1] / 2;
  int nb = (N + 255) / 256;
  int Npad = ((N + 255) / 256) * 256;   // multiple of 256 for k_gemm2
  int P = Npad / 256;                   // gemm2 blocks / partials
  int NB = (N + 63) / 64;               // buckets of 64 nodes
  int per = (E + NBLK - 1) / NBLK;      // edges per hist/place block
  size_t shbytes = (size_t)2 * NB * sizeof(int);

  float* ws = (float*)d_ws;
  size_t o_gacc = 0;                                 // 16
  size_t zero_end = 16;
  size_t o_deg  = zero_end;                          // N ints
  size_t o_row  = al4(o_deg + N);                    // N+1 ints
  size_t o_inv  = al4(o_row + N + 1);                // N floats
  size_t o_w    = al4(o_inv + N);                    // N floats
  size_t o_part = al4(o_w + N);                      // P*256 floats
  size_t o_xi   = al4(o_part + (size_t)P * HID);     // 4N (uint4/node)
  size_t o_w2t  = o_xi + (size_t)N * 4;              // 32768 (HID*HID bf16)
  size_t o_h2dD = o_w2t + (size_t)HID * HID / 2;     // NBLK*NB ints
  size_t o_h2dS = o_h2dD + (size_t)NBLK * NB;        // NBLK*NB ints
  size_t o_btot = o_h2dS + (size_t)NBLK * NB;        // 2*NB
  size_t o_bsD  = o_btot + (size_t)2 * NB;           // NB+1
  size_t o_bsS  = o_bsD + NB + 1;                    // NB+1
  size_t o_seD  = al4(o_bsS + NB + 1);               // E uints
  size_t o_seS  = o_seD + E;                         // E uints
  size_t o_csr  = o_seS + E;                         // E ints
  size_t o_H1q  = al4(o_csr + E);                    // 64N (256 fp8/node)
  size_t o_Z    = o_H1q + (size_t)N * (HID / 4);     // 128*Npad (bf16)
  size_t total  = o_Z + (size_t)Npad * (HID / 2);
  if (ws_size < total * sizeof(float)) {
    hipMemsetAsync(d_out, 0x42, (size_t)out_size * sizeof(float), stream);
    return;
  }

  int* deg = (int*)(ws + o_deg);
  int* row = (int*)(ws + o_row);
  int* h2dD = (int*)(ws + o_h2dD);
  int* h2dS = (int*)(ws + o_h2dS);
  int* btot = (int*)(ws + o_btot);
  int* bsD = (int*)(ws + o_bsD);
  int* bsS = (int*)(ws + o_bsS);
  unsigned int* seD = (unsigned int*)(ws + o_seD);
  unsigned int* seS = (unsigned int*)(ws + o_seS);
  int* csr = (int*)(ws + o_csr);
  unsigned short* W2f = (unsigned short*)(ws + o_w2t);
  uint4* xi = (uint4*)(ws + o_xi);
  unsigned char* H1q = (unsigned char*)(ws + o_H1q);
  unsigned short* Zb = (unsigned short*)(ws + o_Z);

  hipMemsetAsync(ws, 0, zero_end * sizeof(float), stream);

  k_hist<<<NBLK + HID, 256, shbytes, stream>>>(ei, W2, h2dD, h2dS, W2f, E, NB, per);
  k_bred<<<2 * NB, 256, 0, stream>>>(h2dD, h2dS, btot, NB);
  k_bscan<<<1, 256, 0, stream>>>(btot, bsD, bsS, row, E, NB, N);
  k_place<<<NBLK, 256, shbytes, stream>>>(ei, h2dD, h2dS, bsD, bsS, seD, seS, E, NB, per);
  k_csrd<<<NB, 256, 0, stream>>>(seD, bsD, csr, row, deg, NB, N);
  k_inv<<<nb, 256, 0, stream>>>(deg, x, ws + o_inv, xi, ws + o_gacc, N);
  k_csrs<<<NB, 256, 0, stream>>>(seS, bsS, ws + o_inv, ws + o_w, NB, N);
  k_h1f<<<nb, 256, 0, stream>>>(xi, row, csr, ws + o_inv, W1, b1, H1q, ws + o_w, N);
  k_agg<<<Npad / 4, 256, 0, stream>>>(row, csr, ws + o_inv, H1q, Zb, N);
  k_gemm2<<<P, 256, 0, stream>>>(Zb, ws + o_w, W2f, b2, ws + o_part, N);
  k_head<<<1, 256, 0, stream>>>(ws + o_part, P, ws + o_gacc, W3, b3, Wp1, bp1, Wp2, bp2,
                                Wp3, bp3, (float*)d_out, N);
}

// Round 8
// 394.865 us; speedup vs baseline: 15.9881x; 1.3166x over previous
//
#include <hip/hip_runtime.h>
#include <hip/hip_bf16.h>
#include <hip/hip_fp16.h>
#include <cstdint>
#include <cstddef>

#define HID 256
#define EMBD 128
#define FIN 5
#define NBLK 256   // histogram/placement blocks

typedef __attribute__((ext_vector_type(8))) short bf16x8;
typedef __attribute__((ext_vector_type(4))) float f32x4;

__device__ __forceinline__ unsigned short f2bf(float f) {
  unsigned int u = __float_as_uint(f);
  u += 0x7FFFu + ((u >> 16) & 1u);   // RNE
  return (unsigned short)(u >> 16);
}
__device__ __forceinline__ float bflo(unsigned int u) { return __uint_as_float(u << 16); }
__device__ __forceinline__ float bfhi(unsigned int u) { return __uint_as_float(u & 0xFFFF0000u); }
__device__ __forceinline__ unsigned int pack2bf(float a, float b) {
  return ((unsigned int)f2bf(b) << 16) | (unsigned int)f2bf(a);
}
// fp8 e5m2 = top byte of fp16, manual RNE
__device__ __forceinline__ unsigned char f2bf8(float f) {
  unsigned short u = __half_as_ushort(__float2half(f));
  unsigned short r = u + 0x7Fu + ((u >> 8) & 1u);
  return (unsigned char)(r >> 8);
}
__device__ __forceinline__ float bf82f(unsigned int v) {
  return __half2float(__ushort_as_half((unsigned short)(v << 8)));
}
__device__ __forceinline__ unsigned int pk4fp8(float a, float b, float c, float d) {
  return (unsigned int)f2bf8(a) | ((unsigned int)f2bf8(b) << 8) |
         ((unsigned int)f2bf8(c) << 16) | ((unsigned int)f2bf8(d) << 24);
}
__device__ __forceinline__ void acc4u(float* a, unsigned int u) {
  a[0] += bf82f(u & 0xffu);
  a[1] += bf82f((u >> 8) & 0xffu);
  a[2] += bf82f((u >> 16) & 0xffu);
  a[3] += bf82f(u >> 24);
}

// ---------------- K1: dual LDS histogram (dst & src buckets) + W2 -> fragment order ------
__global__ __launch_bounds__(256) void k_hist(const int* __restrict__ ei,
                                              const float* __restrict__ W2,
                                              int* __restrict__ h2dD,
                                              int* __restrict__ h2dS,
                                              unsigned short* __restrict__ W2f,
                                              int E, int NB, int per) {
  int b = blockIdx.x, t = threadIdx.x;
  if (b >= NBLK) {  // W2 pack blocks: b-NBLK = n (col), t = k
    int n = b - NBLK;
    size_t off = ((((size_t)(n >> 4) * 8 + (t >> 5)) * 64) +
                  (size_t)((t >> 3) & 3) * 16 + (n & 15)) * 8 + (t & 7);
    W2f[off] = f2bf(W2[(size_t)t * HID + n]);
    return;
  }
  extern __shared__ int hsh[];  // 2*NB ints
  int* hD = hsh;
  int* hS = hsh + NB;
  for (int j = t; j < 2 * NB; j += 256) hsh[j] = 0;
  __syncthreads();
  int lo = b * per, hi = min(E, lo + per);
  for (int e = lo + t; e < hi; e += 256) {
    int s = ei[e];
    int d = ei[(size_t)E + e];
    atomicAdd(&hD[d >> 6], 1);
    atomicAdd(&hS[s >> 6], 1);
  }
  __syncthreads();
  for (int j = t; j < NB; j += 256) {
    h2dD[(size_t)b * NB + j] = hD[j];
    h2dS[(size_t)b * NB + j] = hS[j];
  }
}

// ---------------- K2: per-bucket exclusive scan over blocks ----------------
__global__ __launch_bounds__(256) void k_bred(int* __restrict__ h2dD,
                                              int* __restrict__ h2dS,
                                              int* __restrict__ btot, int NB) {
  __shared__ int sh[NBLK];
  int bb = blockIdx.x, t = threadIdx.x;
  int* arr = (bb < NB) ? h2dD : h2dS;
  int b = (bb < NB) ? bb : bb - NB;
  int v = arr[(size_t)t * NB + b];
  sh[t] = v;
  __syncthreads();
  for (int off = 1; off < 256; off <<= 1) {
    int u = (t >= off) ? sh[t - off] : 0;
    __syncthreads();
    sh[t] += u;
    __syncthreads();
  }
  arr[(size_t)t * NB + b] = sh[t] - v;   // exclusive over blocks
  if (t == 255) btot[bb] = sh[255];
}

// ---------------- K3: scan bucket totals -> bucket starts ----------------
__global__ __launch_bounds__(256) void k_bscan(const int* __restrict__ btot,
                                               int* __restrict__ bsD,
                                               int* __restrict__ bsS,
                                               int* __restrict__ row,
                                               int E, int NB, int N) {
  __shared__ int sh[256];
  __shared__ int carrysh;
  int t = threadIdx.x;
  for (int which = 0; which < 2; which++) {
    const int* src = btot + (size_t)which * NB;
    int* dst = which ? bsS : bsD;
    if (t == 0) carrysh = 0;
    __syncthreads();
    int nch = (NB + 255) / 256;
    for (int c = 0; c < nch; c++) {
      int i = c * 256 + t;
      int v = (i < NB) ? src[i] : 0;
      sh[t] = v;
      __syncthreads();
      for (int off = 1; off < 256; off <<= 1) {
        int u = (t >= off) ? sh[t - off] : 0;
        __syncthreads();
        sh[t] += u;
        __syncthreads();
      }
      int carry = carrysh;
      if (i < NB) dst[i] = carry + sh[t] - v;
      __syncthreads();
      if (t == 255) carrysh = carry + sh[255];
      __syncthreads();
    }
    if (t == 0) dst[NB] = E;
    __syncthreads();
  }
  if (t == 0) row[N] = E;
}

// ---------------- K4: placement into bucket-sorted edge arrays (LDS counters only) --------
__global__ __launch_bounds__(256) void k_place(const int* __restrict__ ei,
                                               const int* __restrict__ h2dD,
                                               const int* __restrict__ h2dS,
                                               const int* __restrict__ bsD,
                                               const int* __restrict__ bsS,
                                               unsigned int* __restrict__ seD,
                                               unsigned int* __restrict__ seS,
                                               int E, int NB, int per) {
  extern __shared__ int osh[];  // 2*NB ints
  int* oD = osh;
  int* oS = osh + NB;
  int b = blockIdx.x, t = threadIdx.x;
  for (int j = t; j < NB; j += 256) {
    oD[j] = bsD[j] + h2dD[(size_t)b * NB + j];
    oS[j] = bsS[j] + h2dS[(size_t)b * NB + j];
  }
  __syncthreads();
  int lo = b * per, hi = min(E, lo + per);
  for (int e = lo + t; e < hi; e += 256) {
    int s = ei[e];
    int d = ei[(size_t)E + e];
    int pd = atomicAdd(&oD[d >> 6], 1);
    seD[pd] = (unsigned int)s | ((unsigned int)(d & 63) << 20);
    int ps = atomicAdd(&oS[s >> 6], 1);
    seS[ps] = (unsigned int)d | ((unsigned int)(s & 63) << 20);
  }
}

// ---------------- K5: per-bucket dst CSR finalize: csr, row, deg ----------------
__global__ __launch_bounds__(256) void k_csrd(const unsigned int* __restrict__ seD,
                                              const int* __restrict__ bsD,
                                              int* __restrict__ csr,
                                              int* __restrict__ row,
                                              int* __restrict__ deg, int NB, int N) {
  __shared__ int cnt[64], sc[64], ofs[64];
  int b = blockIdx.x, t = threadIdx.x;
  if (t < 64) cnt[t] = 0;
  __syncthreads();
  int lo = bsD[b], hi = bsD[b + 1];
  for (int k = lo + t; k < hi; k += 256) atomicAdd(&cnt[seD[k] >> 20], 1);
  __syncthreads();
  if (t < 64) sc[t] = cnt[t];
  __syncthreads();
  for (int off = 1; off < 64; off <<= 1) {
    int u = (t < 64 && t >= off) ? sc[t - off] : 0;
    __syncthreads();
    if (t < 64) sc[t] += u;
    __syncthreads();
  }
  if (t < 64) {
    int ex = sc[t] - cnt[t];
    ofs[t] = ex;
    int node = b * 64 + t;
    if (node < N) { row[node] = lo + ex; deg[node] = cnt[t]; }
  }
  __syncthreads();
  for (int k = lo + t; k < hi; k += 256) {
    unsigned int v = seD[k];
    int p = atomicAdd(&ofs[v >> 20], 1);
    csr[lo + p] = (int)(v & 0xFFFFFu);
  }
}

// ---------------- K6: inv = rsqrt(deg+1); xi = bf16(x*inv); gfeat partials (NO atomics) --
__global__ __launch_bounds__(256) void k_inv(const int* __restrict__ deg,
                                             const float* __restrict__ x,
                                             float* __restrict__ inv,
                                             uint4* __restrict__ xi,
                                             float* __restrict__ gpart, int N) {
  __shared__ float wsum[4][6];
  int t = threadIdx.x;
  int i = blockIdx.x * 256 + t;
  float s2 = 0.f, s3 = 0.f, s4 = 0.f, c0 = 0.f, sl = 0.f, sm = 0.f;
  if (i < N) {
    float iv = rsqrtf((float)deg[i] + 1.0f);
    inv[i] = iv;
    float x0 = x[(size_t)i * 5 + 0];
    float x1 = x[(size_t)i * 5 + 1];
    float x2 = x[(size_t)i * 5 + 2];
    float x3 = x[(size_t)i * 5 + 3];
    float x4 = x[(size_t)i * 5 + 4];
    uint4 o;
    o.x = pack2bf(x0 * iv, x1 * iv);
    o.y = pack2bf(x2 * iv, x3 * iv);
    o.z = pack2bf(x4 * iv, 0.f);
    o.w = 0u;
    xi[i] = o;
    s2 = x2; s3 = x3; s4 = x4;
    if (x2 == 1.0f) { c0 = 1.f; sl = x0; sm = x1; }
  }
  #pragma unroll
  for (int off = 32; off > 0; off >>= 1) {
    s2 += __shfl_down(s2, off);
    s3 += __shfl_down(s3, off);
    s4 += __shfl_down(s4, off);
    c0 += __shfl_down(c0, off);
    sl += __shfl_down(sl, off);
    sm += __shfl_down(sm, off);
  }
  if ((t & 63) == 0) {
    int wv = t >> 6;
    wsum[wv][0] = s2; wsum[wv][1] = s3; wsum[wv][2] = s4;
    wsum[wv][3] = c0; wsum[wv][4] = sl; wsum[wv][5] = sm;
  }
  __syncthreads();
  if (t < 8) {
    float g = 0.f;
    if (t < 6) g = wsum[0][t] + wsum[1][t] + wsum[2][t] + wsum[3][t];
    gpart[(size_t)blockIdx.x * 8 + t] = g;   // coalesced, zero atomics
  }
}

// ---------------- K7: per-bucket src pass: w_raw[s] = sum inv[dst] (LDS only) ----------
__global__ __launch_bounds__(256) void k_csrs(const unsigned int* __restrict__ seS,
                                              const int* __restrict__ bsS,
                                              const float* __restrict__ inv,
                                              float* __restrict__ w, int NB, int N) {
  __shared__ float wa[64];
  int b = blockIdx.x, t = threadIdx.x;
  if (t < 64) wa[t] = 0.f;
  __syncthreads();
  int lo = bsS[b], hi = bsS[b + 1];
  for (int k = lo + t; k < hi; k += 256) {
    unsigned int v = seS[k];
    atomicAdd(&wa[v >> 20], inv[v & 0xFFFFFu]);
  }
  __syncthreads();
  if (t < 64) {
    int node = b * 64 + t;
    if (node < N) w[node] = wa[t];
  }
}

// ---------------- K8: thread-per-node xi gather; H1' = inv*relu(U@W1+b1) -> fp8 --------
__global__ __launch_bounds__(256) void k_h1f(const uint4* __restrict__ xi,
                                             const int* __restrict__ row,
                                             const int* __restrict__ csr,
                                             const float* __restrict__ inv,
                                             const float* __restrict__ W1,
                                             const float* __restrict__ b1,
                                             unsigned char* __restrict__ H1q,
                                             float* __restrict__ w, int N) {
  __shared__ float W1sh[FIN][HID];
  __shared__ float b1sh[HID];
  int t = threadIdx.x;
  #pragma unroll
  for (int k = 0; k < FIN; k++) W1sh[k][t] = W1[k * HID + t];
  b1sh[t] = b1[t];
  int n = blockIdx.x * 256 + t;
  float a0 = 0.f, a1 = 0.f, a2 = 0.f, a3 = 0.f, a4 = 0.f;
  float invd = 0.f;
  if (n < N) {
    invd = inv[n];
    int start = row[n], end = row[n + 1];
    for (int e = start; e < end; e++) {
      uint4 vx = xi[csr[e]];
      a0 += bflo(vx.x); a1 += bfhi(vx.x);
      a2 += bflo(vx.y); a3 += bfhi(vx.y);
      a4 += bflo(vx.z);
    }
    uint4 vs = xi[n];
    a0 += bflo(vs.x); a1 += bfhi(vs.x);
    a2 += bflo(vs.y); a3 += bfhi(vs.y);
    a4 += bflo(vs.z);
    a0 *= invd; a1 *= invd; a2 *= invd; a3 *= invd; a4 *= invd;
    w[n] = invd * w[n] + invd * invd;  // finalize pooling weight
  }
  __syncthreads();
  if (n >= N) return;
  unsigned char* hrow = H1q + (size_t)n * HID;
  for (int c = 0; c < HID; c += 16) {
    float vv[16];
    #pragma unroll
    for (int j = 0; j < 16; j++) {
      float s = b1sh[c + j];
      s = fmaf(a0, W1sh[0][c + j], s);
      s = fmaf(a1, W1sh[1][c + j], s);
      s = fmaf(a2, W1sh[2][c + j], s);
      s = fmaf(a3, W1sh[3][c + j], s);
      s = fmaf(a4, W1sh[4][c + j], s);
      vv[j] = fmaxf(s, 0.f) * invd;   // H1' = inv * relu(...)
    }
    uint4 o;
    o.x = pk4fp8(vv[0], vv[1], vv[2], vv[3]);
    o.y = pk4fp8(vv[4], vv[5], vv[6], vv[7]);
    o.z = pk4fp8(vv[8], vv[9], vv[10], vv[11]);
    o.w = pk4fp8(vv[12], vv[13], vv[14], vv[15]);
    *(uint4*)(hrow + c) = o;
  }
}

// ---------------- K9: Z[d] = inv_d*(sum_s H1'[s] + H1'[d])  (fp8 gather -> bf16) --------
__global__ __launch_bounds__(256) void k_agg(const int* __restrict__ row,
                                             const int* __restrict__ csr,
                                             const float* __restrict__ inv,
                                             const unsigned char* __restrict__ H1q,
                                             unsigned short* __restrict__ Zb, int N) {
  int wv = threadIdx.x >> 6;
  int l = threadIdx.x & 63;
  int q = l >> 4;       // quarter: which edge in flight
  int sl = l & 15;      // col group: cols sl*16 .. sl*16+15
  int d = blockIdx.x * 4 + wv;
  float acc[16];
  #pragma unroll
  for (int j = 0; j < 16; j++) acc[j] = 0.f;
  if (d >= N) {
    if (l < 32) {  // zero pad rows for k_gemm2
      uint4 z = {0u, 0u, 0u, 0u};
      *(uint4*)(Zb + (size_t)d * HID + (l & 15) * 16 + (l >> 4) * 8) = z;
    }
    return;
  }
  float invd = inv[d];
  int start = row[d], end = row[d + 1];
  int e = start + q;
  for (; e + 4 < end; e += 8) {
    uint4 r0 = *(const uint4*)(H1q + (size_t)csr[e] * HID + sl * 16);
    uint4 r1 = *(const uint4*)(H1q + (size_t)csr[e + 4] * HID + sl * 16);
    acc4u(acc + 0, r0.x); acc4u(acc + 4, r0.y);
    acc4u(acc + 8, r0.z); acc4u(acc + 12, r0.w);
    acc4u(acc + 0, r1.x); acc4u(acc + 4, r1.y);
    acc4u(acc + 8, r1.z); acc4u(acc + 12, r1.w);
  }
  for (; e < end; e += 4) {
    uint4 r0 = *(const uint4*)(H1q + (size_t)csr[e] * HID + sl * 16);
    acc4u(acc + 0, r0.x); acc4u(acc + 4, r0.y);
    acc4u(acc + 8, r0.z); acc4u(acc + 12, r0.w);
  }
  if (q == 0) {  // self-loop term
    uint4 rs = *(const uint4*)(H1q + (size_t)d * HID + sl * 16);
    acc4u(acc + 0, rs.x); acc4u(acc + 4, rs.y);
    acc4u(acc + 8, rs.z); acc4u(acc + 12, rs.w);
  }
  #pragma unroll
  for (int j = 0; j < 16; j++) {
    acc[j] += __shfl_xor(acc[j], 16);
    acc[j] += __shfl_xor(acc[j], 32);
  }
  if (l < 32) {
    int half = l >> 4;
    int base = half * 8;
    int col0 = (l & 15) * 16 + half * 8;
    uint4 o;
    o.x = pack2bf(acc[base + 0] * invd, acc[base + 1] * invd);
    o.y = pack2bf(acc[base + 2] * invd, acc[base + 3] * invd);
    o.z = pack2bf(acc[base + 4] * invd, acc[base + 5] * invd);
    o.w = pack2bf(acc[base + 6] * invd, acc[base + 7] * invd);
    *(uint4*)(Zb + (size_t)d * HID + col0) = o;
  }
}

// ---------------- K10: MFMA GEMM: H2 = relu(Z @ W2 + b2); part[blk] = H2^T w -----------
__global__ __launch_bounds__(256, 2) void k_gemm2(const unsigned short* __restrict__ Zb,
                                                  const float* __restrict__ w,
                                                  const unsigned short* __restrict__ W2f,
                                                  const float* __restrict__ b2,
                                                  float* __restrict__ part, int N) {
  __shared__ unsigned short Bsh[16384];  // 32 KB: 4 col-tiles x 8 kb x 64 lanes x 8
  __shared__ float vsh[4][HID];
  int t = threadIdx.x;
  int wv = t >> 6, l = t & 63;
  int lo = l & 15, hi = l >> 4;
  int row0 = blockIdx.x * 256 + wv * 64;

  bf16x8 a[4][8];
  #pragma unroll
  for (int rt = 0; rt < 4; rt++) {
    const unsigned short* zrow = Zb + (size_t)(row0 + rt * 16 + lo) * HID + hi * 8;
    #pragma unroll
    for (int kb = 0; kb < 8; kb++)
      a[rt][kb] = *reinterpret_cast<const bf16x8*>(zrow + kb * 32);
  }
  float w4[4][4];
  #pragma unroll
  for (int rt = 0; rt < 4; rt++)
    #pragma unroll
    for (int i = 0; i < 4; i++) {
      int gr = row0 + rt * 16 + hi * 4 + i;
      w4[rt][i] = (gr < N) ? w[gr] : 0.f;
    }

  for (int c = 0; c < 4; c++) {  // chunk of 4 col-tiles
    {
      const uint4* src = (const uint4*)(W2f + (size_t)c * 16384);
      uint4* dst = (uint4*)Bsh;
      #pragma unroll
      for (int i = 0; i < 8; i++) dst[t + i * 256] = src[t + i * 256];
    }
    __syncthreads();
    #pragma unroll
    for (int cp = 0; cp < 2; cp++) {
      int ct2 = cp * 2;
      f32x4 acc[2][4];
      #pragma unroll
      for (int u = 0; u < 2; u++)
        #pragma unroll
        for (int rt = 0; rt < 4; rt++) acc[u][rt] = (f32x4){0.f, 0.f, 0.f, 0.f};
      #pragma unroll
      for (int kb = 0; kb < 8; kb++) {
        bf16x8 b0 = *reinterpret_cast<const bf16x8*>(Bsh + ((ct2 * 8 + kb) * 64 + l) * 8);
        bf16x8 b1 = *reinterpret_cast<const bf16x8*>(Bsh + (((ct2 + 1) * 8 + kb) * 64 + l) * 8);
        #pragma unroll
        for (int rt = 0; rt < 4; rt++) {
          acc[0][rt] = __builtin_amdgcn_mfma_f32_16x16x32_bf16(a[rt][kb], b0, acc[0][rt], 0, 0, 0);
          acc[1][rt] = __builtin_amdgcn_mfma_f32_16x16x32_bf16(a[rt][kb], b1, acc[1][rt], 0, 0, 0);
        }
      }
      #pragma unroll
      for (int u = 0; u < 2; u++) {
        int col = (c * 4 + ct2 + u) * 16 + lo;
        float bc = b2[col];
        float p = 0.f;
        #pragma unroll
        for (int rt = 0; rt < 4; rt++)
          #pragma unroll
          for (int i = 0; i < 4; i++)
            p = fmaf(w4[rt][i], fmaxf(acc[u][rt][i] + bc, 0.f), p);
        p += __shfl_xor(p, 16);
        p += __shfl_xor(p, 32);
        if (hi == 0) vsh[wv][col] = p;
      }
    }
    __syncthreads();
  }
  float s = vsh[0][t] + vsh[1][t] + vsh[2][t] + vsh[3][t];
  part[(size_t)blockIdx.x * HID + t] = s;
}

// ---------------- K11: v+gfeat reduce, embedding, MLP head, final transform ------------
__global__ __launch_bounds__(256) void k_head(const float* __restrict__ part, int P,
                                              const float* __restrict__ gpart, int NG,
                                              const float* __restrict__ W3,
                                              const float* __restrict__ b3,
                                              const float* __restrict__ Wp1,
                                              const float* __restrict__ bp1,
                                              const float* __restrict__ Wp2,
                                              const float* __restrict__ bp2,
                                              const float* __restrict__ Wp3,
                                              const float* __restrict__ bp3,
                                              float* __restrict__ out, int N) {
  __shared__ float vsh[HID];
  __shared__ float gred[256];
  __shared__ float gsh[8];
  __shared__ float emb[EMBD + 7];
  __shared__ float h64[64];
  __shared__ float h32[32];
  __shared__ float val[4];
  int t = threadIdx.x;
  {
    float s = 0.f;
    for (int p = 0; p < P; p++) s += part[(size_t)p * HID + t];
    vsh[t] = s;
  }
  {
    float g = 0.f;
    int j = t & 7;
    for (int p = t >> 3; p < NG; p += 32) g += gpart[(size_t)p * 8 + j];
    gred[t] = g;
  }
  __syncthreads();
  if (t < 8) {
    float tot = 0.f;
    for (int q = t; q < 256; q += 8) tot += gred[q];
    gsh[t] = tot;
  }
  __syncthreads();
  if (t < EMBD) {
    float a = 0.f;
    for (int c = 0; c < HID; c++) a = fmaf(vsh[c], W3[c * EMBD + t], a);
    emb[t] = a / (float)N + b3[t];
  } else if (t == EMBD) {
    emb[EMBD + 0] = gsh[0];
    emb[EMBD + 1] = gsh[1];
    emb[EMBD + 2] = gsh[2];
    emb[EMBD + 3] = gsh[1] + gsh[2];
    float cnt = gsh[3];
    emb[EMBD + 4] = cnt > 0.f ? gsh[4] / fmaxf(cnt, 1.f) : 0.f;
    emb[EMBD + 5] = cnt > 0.f ? gsh[5] / fmaxf(cnt, 1.f) : 0.f;
    emb[EMBD + 6] = 100.0f / 500.0f;  // T_norm
  }
  __syncthreads();
  if (t < 64) {
    float a = bp1[t];
    for (int k = 0; k < EMBD + 7; k++) a = fmaf(emb[k], Wp1[k * 64 + t], a);
    h64[t] = fmaxf(a, 0.f);
  }
  __syncthreads();
  if (t < 32) {
    float a = bp2[t];
    for (int k = 0; k < 64; k++) a = fmaf(h64[k], Wp2[k * 32 + t], a);
    h32[t] = fmaxf(a, 0.f);
  }
  __syncthreads();
  if (t < 4) {
    float a = bp3[t];
    for (int k = 0; k < 32; k++) a = fmaf(h32[k], Wp3[k * 4 + t], a);
    val[t] = a > 20.f ? a : log1pf(expf(a));  // softplus
  }
  __syncthreads();
  if (t == 0) {
    const float Tn = 100.0f / 500.0f;
    const float scale = 1.0f - 0.7f * Tn;
    float am = 1.0f + val[0] * scale;
    float aM = 1.0f + (val[0] + val[1] + 1.0f) * scale;
    float bm = 1.0f + val[2] * scale * 0.3f;
    float bM = bm + (val[3] + 0.1f) * scale * 0.3f;
    out[0] = am; out[1] = aM; out[2] = bm; out[3] = bM;
  }
  if (t < EMBD + 7) out[4 + t] = emb[t];
}

static inline size_t al4(size_t a) { return (a + 3) & ~(size_t)3; }

extern "C" void kernel_launch(void* const* d_in, const int* in_sizes, int n_in,
                              void* d_out, int out_size, void* d_ws, size_t ws_size,
                              hipStream_t stream) {
  const float* x = (const float*)d_in[0];
  const int* ei = (const int*)d_in[1];
  const float* W1 = (const float*)d_in[2];
  const float* b1 = (const float*)d_in[3];
  const float* W2 = (const float*)d_in[4];
  const float* b2 = (const float*)d_in[5];
  const float* W3 = (const float*)d_in[6];
  const float* b3 = (const float*)d_in[7];
  const float* Wp1 = (const float*)d_in[8];
  const float* bp1 = (const float*)d_in[9];
  const float* Wp2 = (const float*)d_in[10];
  const float* bp2 = (const float*)d_in[11];
  const float* Wp3 = (const float*)d_in[12];
  const float* bp3 = (const float*)d_in[13];

  int N = in_sizes[0] / FIN;
  int E = in_sizes[1] / 2;
  int nb = (N + 255) / 256;
  int Npad = ((N + 255) / 256) * 256;   // multiple of 256 for k_gemm2
  int P = Npad / 256;                   // gemm2 blocks / partials
  int NB = (N + 63) / 64;               // buckets of 64 nodes
  int per = (E + NBLK - 1) / NBLK;      // edges per hist/place block
  size_t shbytes = (size_t)2 * NB * sizeof(int);

  float* ws = (float*)d_ws;
  size_t o_deg  = 0;                                 // N ints
  size_t o_row  = al4(o_deg + N);                    // N+1 ints
  size_t o_inv  = al4(o_row + N + 1);                // N floats
  size_t o_w    = al4(o_inv + N);                    // N floats
  size_t o_part = al4(o_w + N);                      // P*256 floats
  size_t o_gp   = o_part + (size_t)P * HID;          // nb*8 floats (gfeat partials)
  size_t o_xi   = al4(o_gp + (size_t)nb * 8);        // 4N (uint4/node)
  size_t o_w2t  = o_xi + (size_t)N * 4;              // 32768 (HID*HID bf16)
  size_t o_h2dD = o_w2t + (size_t)HID * HID / 2;     // NBLK*NB ints
  size_t o_h2dS = o_h2dD + (size_t)NBLK * NB;        // NBLK*NB ints
  size_t o_btot = o_h2dS + (size_t)NBLK * NB;        // 2*NB
  size_t o_bsD  = o_btot + (size_t)2 * NB;           // NB+1
  size_t o_bsS  = o_bsD + NB + 1;                    // NB+1
  size_t o_seD  = al4(o_bsS + NB + 1);               // E uints
  size_t o_seS  = o_seD + E;                         // E uints
  size_t o_csr  = o_seS + E;                         // E ints
  size_t o_H1q  = al4(o_csr + E);                    // 64N (256 fp8/node)
  size_t o_Z    = o_H1q + (size_t)N * (HID / 4);     // 128*Npad (bf16)
  size_t total  = o_Z + (size_t)Npad * (HID / 2);
  if (ws_size < total * sizeof(float)) {
    hipMemsetAsync(d_out, 0x42, (size_t)out_size * sizeof(float), stream);
    return;
  }

  int* deg = (int*)(ws + o_deg);
  int* row = (int*)(ws + o_row);
  int* h2dD = (int*)(ws + o_h2dD);
  int* h2dS = (int*)(ws + o_h2dS);
  int* btot = (int*)(ws + o_btot);
  int* bsD = (int*)(ws + o_bsD);
  int* bsS = (int*)(ws + o_bsS);
  unsigned int* seD = (unsigned int*)(ws + o_seD);
  unsigned int* seS = (unsigned int*)(ws + o_seS);
  int* csr = (int*)(ws + o_csr);
  unsigned short* W2f = (unsigned short*)(ws + o_w2t);
  uint4* xi = (uint4*)(ws + o_xi);
  unsigned char* H1q = (unsigned char*)(ws + o_H1q);
  unsigned short* Zb = (unsigned short*)(ws + o_Z);

  // no global memset needed: every buffer is fully written before first read

  k_hist<<<NBLK + HID, 256, shbytes, stream>>>(ei, W2, h2dD, h2dS, W2f, E, NB, per);
  k_bred<<<2 * NB, 256, 0, stream>>>(h2dD, h2dS, btot, NB);
  k_bscan<<<1, 256, 0, stream>>>(btot, bsD, bsS, row, E, NB, N);
  k_place<<<NBLK, 256, shbytes, stream>>>(ei, h2dD, h2dS, bsD, bsS, seD, seS, E, NB, per);
  k_csrd<<<NB, 256, 0, stream>>>(seD, bsD, csr, row, deg, NB, N);
  k_inv<<<nb, 256, 0, stream>>>(deg, x, ws + o_inv, xi, ws + o_gp, N);
  k_csrs<<<NB, 256, 0, stream>>>(seS, bsS, ws + o_inv, ws + o_w, NB, N);
  k_h1f<<<nb, 256, 0, stream>>>(xi, row, csr, ws + o_inv, W1, b1, H1q, ws + o_w, N);
  k_agg<<<Npad / 4, 256, 0, stream>>>(row, csr, ws + o_inv, H1q, Zb, N);
  k_gemm2<<<P, 256, 0, stream>>>(Zb, ws + o_w, W2f, b2, ws + o_part, N);
  k_head<<<1, 256, 0, stream>>>(ws + o_part, P, ws + o_gp, nb, W3, b3, Wp1, bp1, Wp2, bp2,
                                Wp3, bp3, (float*)d_out, N);
}

// Round 9
// 297.086 us; speedup vs baseline: 21.2502x; 1.3291x over previous
//
#include <hip/hip_runtime.h>
#include <hip/hip_bf16.h>
#include <hip/hip_fp16.h>
#include <cstdint>
#include <cstddef>

#define HID 256
#define EMBD 128
#define FIN 5
#define NBLK 256   // histogram/placement blocks
#define VRB 32     // v-reduce blocks

typedef __attribute__((ext_vector_type(8))) short bf16x8;
typedef __attribute__((ext_vector_type(4))) float f32x4;
typedef __attribute__((ext_vector_type(2))) _Float16 half2v;

__device__ __forceinline__ unsigned short f2bf(float f) {
  unsigned int u = __float_as_uint(f);
  u += 0x7FFFu + ((u >> 16) & 1u);   // RNE
  return (unsigned short)(u >> 16);
}
__device__ __forceinline__ float bflo(unsigned int u) { return __uint_as_float(u << 16); }
__device__ __forceinline__ float bfhi(unsigned int u) { return __uint_as_float(u & 0xFFFF0000u); }
__device__ __forceinline__ unsigned int pack2bf(float a, float b) {
  return ((unsigned int)f2bf(b) << 16) | (unsigned int)f2bf(a);
}
// fp8 e5m2 = top byte of fp16, manual RNE
__device__ __forceinline__ unsigned char f2bf8(float f) {
  unsigned short u = __half_as_ushort(__float2half(f));
  unsigned short r = u + 0x7Fu + ((u >> 8) & 1u);
  return (unsigned char)(r >> 8);
}
__device__ __forceinline__ unsigned int pk4fp8(float a, float b, float c, float d) {
  return (unsigned int)f2bf8(a) | ((unsigned int)f2bf8(b) << 8) |
         ((unsigned int)f2bf8(c) << 16) | ((unsigned int)f2bf8(d) << 24);
}
// decode 4 e5m2 bytes of u as two f16 pairs and accumulate (2 bitops + 2 pk_add)
__device__ __forceinline__ void acc2h(half2v* h, unsigned int u) {
  unsigned int p0 = (u << 8) & 0xFF00FF00u;   // bytes 0,2 -> f16 (lo,hi)
  unsigned int p1 = u & 0xFF00FF00u;          // bytes 1,3 -> f16 (lo,hi)
  half2v v0, v1;
  __builtin_memcpy(&v0, &p0, 4);
  __builtin_memcpy(&v1, &p1, 4);
  h[0] += v0;
  h[1] += v1;
}
__device__ __forceinline__ half2v h2shfl_xor(half2v v, int mask) {
  unsigned int b;
  __builtin_memcpy(&b, &v, 4);
  b = __shfl_xor(b, mask);
  half2v r;
  __builtin_memcpy(&r, &b, 4);
  return r;
}

// ---------------- K1: dual LDS histogram (dst & src buckets) + W2 -> fragment order ------
__global__ __launch_bounds__(256) void k_hist(const int* __restrict__ ei,
                                              const float* __restrict__ W2,
                                              int* __restrict__ h2dD,
                                              int* __restrict__ h2dS,
                                              unsigned short* __restrict__ W2f,
                                              int E, int NB, int per) {
  int b = blockIdx.x, t = threadIdx.x;
  if (b >= NBLK) {  // W2 pack blocks: b-NBLK = n (col), t = k
    int n = b - NBLK;
    size_t off = ((((size_t)(n >> 4) * 8 + (t >> 5)) * 64) +
                  (size_t)((t >> 3) & 3) * 16 + (n & 15)) * 8 + (t & 7);
    W2f[off] = f2bf(W2[(size_t)t * HID + n]);
    return;
  }
  extern __shared__ int hsh[];  // 2*NB ints
  int* hD = hsh;
  int* hS = hsh + NB;
  for (int j = t; j < 2 * NB; j += 256) hsh[j] = 0;
  __syncthreads();
  int lo = b * per, hi = min(E, lo + per);
  for (int e = lo + t; e < hi; e += 256) {
    int s = ei[e];
    int d = ei[(size_t)E + e];
    atomicAdd(&hD[d >> 6], 1);
    atomicAdd(&hS[s >> 6], 1);
  }
  __syncthreads();
  for (int j = t; j < NB; j += 256) {
    h2dD[(size_t)b * NB + j] = hD[j];
    h2dS[(size_t)b * NB + j] = hS[j];
  }
}

// ---------------- K2: per-bucket exclusive scan over blocks ----------------
__global__ __launch_bounds__(256) void k_bred(int* __restrict__ h2dD,
                                              int* __restrict__ h2dS,
                                              int* __restrict__ btot, int NB) {
  __shared__ int sh[NBLK];
  int bb = blockIdx.x, t = threadIdx.x;
  int* arr = (bb < NB) ? h2dD : h2dS;
  int b = (bb < NB) ? bb : bb - NB;
  int v = arr[(size_t)t * NB + b];
  sh[t] = v;
  __syncthreads();
  for (int off = 1; off < 256; off <<= 1) {
    int u = (t >= off) ? sh[t - off] : 0;
    __syncthreads();
    sh[t] += u;
    __syncthreads();
  }
  arr[(size_t)t * NB + b] = sh[t] - v;   // exclusive over blocks
  if (t == 255) btot[bb] = sh[255];
}

// ---------------- K3: scan bucket totals -> bucket starts ----------------
__global__ __launch_bounds__(256) void k_bscan(const int* __restrict__ btot,
                                               int* __restrict__ bsD,
                                               int* __restrict__ bsS,
                                               int* __restrict__ row,
                                               int E, int NB, int N) {
  __shared__ int sh[256];
  __shared__ int carrysh;
  int t = threadIdx.x;
  for (int which = 0; which < 2; which++) {
    const int* src = btot + (size_t)which * NB;
    int* dst = which ? bsS : bsD;
    if (t == 0) carrysh = 0;
    __syncthreads();
    int nch = (NB + 255) / 256;
    for (int c = 0; c < nch; c++) {
      int i = c * 256 + t;
      int v = (i < NB) ? src[i] : 0;
      sh[t] = v;
      __syncthreads();
      for (int off = 1; off < 256; off <<= 1) {
        int u = (t >= off) ? sh[t - off] : 0;
        __syncthreads();
        sh[t] += u;
        __syncthreads();
      }
      int carry = carrysh;
      if (i < NB) dst[i] = carry + sh[t] - v;
      __syncthreads();
      if (t == 255) carrysh = carry + sh[255];
      __syncthreads();
    }
    if (t == 0) dst[NB] = E;
    __syncthreads();
  }
  if (t == 0) row[N] = E;
}

// ---------------- K4: placement into bucket-sorted edge arrays (LDS counters only) --------
__global__ __launch_bounds__(256) void k_place(const int* __restrict__ ei,
                                               const int* __restrict__ h2dD,
                                               const int* __restrict__ h2dS,
                                               const int* __restrict__ bsD,
                                               const int* __restrict__ bsS,
                                               unsigned int* __restrict__ seD,
                                               unsigned int* __restrict__ seS,
                                               int E, int NB, int per) {
  extern __shared__ int osh[];  // 2*NB ints
  int* oD = osh;
  int* oS = osh + NB;
  int b = blockIdx.x, t = threadIdx.x;
  for (int j = t; j < NB; j += 256) {
    oD[j] = bsD[j] + h2dD[(size_t)b * NB + j];
    oS[j] = bsS[j] + h2dS[(size_t)b * NB + j];
  }
  __syncthreads();
  int lo = b * per, hi = min(E, lo + per);
  for (int e = lo + t; e < hi; e += 256) {
    int s = ei[e];
    int d = ei[(size_t)E + e];
    int pd = atomicAdd(&oD[d >> 6], 1);
    seD[pd] = (unsigned int)s | ((unsigned int)(d & 63) << 20);
    int ps = atomicAdd(&oS[s >> 6], 1);
    seS[ps] = (unsigned int)d | ((unsigned int)(s & 63) << 20);
  }
}

// ---------------- K5: per-bucket dst CSR finalize: csr, row, deg ----------------
__global__ __launch_bounds__(256) void k_csrd(const unsigned int* __restrict__ seD,
                                              const int* __restrict__ bsD,
                                              int* __restrict__ csr,
                                              int* __restrict__ row,
                                              int* __restrict__ deg, int NB, int N) {
  __shared__ int cnt[64], sc[64], ofs[64];
  int b = blockIdx.x, t = threadIdx.x;
  if (t < 64) cnt[t] = 0;
  __syncthreads();
  int lo = bsD[b], hi = bsD[b + 1];
  for (int k = lo + t; k < hi; k += 256) atomicAdd(&cnt[seD[k] >> 20], 1);
  __syncthreads();
  if (t < 64) sc[t] = cnt[t];
  __syncthreads();
  for (int off = 1; off < 64; off <<= 1) {
    int u = (t < 64 && t >= off) ? sc[t - off] : 0;
    __syncthreads();
    if (t < 64) sc[t] += u;
    __syncthreads();
  }
  if (t < 64) {
    int ex = sc[t] - cnt[t];
    ofs[t] = ex;
    int node = b * 64 + t;
    if (node < N) { row[node] = lo + ex; deg[node] = cnt[t]; }
  }
  __syncthreads();
  for (int k = lo + t; k < hi; k += 256) {
    unsigned int v = seD[k];
    int p = atomicAdd(&ofs[v >> 20], 1);
    csr[lo + p] = (int)(v & 0xFFFFFu);
  }
}

// ---------------- K6: inv = rsqrt(deg+1); xi = bf16(x*inv); gfeat partials (NO atomics) --
__global__ __launch_bounds__(256) void k_inv(const int* __restrict__ deg,
                                             const float* __restrict__ x,
                                             float* __restrict__ inv,
                                             uint4* __restrict__ xi,
                                             float* __restrict__ gpart, int N) {
  __shared__ float wsum[4][6];
  int t = threadIdx.x;
  int i = blockIdx.x * 256 + t;
  float s2 = 0.f, s3 = 0.f, s4 = 0.f, c0 = 0.f, sl = 0.f, sm = 0.f;
  if (i < N) {
    float iv = rsqrtf((float)deg[i] + 1.0f);
    inv[i] = iv;
    float x0 = x[(size_t)i * 5 + 0];
    float x1 = x[(size_t)i * 5 + 1];
    float x2 = x[(size_t)i * 5 + 2];
    float x3 = x[(size_t)i * 5 + 3];
    float x4 = x[(size_t)i * 5 + 4];
    uint4 o;
    o.x = pack2bf(x0 * iv, x1 * iv);
    o.y = pack2bf(x2 * iv, x3 * iv);
    o.z = pack2bf(x4 * iv, 0.f);
    o.w = 0u;
    xi[i] = o;
    s2 = x2; s3 = x3; s4 = x4;
    if (x2 == 1.0f) { c0 = 1.f; sl = x0; sm = x1; }
  }
  #pragma unroll
  for (int off = 32; off > 0; off >>= 1) {
    s2 += __shfl_down(s2, off);
    s3 += __shfl_down(s3, off);
    s4 += __shfl_down(s4, off);
    c0 += __shfl_down(c0, off);
    sl += __shfl_down(sl, off);
    sm += __shfl_down(sm, off);
  }
  if ((t & 63) == 0) {
    int wv = t >> 6;
    wsum[wv][0] = s2; wsum[wv][1] = s3; wsum[wv][2] = s4;
    wsum[wv][3] = c0; wsum[wv][4] = sl; wsum[wv][5] = sm;
  }
  __syncthreads();
  if (t < 8) {
    float g = 0.f;
    if (t < 6) g = wsum[0][t] + wsum[1][t] + wsum[2][t] + wsum[3][t];
    gpart[(size_t)blockIdx.x * 8 + t] = g;   // coalesced, zero atomics
  }
}

// ---------------- K7: per-bucket src pass: w_raw[s] = sum inv[dst] (LDS only) ----------
__global__ __launch_bounds__(256) void k_csrs(const unsigned int* __restrict__ seS,
                                              const int* __restrict__ bsS,
                                              const float* __restrict__ inv,
                                              float* __restrict__ w, int NB, int N) {
  __shared__ float wa[64];
  int b = blockIdx.x, t = threadIdx.x;
  if (t < 64) wa[t] = 0.f;
  __syncthreads();
  int lo = bsS[b], hi = bsS[b + 1];
  for (int k = lo + t; k < hi; k += 256) {
    unsigned int v = seS[k];
    atomicAdd(&wa[v >> 20], inv[v & 0xFFFFFu]);
  }
  __syncthreads();
  if (t < 64) {
    int node = b * 64 + t;
    if (node < N) w[node] = wa[t];
  }
}

// ---------------- K8: thread-per-node xi gather; H1' = inv*relu(U@W1+b1) -> fp8 --------
__global__ __launch_bounds__(256) void k_h1f(const uint4* __restrict__ xi,
                                             const int* __restrict__ row,
                                             const int* __restrict__ csr,
                                             const float* __restrict__ inv,
                                             const float* __restrict__ W1,
                                             const float* __restrict__ b1,
                                             unsigned char* __restrict__ H1q,
                                             float* __restrict__ w, int N) {
  __shared__ float W1sh[FIN][HID];
  __shared__ float b1sh[HID];
  int t = threadIdx.x;
  #pragma unroll
  for (int k = 0; k < FIN; k++) W1sh[k][t] = W1[k * HID + t];
  b1sh[t] = b1[t];
  int n = blockIdx.x * 256 + t;
  float a0 = 0.f, a1 = 0.f, a2 = 0.f, a3 = 0.f, a4 = 0.f;
  float invd = 0.f;
  if (n < N) {
    invd = inv[n];
    int start = row[n], end = row[n + 1];
    for (int e = start; e < end; e++) {
      uint4 vx = xi[csr[e]];
      a0 += bflo(vx.x); a1 += bfhi(vx.x);
      a2 += bflo(vx.y); a3 += bfhi(vx.y);
      a4 += bflo(vx.z);
    }
    uint4 vs = xi[n];
    a0 += bflo(vs.x); a1 += bfhi(vs.x);
    a2 += bflo(vs.y); a3 += bfhi(vs.y);
    a4 += bflo(vs.z);
    a0 *= invd; a1 *= invd; a2 *= invd; a3 *= invd; a4 *= invd;
    w[n] = invd * w[n] + invd * invd;  // finalize pooling weight
  }
  __syncthreads();
  if (n >= N) return;
  unsigned char* hrow = H1q + (size_t)n * HID;
  for (int c = 0; c < HID; c += 16) {
    float vv[16];
    #pragma unroll
    for (int j = 0; j < 16; j++) {
      float s = b1sh[c + j];
      s = fmaf(a0, W1sh[0][c + j], s);
      s = fmaf(a1, W1sh[1][c + j], s);
      s = fmaf(a2, W1sh[2][c + j], s);
      s = fmaf(a3, W1sh[3][c + j], s);
      s = fmaf(a4, W1sh[4][c + j], s);
      vv[j] = fmaxf(s, 0.f) * invd;   // H1' = inv * relu(...)
    }
    uint4 o;
    o.x = pk4fp8(vv[0], vv[1], vv[2], vv[3]);
    o.y = pk4fp8(vv[4], vv[5], vv[6], vv[7]);
    o.z = pk4fp8(vv[8], vv[9], vv[10], vv[11]);
    o.w = pk4fp8(vv[12], vv[13], vv[14], vv[15]);
    *(uint4*)(hrow + c) = o;
  }
}

// ---------------- K9: Z[d] = inv_d*(sum_s H1'[s] + H1'[d])  (fp8 gather, f16 pk-accum) --
__global__ __launch_bounds__(256) void k_agg(const int* __restrict__ row,
                                             const int* __restrict__ csr,
                                             const float* __restrict__ inv,
                                             const unsigned char* __restrict__ H1q,
                                             unsigned short* __restrict__ Zb, int N) {
  int wv = threadIdx.x >> 6;
  int l = threadIdx.x & 63;
  int q = l >> 4;       // quarter: which edge in flight
  int sl = l & 15;      // col group: cols sl*16 .. sl*16+15
  int d = blockIdx.x * 4 + wv;
  half2v hacc[8];
  #pragma unroll
  for (int j = 0; j < 8; j++) hacc[j] = (half2v){(_Float16)0.f, (_Float16)0.f};
  if (d >= N) {
    if (l < 32) {  // zero pad rows for k_gemm2
      uint4 z = {0u, 0u, 0u, 0u};
      *(uint4*)(Zb + (size_t)d * HID + (l & 15) * 16 + (l >> 4) * 8) = z;
    }
    return;
  }
  float invd = inv[d];
  int start = row[d], end = row[d + 1];
  int e = start + q;
  for (; e + 4 < end; e += 8) {
    uint4 r0 = *(const uint4*)(H1q + (size_t)csr[e] * HID + sl * 16);
    uint4 r1 = *(const uint4*)(H1q + (size_t)csr[e + 4] * HID + sl * 16);
    acc2h(hacc + 0, r0.x); acc2h(hacc + 2, r0.y);
    acc2h(hacc + 4, r0.z); acc2h(hacc + 6, r0.w);
    acc2h(hacc + 0, r1.x); acc2h(hacc + 2, r1.y);
    acc2h(hacc + 4, r1.z); acc2h(hacc + 6, r1.w);
  }
  for (; e < end; e += 4) {
    uint4 r0 = *(const uint4*)(H1q + (size_t)csr[e] * HID + sl * 16);
    acc2h(hacc + 0, r0.x); acc2h(hacc + 2, r0.y);
    acc2h(hacc + 4, r0.z); acc2h(hacc + 6, r0.w);
  }
  if (q == 0) {  // self-loop term
    uint4 rs = *(const uint4*)(H1q + (size_t)d * HID + sl * 16);
    acc2h(hacc + 0, rs.x); acc2h(hacc + 2, rs.y);
    acc2h(hacc + 4, rs.z); acc2h(hacc + 6, rs.w);
  }
  #pragma unroll
  for (int j = 0; j < 8; j++) {
    hacc[j] += h2shfl_xor(hacc[j], 16);
    hacc[j] += h2shfl_xor(hacc[j], 32);
  }
  if (l < 32) {
    // unpack: chunk j covers cols 4j..4j+3; hacc[2j]=(c0,c2), hacc[2j+1]=(c1,c3)
    float vals[16];
    #pragma unroll
    for (int j = 0; j < 4; j++) {
      vals[4 * j + 0] = (float)hacc[2 * j][0];
      vals[4 * j + 2] = (float)hacc[2 * j][1];
      vals[4 * j + 1] = (float)hacc[2 * j + 1][0];
      vals[4 * j + 3] = (float)hacc[2 * j + 1][1];
    }
    int half = l >> 4;
    int base = half * 8;
    int col0 = (l & 15) * 16 + half * 8;
    uint4 o;
    o.x = pack2bf(vals[base + 0] * invd, vals[base + 1] * invd);
    o.y = pack2bf(vals[base + 2] * invd, vals[base + 3] * invd);
    o.z = pack2bf(vals[base + 4] * invd, vals[base + 5] * invd);
    o.w = pack2bf(vals[base + 6] * invd, vals[base + 7] * invd);
    *(uint4*)(Zb + (size_t)d * HID + col0) = o;
  }
}

// ---------------- K10: MFMA GEMM: H2 = relu(Z @ W2 + b2); part[blk] = H2^T w -----------
__global__ __launch_bounds__(256, 2) void k_gemm2(const unsigned short* __restrict__ Zb,
                                                  const float* __restrict__ w,
                                                  const unsigned short* __restrict__ W2f,
                                                  const float* __restrict__ b2,
                                                  float* __restrict__ part, int N) {
  __shared__ unsigned short Bsh[16384];  // 32 KB: 4 col-tiles x 8 kb x 64 lanes x 8
  __shared__ float vsh[4][HID];
  int t = threadIdx.x;
  int wv = t >> 6, l = t & 63;
  int lo = l & 15, hi = l >> 4;
  int row0 = blockIdx.x * 256 + wv * 64;

  bf16x8 a[4][8];
  #pragma unroll
  for (int rt = 0; rt < 4; rt++) {
    const unsigned short* zrow = Zb + (size_t)(row0 + rt * 16 + lo) * HID + hi * 8;
    #pragma unroll
    for (int kb = 0; kb < 8; kb++)
      a[rt][kb] = *reinterpret_cast<const bf16x8*>(zrow + kb * 32);
  }
  float w4[4][4];
  #pragma unroll
  for (int rt = 0; rt < 4; rt++)
    #pragma unroll
    for (int i = 0; i < 4; i++) {
      int gr = row0 + rt * 16 + hi * 4 + i;
      w4[rt][i] = (gr < N) ? w[gr] : 0.f;
    }

  for (int c = 0; c < 4; c++) {  // chunk of 4 col-tiles
    {
      const uint4* src = (const uint4*)(W2f + (size_t)c * 16384);
      uint4* dst = (uint4*)Bsh;
      #pragma unroll
      for (int i = 0; i < 8; i++) dst[t + i * 256] = src[t + i * 256];
    }
    __syncthreads();
    #pragma unroll
    for (int cp = 0; cp < 2; cp++) {
      int ct2 = cp * 2;
      f32x4 acc[2][4];
      #pragma unroll
      for (int u = 0; u < 2; u++)
        #pragma unroll
        for (int rt = 0; rt < 4; rt++) acc[u][rt] = (f32x4){0.f, 0.f, 0.f, 0.f};
      #pragma unroll
      for (int kb = 0; kb < 8; kb++) {
        bf16x8 b0 = *reinterpret_cast<const bf16x8*>(Bsh + ((ct2 * 8 + kb) * 64 + l) * 8);
        bf16x8 b1 = *reinterpret_cast<const bf16x8*>(Bsh + (((ct2 + 1) * 8 + kb) * 64 + l) * 8);
        #pragma unroll
        for (int rt = 0; rt < 4; rt++) {
          acc[0][rt] = __builtin_amdgcn_mfma_f32_16x16x32_bf16(a[rt][kb], b0, acc[0][rt], 0, 0, 0);
          acc[1][rt] = __builtin_amdgcn_mfma_f32_16x16x32_bf16(a[rt][kb], b1, acc[1][rt], 0, 0, 0);
        }
      }
      #pragma unroll
      for (int u = 0; u < 2; u++) {
        int col = (c * 4 + ct2 + u) * 16 + lo;
        float bc = b2[col];
        float p = 0.f;
        #pragma unroll
        for (int rt = 0; rt < 4; rt++)
          #pragma unroll
          for (int i = 0; i < 4; i++)
            p = fmaf(w4[rt][i], fmaxf(acc[u][rt][i] + bc, 0.f), p);
        p += __shfl_xor(p, 16);
        p += __shfl_xor(p, 32);
        if (hi == 0) vsh[wv][col] = p;
      }
    }
    __syncthreads();
  }
  float s = vsh[0][t] + vsh[1][t] + vsh[2][t] + vsh[3][t];
  part[(size_t)blockIdx.x * HID + t] = s;
}

// ---------------- K10b: parallel partial reduce part[P][256] -> part2[VRB][256] --------
__global__ __launch_bounds__(256) void k_vred(const float* __restrict__ part, int P,
                                              float* __restrict__ part2) {
  int b = blockIdx.x, t = threadIdx.x;
  int chunk = (P + VRB - 1) / VRB;
  int lo = b * chunk, hi = min(P, lo + chunk);
  float s0 = 0.f, s1 = 0.f, s2 = 0.f, s3 = 0.f;
  int p = lo;
  for (; p + 3 < hi; p += 4) {
    s0 += part[(size_t)p * HID + t];
    s1 += part[(size_t)(p + 1) * HID + t];
    s2 += part[(size_t)(p + 2) * HID + t];
    s3 += part[(size_t)(p + 3) * HID + t];
  }
  for (; p < hi; p++) s0 += part[(size_t)p * HID + t];
  part2[(size_t)b * HID + t] = (s0 + s1) + (s2 + s3);
}

// ---------------- K11: v+gfeat reduce, embedding, MLP head, final transform ------------
__global__ __launch_bounds__(256) void k_head(const float* __restrict__ part2,
                                              const float* __restrict__ gpart, int NG,
                                              const float* __restrict__ W3,
                                              const float* __restrict__ b3,
                                              const float* __restrict__ Wp1,
                                              const float* __restrict__ bp1,
                                              const float* __restrict__ Wp2,
                                              const float* __restrict__ bp2,
                                              const float* __restrict__ Wp3,
                                              const float* __restrict__ bp3,
                                              float* __restrict__ out, int N) {
  __shared__ float vsh[HID];
  __shared__ float gred[256];
  __shared__ float gsh[8];
  __shared__ float emb2[256];
  __shared__ float emb[EMBD + 7];
  __shared__ float h64[64];
  __shared__ float h32[32];
  __shared__ float val[4];
  int t = threadIdx.x;
  {
    float s0 = 0.f, s1 = 0.f, s2 = 0.f, s3 = 0.f;
    #pragma unroll
    for (int p = 0; p < VRB; p += 4) {
      s0 += part2[(size_t)p * HID + t];
      s1 += part2[(size_t)(p + 1) * HID + t];
      s2 += part2[(size_t)(p + 2) * HID + t];
      s3 += part2[(size_t)(p + 3) * HID + t];
    }
    vsh[t] = (s0 + s1) + (s2 + s3);
  }
  {
    float g = 0.f;
    int j = t & 7;
    for (int p = t >> 3; p < NG; p += 32) g += gpart[(size_t)p * 8 + j];
    gred[t] = g;
  }
  __syncthreads();
  if (t < 8) {
    float tot = 0.f;
    for (int q = t; q < 256; q += 8) tot += gred[q];
    gsh[t] = tot;
  }
  // W3 matvec with all 256 threads: 2 threads per output dim
  {
    int dim = t & 127, ch = (t >> 7) * 128;
    float a0 = 0.f, a1 = 0.f, a2 = 0.f, a3 = 0.f;
    #pragma unroll 4
    for (int c = 0; c < 128; c += 4) {
      a0 = fmaf(vsh[ch + c + 0], W3[(size_t)(ch + c + 0) * EMBD + dim], a0);
      a1 = fmaf(vsh[ch + c + 1], W3[(size_t)(ch + c + 1) * EMBD + dim], a1);
      a2 = fmaf(vsh[ch + c + 2], W3[(size_t)(ch + c + 2) * EMBD + dim], a2);
      a3 = fmaf(vsh[ch + c + 3], W3[(size_t)(ch + c + 3) * EMBD + dim], a3);
    }
    emb2[t] = (a0 + a1) + (a2 + a3);
  }
  __syncthreads();
  if (t < EMBD) {
    emb[t] = (emb2[t] + emb2[t + 128]) / (float)N + b3[t];
  } else if (t == EMBD) {
    emb[EMBD + 0] = gsh[0];
    emb[EMBD + 1] = gsh[1];
    emb[EMBD + 2] = gsh[2];
    emb[EMBD + 3] = gsh[1] + gsh[2];
    float cnt = gsh[3];
    emb[EMBD + 4] = cnt > 0.f ? gsh[4] / fmaxf(cnt, 1.f) : 0.f;
    emb[EMBD + 5] = cnt > 0.f ? gsh[5] / fmaxf(cnt, 1.f) : 0.f;
    emb[EMBD + 6] = 100.0f / 500.0f;  // T_norm
  }
  __syncthreads();
  if (t < 64) {
    float a = bp1[t];
    for (int k = 0; k < EMBD + 7; k++) a = fmaf(emb[k], Wp1[k * 64 + t], a);
    h64[t] = fmaxf(a, 0.f);
  }
  __syncthreads();
  if (t < 32) {
    float a = bp2[t];
    for (int k = 0; k < 64; k++) a = fmaf(h64[k], Wp2[k * 32 + t], a);
    h32[t] = fmaxf(a, 0.f);
  }
  __syncthreads();
  if (t < 4) {
    float a = bp3[t];
    for (int k = 0; k < 32; k++) a = fmaf(h32[k], Wp3[k * 4 + t], a);
    val[t] = a > 20.f ? a : log1pf(expf(a));  // softplus
  }
  __syncthreads();
  if (t == 0) {
    const float Tn = 100.0f / 500.0f;
    const float scale = 1.0f - 0.7f * Tn;
    float am = 1.0f + val[0] * scale;
    float aM = 1.0f + (val[0] + val[1] + 1.0f) * scale;
    float bm = 1.0f + val[2] * scale * 0.3f;
    float bM = bm + (val[3] + 0.1f) * scale * 0.3f;
    out[0] = am; out[1] = aM; out[2] = bm; out[3] = bM;
  }
  if (t < EMBD + 7) out[4 + t] = emb[t];
}

static inline size_t al4(size_t a) { return (a + 3) & ~(size_t)3; }

extern "C" void kernel_launch(void* const* d_in, const int* in_sizes, int n_in,
                              void* d_out, int out_size, void* d_ws, size_t ws_size,
                              hipStream_t stream) {
  const float* x = (const float*)d_in[0];
  const int* ei = (const int*)d_in[1];
  const float* W1 = (const float*)d_in[2];
  const float* b1 = (const float*)d_in[3];
  const float* W2 = (const float*)d_in[4];
  const float* b2 = (const float*)d_in[5];
  const float* W3 = (const float*)d_in[6];
  const float* b3 = (const float*)d_in[7];
  const float* Wp1 = (const float*)d_in[8];
  const float* bp1 = (const float*)d_in[9];
  const float* Wp2 = (const float*)d_in[10];
  const float* bp2 = (const float*)d_in[11];
  const float* Wp3 = (const float*)d_in[12];
  const float* bp3 = (const float*)d_in[13];

  int N = in_sizes[0] / FIN;
  int E = in_sizes[1] / 2;
  int nb = (N + 255) / 256;
  int Npad = ((N + 255) / 256) * 256;   // multiple of 256 for k_gemm2
  int P = Npad / 256;                   // gemm2 blocks / partials
  int NB = (N + 63) / 64;               // buckets of 64 nodes
  int per = (E + NBLK - 1) / NBLK;      // edges per hist/place block
  size_t shbytes = (size_t)2 * NB * sizeof(int);

  float* ws = (float*)d_ws;
  size_t o_deg  = 0;                                 // N ints
  size_t o_row  = al4(o_deg + N);                    // N+1 ints
  size_t o_inv  = al4(o_row + N + 1);                // N floats
  size_t o_w    = al4(o_inv + N);                    // N floats
  size_t o_part = al4(o_w + N);                      // P*256 floats
  size_t o_p2   = o_part + (size_t)P * HID;          // VRB*256 floats
  size_t o_gp   = o_p2 + (size_t)VRB * HID;          // nb*8 floats (gfeat partials)
  size_t o_xi   = al4(o_gp + (size_t)nb * 8);        // 4N (uint4/node)
  size_t o_w2t  = o_xi + (size_t)N * 4;              // 32768 (HID*HID bf16)
  size_t o_h2dD = o_w2t + (size_t)HID * HID / 2;     // NBLK*NB ints
  size_t o_h2dS = o_h2dD + (size_t)NBLK * NB;        // NBLK*NB ints
  size_t o_btot = o_h2dS + (size_t)NBLK * NB;        // 2*NB
  size_t o_bsD  = o_btot + (size_t)2 * NB;           // NB+1
  size_t o_bsS  = o_bsD + NB + 1;                    // NB+1
  size_t o_seD  = al4(o_bsS + NB + 1);               // E uints
  size_t o_seS  = o_seD + E;                         // E uints
  size_t o_csr  = o_seS + E;                         // E ints
  size_t o_H1q  = al4(o_csr + E);                    // 64N (256 fp8/node)
  size_t o_Z    = o_H1q + (size_t)N * (HID / 4);     // 128*Npad (bf16)
  size_t total  = o_Z + (size_t)Npad * (HID / 2);
  if (ws_size < total * sizeof(float)) {
    hipMemsetAsync(d_out, 0x42, (size_t)out_size * sizeof(float), stream);
    return;
  }

  int* deg = (int*)(ws + o_deg);
  int* row = (int*)(ws + o_row);
  int* h2dD = (int*)(ws + o_h2dD);
  int* h2dS = (int*)(ws + o_h2dS);
  int* btot = (int*)(ws + o_btot);
  int* bsD = (int*)(ws + o_bsD);
  int* bsS = (int*)(ws + o_bsS);
  unsigned int* seD = (unsigned int*)(ws + o_seD);
  unsigned int* seS = (unsigned int*)(ws + o_seS);
  int* csr = (int*)(ws + o_csr);
  unsigned short* W2f = (unsigned short*)(ws + o_w2t);
  uint4* xi = (uint4*)(ws + o_xi);
  unsigned char* H1q = (unsigned char*)(ws + o_H1q);
  unsigned short* Zb = (unsigned short*)(ws + o_Z);

  k_hist<<<NBLK + HID, 256, shbytes, stream>>>(ei, W2, h2dD, h2dS, W2f, E, NB, per);
  k_bred<<<2 * NB, 256, 0, stream>>>(h2dD, h2dS, btot, NB);
  k_bscan<<<1, 256, 0, stream>>>(btot, bsD, bsS, row, E, NB, N);
  k_place<<<NBLK, 256, shbytes, stream>>>(ei, h2dD, h2dS, bsD, bsS, seD, seS, E, NB, per);
  k_csrd<<<NB, 256, 0, stream>>>(seD, bsD, csr, row, deg, NB, N);
  k_inv<<<nb, 256, 0, stream>>>(deg, x, ws + o_inv, xi, ws + o_gp, N);
  k_csrs<<<NB, 256, 0, stream>>>(seS, bsS, ws + o_inv, ws + o_w, NB, N);
  k_h1f<<<nb, 256, 0, stream>>>(xi, row, csr, ws + o_inv, W1, b1, H1q, ws + o_w, N);
  k_agg<<<Npad / 4, 256, 0, stream>>>(row, csr, ws + o_inv, H1q, Zb, N);
  k_gemm2<<<P, 256, 0, stream>>>(Zb, ws + o_w, W2f, b2, ws + o_part, N);
  k_vred<<<VRB, 256, 0, stream>>>(ws + o_part, P, ws + o_p2);
  k_head<<<1, 256, 0, stream>>>(ws + o_p2, ws + o_gp, nb, W3, b3, Wp1, bp1, Wp2, bp2,
                                Wp3, bp3, (float*)d_out, N);
}